// Round 1
// baseline (3343.306 us; speedup 1.0000x reference)
//
#include <hip/hip_runtime.h>

#define L_TXT 256
#define L_IMG 1024
#define L_TMP 1024
#define LTOT  2304
#define DMODEL 1024
#define NH 16
#define HDIM 64
#define DMLP 4096
#define EPSV 1e-6f

// workspace offsets (in floats)
#define WS_SV   0
#define WS_MOD  1024
#define WS_XM   32768
#define WS_QKV  (WS_XM  + LTOT*DMODEL)          // 2392064
#define WS_Q    (WS_QKV + LTOT*3*DMODEL)        // 9469952
#define WS_K    (WS_Q   + NH*LTOT*HDIM)
#define WS_V    (WS_K   + NH*LTOT*HDIM)
#define WS_ATT  (WS_V   + NH*LTOT*HDIM)
#define WS_S1   (WS_ATT + LTOT*DMODEL)
#define WS_H    (WS_S1  + LTOT*DMODEL)
#define WS_T1   (WS_H   + L_IMG*DMODEL)

// ---------------- silu(vec) ----------------
__global__ void k_silu(const float* __restrict__ vec, float* __restrict__ sv) {
    int i = blockIdx.x * 256 + threadIdx.x;
    if (i < DMODEL) {
        float v = vec[i];
        sv[i] = v / (1.0f + __expf(-v));
    }
}

// ---------------- mod GEMV: (1,1024) @ (3,1024,6144) + b ----------------
__global__ __launch_bounds__(256) void k_mod(const float* __restrict__ sv,
                                             const float* __restrict__ mw,
                                             const float* __restrict__ mb,
                                             float* __restrict__ mod) {
    __shared__ float svs[DMODEL];
    for (int i = threadIdx.x; i < DMODEL; i += 256) svs[i] = sv[i];
    __syncthreads();
    int g = blockIdx.x * 256 + threadIdx.x;   // 0..18431
    int i = g / 6144;
    int j = g - i * 6144;
    const float* w = mw + (size_t)i * DMODEL * 6144 + j;
    float acc = 0.f;
#pragma unroll 4
    for (int k = 0; k < DMODEL; k++) acc += svs[k] * w[(size_t)k * 6144];
    mod[g] = acc + mb[g];
}

// ---------------- LN + (1+sc)*x + sh, stream-select by global row ----------------
__global__ __launch_bounds__(256) void k_ln_mod1(const float* __restrict__ img,
                                                 const float* __restrict__ tmp,
                                                 const float* __restrict__ txt,
                                                 const float* __restrict__ mod,
                                                 float* __restrict__ xm) {
    int l = blockIdx.x;
    const float* src; int strm;
    if (l < L_TXT)              { src = txt + (size_t)l * DMODEL;            strm = 2; }
    else if (l < L_TXT + L_IMG) { src = img + (size_t)(l - L_TXT) * DMODEL;  strm = 0; }
    else                        { src = tmp + (size_t)(l - L_TXT - L_IMG) * DMODEL; strm = 1; }

    int d = threadIdx.x * 4;
    float4 x = *reinterpret_cast<const float4*>(src + d);
    float s  = x.x + x.y + x.z + x.w;
    float s2 = x.x*x.x + x.y*x.y + x.z*x.z + x.w*x.w;
#pragma unroll
    for (int o = 32; o > 0; o >>= 1) { s += __shfl_xor(s, o); s2 += __shfl_xor(s2, o); }
    __shared__ float red[8];
    int wave = threadIdx.x >> 6, lane = threadIdx.x & 63;
    if (lane == 0) { red[wave*2] = s; red[wave*2+1] = s2; }
    __syncthreads();
    if (threadIdx.x == 0) {
        float a = 0.f, b = 0.f;
        for (int w = 0; w < 4; w++) { a += red[w*2]; b += red[w*2+1]; }
        red[0] = a; red[1] = b;
    }
    __syncthreads();
    float mean = red[0] * (1.0f/DMODEL);
    float var  = red[1] * (1.0f/DMODEL) - mean*mean;
    float inv  = rsqrtf(var + EPSV);

    const float* sh = mod + strm*6144;
    const float* sc = sh + 1024;
    float4 shv = *reinterpret_cast<const float4*>(sh + d);
    float4 scv = *reinterpret_cast<const float4*>(sc + d);
    float4 o;
    o.x = (1.f+scv.x)*((x.x-mean)*inv) + shv.x;
    o.y = (1.f+scv.y)*((x.y-mean)*inv) + shv.y;
    o.z = (1.f+scv.z)*((x.z-mean)*inv) + shv.z;
    o.w = (1.f+scv.w)*((x.w-mean)*inv) + shv.w;
    *reinterpret_cast<float4*>(xm + (size_t)l*DMODEL + d) = o;
}

// ---------------- generic LN + modulate (explicit pointers) ----------------
__global__ __launch_bounds__(256) void k_ln_mod2(const float* __restrict__ src,
                                                 const float* __restrict__ sh,
                                                 const float* __restrict__ sc,
                                                 float* __restrict__ out) {
    int r = blockIdx.x;
    const float* srow = src + (size_t)r * DMODEL;
    int d = threadIdx.x * 4;
    float4 x = *reinterpret_cast<const float4*>(srow + d);
    float s  = x.x + x.y + x.z + x.w;
    float s2 = x.x*x.x + x.y*x.y + x.z*x.z + x.w*x.w;
#pragma unroll
    for (int o = 32; o > 0; o >>= 1) { s += __shfl_xor(s, o); s2 += __shfl_xor(s2, o); }
    __shared__ float red[8];
    int wave = threadIdx.x >> 6, lane = threadIdx.x & 63;
    if (lane == 0) { red[wave*2] = s; red[wave*2+1] = s2; }
    __syncthreads();
    if (threadIdx.x == 0) {
        float a = 0.f, b = 0.f;
        for (int w = 0; w < 4; w++) { a += red[w*2]; b += red[w*2+1]; }
        red[0] = a; red[1] = b;
    }
    __syncthreads();
    float mean = red[0] * (1.0f/DMODEL);
    float var  = red[1] * (1.0f/DMODEL) - mean*mean;
    float inv  = rsqrtf(var + EPSV);
    float4 shv = *reinterpret_cast<const float4*>(sh + d);
    float4 scv = *reinterpret_cast<const float4*>(sc + d);
    float4 o;
    o.x = (1.f+scv.x)*((x.x-mean)*inv) + shv.x;
    o.y = (1.f+scv.y)*((x.y-mean)*inv) + shv.y;
    o.z = (1.f+scv.z)*((x.z-mean)*inv) + shv.z;
    o.w = (1.f+scv.w)*((x.w-mean)*inv) + shv.w;
    *reinterpret_cast<float4*>(out + (size_t)r*DMODEL + d) = o;
}

// ---------------- tiled f32 GEMM, 64x64 tile, BK=16, epilogue modes ----------------
// MODE 0: C = A@W (+bias)     MODE 1: C = gelu(A@W+bias)    MODE 2: C = res + gate*(A@W+bias)
__device__ __forceinline__ float gelu_tanh(float x) {
    return 0.5f * x * (1.0f + tanhf(0.7978845608028654f * (x + 0.044715f * x * x * x)));
}

template<int MODE>
__global__ __launch_bounds__(256) void k_gemm(const float* __restrict__ A,
                                              const float* __restrict__ W,
                                              const float* __restrict__ bias,
                                              const float* __restrict__ res,
                                              const float* __restrict__ gate,
                                              float* __restrict__ C,
                                              int M, int N, int K) {
    __shared__ float As[16][68];
    __shared__ float Bs[16][68];
    const int tid = threadIdx.x;
    const int tx = tid & 15, ty = tid >> 4;
    const int bm = blockIdx.y * 64, bn = blockIdx.x * 64;

    const int am  = tid >> 2;         // 0..63
    const int ak  = (tid & 3) * 4;    // 0,4,8,12
    const int bk  = tid >> 4;         // 0..15
    const int bn4 = (tid & 15) * 4;   // 0..60

    float acc[4][4] = {};
    for (int k0 = 0; k0 < K; k0 += 16) {
        float4 a4 = *reinterpret_cast<const float4*>(A + (size_t)(bm + am) * K + k0 + ak);
        float4 b4 = *reinterpret_cast<const float4*>(W + (size_t)(k0 + bk) * N + bn + bn4);
        As[ak+0][am] = a4.x; As[ak+1][am] = a4.y; As[ak+2][am] = a4.z; As[ak+3][am] = a4.w;
        *reinterpret_cast<float4*>(&Bs[bk][bn4]) = b4;
        __syncthreads();
#pragma unroll
        for (int kk = 0; kk < 16; kk++) {
            float4 av = *reinterpret_cast<const float4*>(&As[kk][ty*4]);
            float4 bv = *reinterpret_cast<const float4*>(&Bs[kk][tx*4]);
            float a_[4] = {av.x, av.y, av.z, av.w};
            float b_[4] = {bv.x, bv.y, bv.z, bv.w};
#pragma unroll
            for (int i = 0; i < 4; i++)
#pragma unroll
                for (int j = 0; j < 4; j++)
                    acc[i][j] += a_[i] * b_[j];
        }
        __syncthreads();
    }
#pragma unroll
    for (int i = 0; i < 4; i++) {
        int row = bm + ty*4 + i;
#pragma unroll
        for (int j = 0; j < 4; j++) {
            int col = bn + tx*4 + j;
            float v = acc[i][j];
            if (bias) v += bias[col];
            if (MODE == 1) v = gelu_tanh(v);
            if (MODE == 2) v = res[(size_t)row * N + col] + gate[col] * v;
            C[(size_t)row * N + col] = v;
        }
    }
}

// ---------------- qkv finalize: RMS + RoPE + scatter to (H,L,HD); temporal-V bug ----------------
__global__ __launch_bounds__(256) void k_qkvfin(const float* __restrict__ qkv,
                                                const float* __restrict__ pe,
                                                const float* __restrict__ qs,
                                                const float* __restrict__ ks,
                                                float* __restrict__ Q,
                                                float* __restrict__ K,
                                                float* __restrict__ V) {
    int wid  = (blockIdx.x * 256 + threadIdx.x) >> 6;  // 0..36863
    int lane = threadIdx.x & 63;
    int l = wid >> 4;       // 0..2303  (global seq position)
    int h = wid & 15;
    int strm;
    if (l < L_TXT) strm = 2; else if (l < L_TXT + L_IMG) strm = 0; else strm = 1;

    const float* row = qkv + (size_t)l * 3 * DMODEL;
    float q = row[h*HDIM + lane];
    float k = row[DMODEL + h*HDIM + lane];
    float v = row[2*DMODEL + h*HDIM + lane];

    float sq = q*q, sk = k*k;
#pragma unroll
    for (int o = 32; o > 0; o >>= 1) { sq += __shfl_xor(sq, o); sk += __shfl_xor(sk, o); }
    float rq = q * rsqrtf(sq * (1.0f/HDIM) + EPSV) * qs[strm*HDIM + lane];
    float rk = k * rsqrtf(sk * (1.0f/HDIM) + EPSV) * ks[strm*HDIM + lane];

    // BUG replication: temporal stream's V is its RMS'd Q (pre-RoPE)
    float vout = (strm == 1) ? rq : v;

    // RoPE: y[2i+j] = pe[l,i,j,0]*x[2i] + pe[l,i,j,1]*x[2i+1]
    float rq_p = __shfl_xor(rq, 1);
    float rk_p = __shfl_xor(rk, 1);
    float qe = (lane & 1) ? rq_p : rq;
    float qo = (lane & 1) ? rq : rq_p;
    float ke = (lane & 1) ? rk_p : rk;
    float ko = (lane & 1) ? rk : rk_p;
    const float* pel = pe + (size_t)l*128 + (lane >> 1)*4 + (lane & 1)*2;
    float qr = pel[0]*qe + pel[1]*qo;
    float kr = pel[0]*ke + pel[1]*ko;

    size_t idx = ((size_t)h * LTOT + l) * HDIM + lane;
    Q[idx] = qr;
    K[idx] = kr;
    V[idx] = vout;
}

// ---------------- flash attention: 1 wave per 64-query tile, online softmax ----------------
__global__ __launch_bounds__(64) void k_attn(const float* __restrict__ Q,
                                             const float* __restrict__ Kg,
                                             const float* __restrict__ Vg,
                                             float* __restrict__ att) {
    int h  = blockIdx.x / (LTOT/64);
    int qt = blockIdx.x % (LTOT/64);
    int t  = threadIdx.x;
    int q  = qt*64 + t;

    const float* qrow = Q + ((size_t)h * LTOT + q) * HDIM;
    float qreg[64];
#pragma unroll
    for (int i = 0; i < 16; i++) {
        float4 x = *reinterpret_cast<const float4*>(qrow + i*4);
        qreg[i*4+0] = x.x; qreg[i*4+1] = x.y; qreg[i*4+2] = x.z; qreg[i*4+3] = x.w;
    }
    float o[64];
#pragma unroll
    for (int i = 0; i < 64; i++) o[i] = 0.f;
    float m = -1e30f, lsum = 0.f;

    __shared__ float Ks[64][64];
    __shared__ float Vs[64][64];
    for (int kt = 0; kt < LTOT/64; kt++) {
        __syncthreads();
        const float* kr = Kg + ((size_t)h * LTOT + kt*64 + t) * HDIM;
        const float* vr = Vg + ((size_t)h * LTOT + kt*64 + t) * HDIM;
#pragma unroll
        for (int i = 0; i < 16; i++) {
            *reinterpret_cast<float4*>(&Ks[t][i*4]) = *reinterpret_cast<const float4*>(kr + i*4);
            *reinterpret_cast<float4*>(&Vs[t][i*4]) = *reinterpret_cast<const float4*>(vr + i*4);
        }
        __syncthreads();
        for (int kk = 0; kk < 64; kk++) {
            float s = 0.f;
#pragma unroll
            for (int d = 0; d < 64; d++) s += qreg[d] * Ks[kk][d];
            s *= 0.125f;
            if (s <= m) {
                float p = __expf(s - m);
                lsum += p;
#pragma unroll
                for (int d = 0; d < 64; d++) o[d] += p * Vs[kk][d];
            } else {
                float c = __expf(m - s);
                lsum = lsum * c + 1.0f;
#pragma unroll
                for (int d = 0; d < 64; d++) o[d] = o[d]*c + Vs[kk][d];
                m = s;
            }
        }
    }
    float inv = 1.0f / lsum;
    float* orow = att + (size_t)q * DMODEL + h * HDIM;
#pragma unroll
    for (int i = 0; i < 16; i++) {
        float4 x;
        x.x = o[i*4+0]*inv; x.y = o[i*4+1]*inv; x.z = o[i*4+2]*inv; x.w = o[i*4+3]*inv;
        *reinterpret_cast<float4*>(orow + i*4) = x;
    }
}

// ---------------- launch ----------------
extern "C" void kernel_launch(void* const* d_in, const int* in_sizes, int n_in,
                              void* d_out, int out_size, void* d_ws, size_t ws_size,
                              hipStream_t stream) {
    const float* img  = (const float*)d_in[0];
    const float* tmp  = (const float*)d_in[1];
    const float* txt  = (const float*)d_in[2];
    const float* vec  = (const float*)d_in[3];
    const float* pe   = (const float*)d_in[4];
    const float* modw = (const float*)d_in[5];
    const float* modb = (const float*)d_in[6];
    const float* qkvw = (const float*)d_in[7];
    const float* qsc  = (const float*)d_in[8];
    const float* ksc  = (const float*)d_in[9];
    const float* projw= (const float*)d_in[10];
    const float* projb= (const float*)d_in[11];
    const float* w1   = (const float*)d_in[12];
    const float* b1   = (const float*)d_in[13];
    const float* w2   = (const float*)d_in[14];
    const float* b2   = (const float*)d_in[15];

    float* ws = (float*)d_ws;
    float* out_img = (float*)d_out;
    float* out_tmp = out_img + (size_t)L_IMG * DMODEL;
    float* out_txt = out_tmp + (size_t)L_TMP * DMODEL;

    float* sv   = ws + WS_SV;
    float* mod  = ws + WS_MOD;
    float* xm   = ws + WS_XM;
    float* qkv  = ws + WS_QKV;
    float* Qb   = ws + WS_Q;
    float* Kb   = ws + WS_K;
    float* Vb   = ws + WS_V;
    float* att  = ws + WS_ATT;
    float* s1   = ws + WS_S1;
    float* hbuf = ws + WS_H;
    float* t1   = ws + WS_T1;

    // 1. silu + mod vectors
    k_silu<<<4, 256, 0, stream>>>(vec, sv);
    k_mod<<<72, 256, 0, stream>>>(sv, modw, modb, mod);

    // 2. LN+mod1 (global row order: txt, img, tmp)
    k_ln_mod1<<<LTOT, 256, 0, stream>>>(img, tmp, txt, mod, xm);

    // 3. QKV GEMMs (per stream, stream weight index: img=0, tmp=1, txt=2)
    k_gemm<0><<<dim3(48, 4),  256, 0, stream>>>(xm,                 qkvw + (size_t)2*DMODEL*3072, nullptr, nullptr, nullptr, qkv,                 L_TXT, 3072, DMODEL);
    k_gemm<0><<<dim3(48, 16), 256, 0, stream>>>(xm + (size_t)256*DMODEL,  qkvw,                   nullptr, nullptr, nullptr, qkv + (size_t)256*3072,  L_IMG, 3072, DMODEL);
    k_gemm<0><<<dim3(48, 16), 256, 0, stream>>>(xm + (size_t)1280*DMODEL, qkvw + (size_t)1*DMODEL*3072, nullptr, nullptr, nullptr, qkv + (size_t)1280*3072, L_TMP, 3072, DMODEL);

    // 4. RMS + RoPE + scatter (+ temporal-V=Q bug)
    k_qkvfin<<<9216, 256, 0, stream>>>(qkv, pe, qsc, ksc, Qb, Kb, Vb);

    // 5. attention
    k_attn<<<NH * (LTOT/64), 64, 0, stream>>>(Qb, Kb, Vb, att);

    // 6. proj + residual + gate1  -> s1 (global row order)
    k_gemm<2><<<dim3(16, 16), 256, 0, stream>>>(att + (size_t)256*DMODEL,  projw,                       projb,        img, mod + 0*6144 + 2*1024, s1 + (size_t)256*DMODEL,  L_IMG, DMODEL, DMODEL);
    k_gemm<2><<<dim3(16, 16), 256, 0, stream>>>(att + (size_t)1280*DMODEL, projw + (size_t)1*DMODEL*DMODEL, projb + DMODEL, tmp, mod + 1*6144 + 2*1024, s1 + (size_t)1280*DMODEL, L_TMP, DMODEL, DMODEL);
    k_gemm<2><<<dim3(16, 4),  256, 0, stream>>>(att,                       projw + (size_t)2*DMODEL*DMODEL, projb + 2*DMODEL, txt, mod + 2*6144 + 2*1024, s1,                      L_TXT, DMODEL, DMODEL);

    // 7. img MLP -> out_img
    k_ln_mod2<<<L_IMG, 256, 0, stream>>>(s1 + (size_t)256*DMODEL, mod + 0*6144 + 3*1024, mod + 0*6144 + 4*1024, hbuf);
    k_gemm<1><<<dim3(64, 16), 256, 0, stream>>>(hbuf, w1, b1, nullptr, nullptr, t1, L_IMG, DMLP, DMODEL);
    k_gemm<2><<<dim3(16, 16), 256, 0, stream>>>(t1, w2, b2, s1 + (size_t)256*DMODEL, mod + 0*6144 + 5*1024, out_img, L_IMG, DMODEL, DMLP);

    // 8. temporal MLP (LN input is FINAL img — reference quirk) -> out_tmp
    k_ln_mod2<<<L_TMP, 256, 0, stream>>>(out_img, mod + 1*6144 + 3*1024, mod + 1*6144 + 4*1024, hbuf);
    k_gemm<1><<<dim3(64, 16), 256, 0, stream>>>(hbuf, w1 + (size_t)1*DMODEL*DMLP, b1 + DMLP, nullptr, nullptr, t1, L_TMP, DMLP, DMODEL);
    k_gemm<2><<<dim3(16, 16), 256, 0, stream>>>(t1, w2 + (size_t)1*DMLP*DMODEL, b2 + DMODEL, s1 + (size_t)1280*DMODEL, mod + 1*6144 + 5*1024, out_tmp, L_TMP, DMODEL, DMLP);

    // 9. txt MLP -> out_txt
    k_ln_mod2<<<L_TXT, 256, 0, stream>>>(s1, mod + 2*6144 + 3*1024, mod + 2*6144 + 4*1024, hbuf);
    k_gemm<1><<<dim3(64, 4), 256, 0, stream>>>(hbuf, w1 + (size_t)2*DMODEL*DMLP, b1 + 2*DMLP, nullptr, nullptr, t1, L_TXT, DMLP, DMODEL);
    k_gemm<2><<<dim3(16, 4), 256, 0, stream>>>(t1, w2 + (size_t)2*DMLP*DMODEL, b2 + 2*DMODEL, s1, mod + 2*6144 + 5*1024, out_txt, L_TXT, DMODEL, DMLP);
}

// Round 2
// 1945.984 us; speedup vs baseline: 1.7181x; 1.7181x over previous
//
#include <hip/hip_runtime.h>
#include <hip/hip_bf16.h>

#define L_TXT 256
#define L_IMG 1024
#define L_TMP 1024
#define LTOT  2304
#define DMODEL 1024
#define NH 16
#define HDIM 64
#define DMLP 4096
#define EPSV 1e-6f

typedef unsigned short ushort;
typedef __attribute__((ext_vector_type(8))) short short8b;   // 8 x bf16
typedef __attribute__((ext_vector_type(4))) float f32x4;
typedef __attribute__((ext_vector_type(4))) unsigned short ushort4v;

// workspace offsets (in floats)
#define WS_SV   0
#define WS_MOD  1024
#define WS_XM   32768
#define WS_QKV  (WS_XM  + LTOT*DMODEL)
#define WS_Q    (WS_QKV + LTOT*3*DMODEL)        // bf16 Q  [H][L][64]  (region sized for f32, half used)
#define WS_K    (WS_Q   + NH*LTOT*HDIM)         // bf16 K  [H][L][64]
#define WS_V    (WS_K   + NH*LTOT*HDIM)         // bf16 V^T [H][64][L]
#define WS_ATT  (WS_V   + NH*LTOT*HDIM)
#define WS_S1   (WS_ATT + LTOT*DMODEL)
#define WS_H    (WS_S1  + LTOT*DMODEL)
#define WS_T1   (WS_H   + L_IMG*DMODEL)

static __device__ __forceinline__ ushort f2bf(float x) {
    __hip_bfloat16 b = __float2bfloat16(x);
    return *reinterpret_cast<ushort*>(&b);
}

// ---------------- silu(vec) ----------------
__global__ void k_silu(const float* __restrict__ vec, float* __restrict__ sv) {
    int i = blockIdx.x * 256 + threadIdx.x;
    if (i < DMODEL) {
        float v = vec[i];
        sv[i] = v / (1.0f + __expf(-v));
    }
}

// ---------------- mod GEMV ----------------
__global__ __launch_bounds__(256) void k_mod(const float* __restrict__ sv,
                                             const float* __restrict__ mw,
                                             const float* __restrict__ mb,
                                             float* __restrict__ mod) {
    __shared__ float svs[DMODEL];
    for (int i = threadIdx.x; i < DMODEL; i += 256) svs[i] = sv[i];
    __syncthreads();
    int g = blockIdx.x * 256 + threadIdx.x;
    int i = g / 6144;
    int j = g - i * 6144;
    const float* w = mw + (size_t)i * DMODEL * 6144 + j;
    float acc = 0.f;
#pragma unroll 4
    for (int k = 0; k < DMODEL; k++) acc += svs[k] * w[(size_t)k * 6144];
    mod[g] = acc + mb[g];
}

// ---------------- LN + (1+sc)*x + sh, stream-select ----------------
__global__ __launch_bounds__(256) void k_ln_mod1(const float* __restrict__ img,
                                                 const float* __restrict__ tmp,
                                                 const float* __restrict__ txt,
                                                 const float* __restrict__ mod,
                                                 float* __restrict__ xm) {
    int l = blockIdx.x;
    const float* src; int strm;
    if (l < L_TXT)              { src = txt + (size_t)l * DMODEL;            strm = 2; }
    else if (l < L_TXT + L_IMG) { src = img + (size_t)(l - L_TXT) * DMODEL;  strm = 0; }
    else                        { src = tmp + (size_t)(l - L_TXT - L_IMG) * DMODEL; strm = 1; }

    int d = threadIdx.x * 4;
    float4 x = *reinterpret_cast<const float4*>(src + d);
    float s  = x.x + x.y + x.z + x.w;
    float s2 = x.x*x.x + x.y*x.y + x.z*x.z + x.w*x.w;
#pragma unroll
    for (int o = 32; o > 0; o >>= 1) { s += __shfl_xor(s, o); s2 += __shfl_xor(s2, o); }
    __shared__ float red[8];
    int wave = threadIdx.x >> 6, lane = threadIdx.x & 63;
    if (lane == 0) { red[wave*2] = s; red[wave*2+1] = s2; }
    __syncthreads();
    if (threadIdx.x == 0) {
        float a = 0.f, b = 0.f;
        for (int w = 0; w < 4; w++) { a += red[w*2]; b += red[w*2+1]; }
        red[0] = a; red[1] = b;
    }
    __syncthreads();
    float mean = red[0] * (1.0f/DMODEL);
    float var  = red[1] * (1.0f/DMODEL) - mean*mean;
    float inv  = rsqrtf(var + EPSV);

    const float* sh = mod + strm*6144;
    const float* sc = sh + 1024;
    float4 shv = *reinterpret_cast<const float4*>(sh + d);
    float4 scv = *reinterpret_cast<const float4*>(sc + d);
    float4 o;
    o.x = (1.f+scv.x)*((x.x-mean)*inv) + shv.x;
    o.y = (1.f+scv.y)*((x.y-mean)*inv) + shv.y;
    o.z = (1.f+scv.z)*((x.z-mean)*inv) + shv.z;
    o.w = (1.f+scv.w)*((x.w-mean)*inv) + shv.w;
    *reinterpret_cast<float4*>(xm + (size_t)l*DMODEL + d) = o;
}

// ---------------- generic LN + modulate ----------------
__global__ __launch_bounds__(256) void k_ln_mod2(const float* __restrict__ src,
                                                 const float* __restrict__ sh,
                                                 const float* __restrict__ sc,
                                                 float* __restrict__ out) {
    int r = blockIdx.x;
    const float* srow = src + (size_t)r * DMODEL;
    int d = threadIdx.x * 4;
    float4 x = *reinterpret_cast<const float4*>(srow + d);
    float s  = x.x + x.y + x.z + x.w;
    float s2 = x.x*x.x + x.y*x.y + x.z*x.z + x.w*x.w;
#pragma unroll
    for (int o = 32; o > 0; o >>= 1) { s += __shfl_xor(s, o); s2 += __shfl_xor(s2, o); }
    __shared__ float red[8];
    int wave = threadIdx.x >> 6, lane = threadIdx.x & 63;
    if (lane == 0) { red[wave*2] = s; red[wave*2+1] = s2; }
    __syncthreads();
    if (threadIdx.x == 0) {
        float a = 0.f, b = 0.f;
        for (int w = 0; w < 4; w++) { a += red[w*2]; b += red[w*2+1]; }
        red[0] = a; red[1] = b;
    }
    __syncthreads();
    float mean = red[0] * (1.0f/DMODEL);
    float var  = red[1] * (1.0f/DMODEL) - mean*mean;
    float inv  = rsqrtf(var + EPSV);
    float4 shv = *reinterpret_cast<const float4*>(sh + d);
    float4 scv = *reinterpret_cast<const float4*>(sc + d);
    float4 o;
    o.x = (1.f+scv.x)*((x.x-mean)*inv) + shv.x;
    o.y = (1.f+scv.y)*((x.y-mean)*inv) + shv.y;
    o.z = (1.f+scv.z)*((x.z-mean)*inv) + shv.z;
    o.w = (1.f+scv.w)*((x.w-mean)*inv) + shv.w;
    *reinterpret_cast<float4*>(out + (size_t)r*DMODEL + d) = o;
}

// ---------------- tiled f32 GEMM ----------------
__device__ __forceinline__ float gelu_tanh(float x) {
    return 0.5f * x * (1.0f + tanhf(0.7978845608028654f * (x + 0.044715f * x * x * x)));
}

template<int MODE>
__global__ __launch_bounds__(256) void k_gemm(const float* __restrict__ A,
                                              const float* __restrict__ W,
                                              const float* __restrict__ bias,
                                              const float* __restrict__ res,
                                              const float* __restrict__ gate,
                                              float* __restrict__ C,
                                              int M, int N, int K) {
    __shared__ float As[16][68];
    __shared__ float Bs[16][68];
    const int tid = threadIdx.x;
    const int tx = tid & 15, ty = tid >> 4;
    const int bm = blockIdx.y * 64, bn = blockIdx.x * 64;

    const int am  = tid >> 2;
    const int ak  = (tid & 3) * 4;
    const int bk  = tid >> 4;
    const int bn4 = (tid & 15) * 4;

    float acc[4][4] = {};
    for (int k0 = 0; k0 < K; k0 += 16) {
        float4 a4 = *reinterpret_cast<const float4*>(A + (size_t)(bm + am) * K + k0 + ak);
        float4 b4 = *reinterpret_cast<const float4*>(W + (size_t)(k0 + bk) * N + bn + bn4);
        As[ak+0][am] = a4.x; As[ak+1][am] = a4.y; As[ak+2][am] = a4.z; As[ak+3][am] = a4.w;
        *reinterpret_cast<float4*>(&Bs[bk][bn4]) = b4;
        __syncthreads();
#pragma unroll
        for (int kk = 0; kk < 16; kk++) {
            float4 av = *reinterpret_cast<const float4*>(&As[kk][ty*4]);
            float4 bv = *reinterpret_cast<const float4*>(&Bs[kk][tx*4]);
            float a_[4] = {av.x, av.y, av.z, av.w};
            float b_[4] = {bv.x, bv.y, bv.z, bv.w};
#pragma unroll
            for (int i = 0; i < 4; i++)
#pragma unroll
                for (int j = 0; j < 4; j++)
                    acc[i][j] += a_[i] * b_[j];
        }
        __syncthreads();
    }
#pragma unroll
    for (int i = 0; i < 4; i++) {
        int row = bm + ty*4 + i;
#pragma unroll
        for (int j = 0; j < 4; j++) {
            int col = bn + tx*4 + j;
            float v = acc[i][j];
            if (bias) v += bias[col];
            if (MODE == 1) v = gelu_tanh(v);
            if (MODE == 2) v = res[(size_t)row * N + col] + gate[col] * v;
            C[(size_t)row * N + col] = v;
        }
    }
}

// ---------------- qkv finalize: RMS + RoPE -> bf16 Q,K [H][L][64], V^T [H][64][L] ----------------
__global__ __launch_bounds__(256) void k_qkvfin(const float* __restrict__ qkv,
                                                const float* __restrict__ pe,
                                                const float* __restrict__ qs,
                                                const float* __restrict__ ks,
                                                ushort* __restrict__ Q,
                                                ushort* __restrict__ K,
                                                ushort* __restrict__ VT) {
    int wid  = (blockIdx.x * 256 + threadIdx.x) >> 6;
    int lane = threadIdx.x & 63;
    int l = wid >> 4;
    int h = wid & 15;
    int strm;
    if (l < L_TXT) strm = 2; else if (l < L_TXT + L_IMG) strm = 0; else strm = 1;

    const float* row = qkv + (size_t)l * 3 * DMODEL;
    float q = row[h*HDIM + lane];
    float k = row[DMODEL + h*HDIM + lane];
    float v = row[2*DMODEL + h*HDIM + lane];

    float sq = q*q, sk = k*k;
#pragma unroll
    for (int o = 32; o > 0; o >>= 1) { sq += __shfl_xor(sq, o); sk += __shfl_xor(sk, o); }
    float rq = q * rsqrtf(sq * (1.0f/HDIM) + EPSV) * qs[strm*HDIM + lane];
    float rk = k * rsqrtf(sk * (1.0f/HDIM) + EPSV) * ks[strm*HDIM + lane];

    // BUG replication: temporal stream's V is its RMS'd Q (pre-RoPE)
    float vout = (strm == 1) ? rq : v;

    float rq_p = __shfl_xor(rq, 1);
    float rk_p = __shfl_xor(rk, 1);
    float qe = (lane & 1) ? rq_p : rq;
    float qo = (lane & 1) ? rq : rq_p;
    float ke = (lane & 1) ? rk_p : rk;
    float ko = (lane & 1) ? rk : rk_p;
    const float* pel = pe + (size_t)l*128 + (lane >> 1)*4 + (lane & 1)*2;
    float qr = pel[0]*qe + pel[1]*qo;
    float kr = pel[0]*ke + pel[1]*ko;

    size_t idx = ((size_t)h * LTOT + l) * HDIM + lane;
    Q[idx] = f2bf(qr);
    K[idx] = f2bf(kr);
    VT[((size_t)h * HDIM + lane) * LTOT + l] = f2bf(vout);
}

// ---------------- MFMA flash attention ----------------
// 1 wave per 16-query strip. S^T = mfma(K_frag, Q_frag); online softmax per q-column
// (in-register + shfl_xor 16/32); P via wave-private swizzled LDS; PV^T = mfma(V^T_frag, P_frag).
__global__ __launch_bounds__(256) void k_attn_mfma(const ushort* __restrict__ Qb,
                                                   const ushort* __restrict__ Kb,
                                                   const ushort* __restrict__ VTb,
                                                   float* __restrict__ att) {
    const int w = threadIdx.x >> 6, lane = threadIdx.x & 63;
    const int strip = blockIdx.x * 4 + w;           // 0..2303
    const int h  = strip / 144;
    const int qt = strip % 144;
    const int qbase = qt * 16;
    const int g = lane >> 4;        // row-group 0..3
    const int q = lane & 15;        // q column (also d_local for PV A-frag)

    __shared__ ushort plds[4][1024];                // per-wave 16x64 bf16 P tile, swizzled
    ushort* P = plds[w];

    // Q B-frags (persistent): lane holds Q[qbase+q][df*32 + g*8 .. +8]
    const ushort* qp = Qb + ((size_t)h * LTOT + qbase + q) * 64 + g*8;
    const short8b qf0 = *reinterpret_cast<const short8b*>(qp);
    const short8b qf1 = *reinterpret_cast<const short8b*>(qp + 32);

    f32x4 out[4];
#pragma unroll
    for (int d = 0; d < 4; d++) out[d] = (f32x4){0.f,0.f,0.f,0.f};
    float m = -1e30f, lsum = 0.f;

    for (int kv0 = 0; kv0 < LTOT; kv0 += 64) {
        // ---- S^T tile: 4 sub-tiles of 16kv x 16q ----
        f32x4 s[4];
        const ushort* kbase = Kb + ((size_t)h * LTOT + kv0 + q) * 64 + g*8;
#pragma unroll
        for (int ks = 0; ks < 4; ks++) {
            short8b kf0 = *reinterpret_cast<const short8b*>(kbase + ks*16*64);
            short8b kf1 = *reinterpret_cast<const short8b*>(kbase + ks*16*64 + 32);
            f32x4 acc = (f32x4){0.f,0.f,0.f,0.f};
            acc = __builtin_amdgcn_mfma_f32_16x16x32_bf16(kf0, qf0, acc, 0, 0, 0);
            acc = __builtin_amdgcn_mfma_f32_16x16x32_bf16(kf1, qf1, acc, 0, 0, 0);
            s[ks] = acc;
        }
        // ---- online softmax along kv (rows) for this lane's q column ----
        float tmax = -1e30f;
#pragma unroll
        for (int ks = 0; ks < 4; ks++)
#pragma unroll
            for (int r = 0; r < 4; r++) tmax = fmaxf(tmax, s[ks][r]);
        tmax = fmaxf(tmax, __shfl_xor(tmax, 16));
        tmax = fmaxf(tmax, __shfl_xor(tmax, 32));
        float newm = fmaxf(m, tmax * 0.125f);
        float c = __expf(m - newm);
        float p[16];
        float tsum = 0.f;
#pragma unroll
        for (int ks = 0; ks < 4; ks++)
#pragma unroll
            for (int r = 0; r < 4; r++) {
                float pv = __expf(s[ks][r] * 0.125f - newm);
                p[ks*4+r] = pv;
                tsum += pv;
            }
        tsum += __shfl_xor(tsum, 16);
        tsum += __shfl_xor(tsum, 32);
        lsum = lsum * c + tsum;
        m = newm;
#pragma unroll
        for (int d = 0; d < 4; d++) out[d] *= c;

        // ---- P -> bf16 -> wave-private LDS as [q][kv], XOR-swizzled ----
#pragma unroll
        for (int ks = 0; ks < 4; ks++) {
            ushort4v pk;
            pk.x = f2bf(p[ks*4+0]); pk.y = f2bf(p[ks*4+1]);
            pk.z = f2bf(p[ks*4+2]); pk.w = f2bf(p[ks*4+3]);
            int widx = (q*64 + ks*16 + g*4) ^ ((q & 7) << 3);
            *reinterpret_cast<ushort4v*>(&P[widx]) = pk;
        }
        // ---- PV^T: out^T[d][q] += V^T[d][kv] * P^T[kv][q] ----
#pragma unroll
        for (int c2 = 0; c2 < 2; c2++) {
            int ridx = (q*64 + c2*32 + g*8) ^ ((q & 7) << 3);
            short8b pf = *reinterpret_cast<const short8b*>(&P[ridx]);
#pragma unroll
            for (int ds = 0; ds < 4; ds++) {
                short8b vf = *reinterpret_cast<const short8b*>(
                    VTb + ((size_t)h * 64 + ds*16 + q) * LTOT + kv0 + c2*32 + g*8);
                out[ds] = __builtin_amdgcn_mfma_f32_16x16x32_bf16(vf, pf, out[ds], 0, 0, 0);
            }
        }
    }

    float inv = 1.0f / lsum;
    float* orow = att + (size_t)(qbase + q) * DMODEL + h * HDIM;
#pragma unroll
    for (int ds = 0; ds < 4; ds++) {
        float4 o4;
        o4.x = out[ds][0]*inv; o4.y = out[ds][1]*inv;
        o4.z = out[ds][2]*inv; o4.w = out[ds][3]*inv;
        *reinterpret_cast<float4*>(orow + ds*16 + g*4) = o4;
    }
}

// ---------------- launch ----------------
extern "C" void kernel_launch(void* const* d_in, const int* in_sizes, int n_in,
                              void* d_out, int out_size, void* d_ws, size_t ws_size,
                              hipStream_t stream) {
    const float* img  = (const float*)d_in[0];
    const float* tmp  = (const float*)d_in[1];
    const float* txt  = (const float*)d_in[2];
    const float* vec  = (const float*)d_in[3];
    const float* pe   = (const float*)d_in[4];
    const float* modw = (const float*)d_in[5];
    const float* modb = (const float*)d_in[6];
    const float* qkvw = (const float*)d_in[7];
    const float* qsc  = (const float*)d_in[8];
    const float* ksc  = (const float*)d_in[9];
    const float* projw= (const float*)d_in[10];
    const float* projb= (const float*)d_in[11];
    const float* w1   = (const float*)d_in[12];
    const float* b1   = (const float*)d_in[13];
    const float* w2   = (const float*)d_in[14];
    const float* b2   = (const float*)d_in[15];

    float* ws = (float*)d_ws;
    float* out_img = (float*)d_out;
    float* out_tmp = out_img + (size_t)L_IMG * DMODEL;
    float* out_txt = out_tmp + (size_t)L_TMP * DMODEL;

    float* sv   = ws + WS_SV;
    float* mod  = ws + WS_MOD;
    float* xm   = ws + WS_XM;
    float* qkv  = ws + WS_QKV;
    ushort* Qb  = (ushort*)(ws + WS_Q);
    ushort* Kb  = (ushort*)(ws + WS_K);
    ushort* VTb = (ushort*)(ws + WS_V);
    float* att  = ws + WS_ATT;
    float* s1   = ws + WS_S1;
    float* hbuf = ws + WS_H;
    float* t1   = ws + WS_T1;

    k_silu<<<4, 256, 0, stream>>>(vec, sv);
    k_mod<<<72, 256, 0, stream>>>(sv, modw, modb, mod);

    k_ln_mod1<<<LTOT, 256, 0, stream>>>(img, tmp, txt, mod, xm);

    k_gemm<0><<<dim3(48, 4),  256, 0, stream>>>(xm,                 qkvw + (size_t)2*DMODEL*3072, nullptr, nullptr, nullptr, qkv,                 L_TXT, 3072, DMODEL);
    k_gemm<0><<<dim3(48, 16), 256, 0, stream>>>(xm + (size_t)256*DMODEL,  qkvw,                   nullptr, nullptr, nullptr, qkv + (size_t)256*3072,  L_IMG, 3072, DMODEL);
    k_gemm<0><<<dim3(48, 16), 256, 0, stream>>>(xm + (size_t)1280*DMODEL, qkvw + (size_t)1*DMODEL*3072, nullptr, nullptr, nullptr, qkv + (size_t)1280*3072, L_TMP, 3072, DMODEL);

    k_qkvfin<<<9216, 256, 0, stream>>>(qkv, pe, qsc, ksc, Qb, Kb, VTb);

    k_attn_mfma<<<576, 256, 0, stream>>>(Qb, Kb, VTb, att);

    k_gemm<2><<<dim3(16, 16), 256, 0, stream>>>(att + (size_t)256*DMODEL,  projw,                       projb,        img, mod + 0*6144 + 2*1024, s1 + (size_t)256*DMODEL,  L_IMG, DMODEL, DMODEL);
    k_gemm<2><<<dim3(16, 16), 256, 0, stream>>>(att + (size_t)1280*DMODEL, projw + (size_t)1*DMODEL*DMODEL, projb + DMODEL, tmp, mod + 1*6144 + 2*1024, s1 + (size_t)1280*DMODEL, L_TMP, DMODEL, DMODEL);
    k_gemm<2><<<dim3(16, 4),  256, 0, stream>>>(att,                       projw + (size_t)2*DMODEL*DMODEL, projb + 2*DMODEL, txt, mod + 2*6144 + 2*1024, s1,                      L_TXT, DMODEL, DMODEL);

    k_ln_mod2<<<L_IMG, 256, 0, stream>>>(s1 + (size_t)256*DMODEL, mod + 0*6144 + 3*1024, mod + 0*6144 + 4*1024, hbuf);
    k_gemm<1><<<dim3(64, 16), 256, 0, stream>>>(hbuf, w1, b1, nullptr, nullptr, t1, L_IMG, DMLP, DMODEL);
    k_gemm<2><<<dim3(16, 16), 256, 0, stream>>>(t1, w2, b2, s1 + (size_t)256*DMODEL, mod + 0*6144 + 5*1024, out_img, L_IMG, DMODEL, DMLP);

    k_ln_mod2<<<L_TMP, 256, 0, stream>>>(out_img, mod + 1*6144 + 3*1024, mod + 1*6144 + 4*1024, hbuf);
    k_gemm<1><<<dim3(64, 16), 256, 0, stream>>>(hbuf, w1 + (size_t)1*DMODEL*DMLP, b1 + DMLP, nullptr, nullptr, t1, L_TMP, DMLP, DMODEL);
    k_gemm<2><<<dim3(16, 16), 256, 0, stream>>>(t1, w2 + (size_t)1*DMLP*DMODEL, b2 + DMODEL, s1 + (size_t)1280*DMODEL, mod + 1*6144 + 5*1024, out_tmp, L_TMP, DMODEL, DMLP);

    k_ln_mod2<<<L_TXT, 256, 0, stream>>>(s1, mod + 2*6144 + 3*1024, mod + 2*6144 + 4*1024, hbuf);
    k_gemm<1><<<dim3(64, 4), 256, 0, stream>>>(hbuf, w1 + (size_t)2*DMODEL*DMLP, b1 + 2*DMLP, nullptr, nullptr, t1, L_TXT, DMLP, DMODEL);
    k_gemm<2><<<dim3(16, 4), 256, 0, stream>>>(t1, w2 + (size_t)2*DMLP*DMODEL, b2 + 2*DMODEL, s1, mod + 2*6144 + 5*1024, out_txt, L_TXT, DMODEL, DMLP);
}

// Round 3
// 845.555 us; speedup vs baseline: 3.9540x; 2.3014x over previous
//
#include <hip/hip_runtime.h>
#include <hip/hip_bf16.h>

#define L_TXT 256
#define L_IMG 1024
#define L_TMP 1024
#define LTOT  2304
#define DMODEL 1024
#define NH 16
#define HDIM 64
#define DMLP 4096
#define EPSV 1e-6f

typedef unsigned short ushort;
typedef __attribute__((ext_vector_type(8))) short short8b;   // 8 x bf16
typedef __attribute__((ext_vector_type(4))) float f32x4;
typedef __attribute__((ext_vector_type(4))) unsigned short ushort4v;

// ---- workspace layout (bytes) ----
#define MOD_OFF    ((size_t)0)                       // f32 3*6144
#define XM_OFF     ((size_t)73728)                   // bf16 2304*1024
#define QKV_OFF    ((size_t)4792320)                 // bf16 2304*3072  (t1 overlays)
#define QB_OFF     ((size_t)18948096)                // bf16 16*2304*64 (w2t slice overlays QB+KB)
#define KB_OFF     ((size_t)23666688)
#define VTB_OFF    ((size_t)28385280)
#define ATT_OFF    ((size_t)33103872)                // bf16 2304*1024
#define S1_OFF     ((size_t)37822464)                // f32 2304*1024
#define HBUF_OFF   ((size_t)47259648)                // bf16 1024*1024
#define QKVWT_OFF  ((size_t)49356800)                // bf16 3*3072*1024
#define PROJWT_OFF ((size_t)68231168)                // bf16 3*1024*1024
#define W1T_OFF    ((size_t)74522624)                // bf16 3*4096*1024
// end ~ 99.7 MB

static __device__ __forceinline__ ushort f2bf(float x) {
    __hip_bfloat16 b = __float2bfloat16(x);
    return *reinterpret_cast<ushort*>(&b);
}
static __device__ __forceinline__ float bf2f(ushort u) {
    return __uint_as_float(((unsigned)u) << 16);
}

typedef __attribute__((address_space(1))) const unsigned char gas_t;
typedef __attribute__((address_space(3))) unsigned char las_t;
static __device__ __forceinline__ void gload16(const void* g, void* l) {
    __builtin_amdgcn_global_load_lds((gas_t*)g, (las_t*)l, 16, 0, 0);
}

// ---------------- mod GEMV (silu fused) ----------------
__global__ __launch_bounds__(256) void k_mod(const float* __restrict__ vec,
                                             const float* __restrict__ mw,
                                             const float* __restrict__ mb,
                                             float* __restrict__ mod) {
    __shared__ float svs[DMODEL];
    for (int i = threadIdx.x; i < DMODEL; i += 256) {
        float v = vec[i];
        svs[i] = v / (1.0f + __expf(-v));
    }
    __syncthreads();
    int g = blockIdx.x * 256 + threadIdx.x;
    int i = g / 6144;
    int j = g - i * 6144;
    const float* w = mw + (size_t)i * DMODEL * 6144 + j;
    float acc = 0.f;
#pragma unroll 4
    for (int k = 0; k < DMODEL; k++) acc += svs[k] * w[(size_t)k * 6144];
    mod[g] = acc + mb[g];
}

// ---------------- weight transpose-convert: f32 [K][N] -> bf16 [N][K] ----------------
__global__ __launch_bounds__(256) void k_wt_all(const float* __restrict__ qkvw,
                                                const float* __restrict__ projw,
                                                const float* __restrict__ w1,
                                                ushort* __restrict__ qkvwt,
                                                ushort* __restrict__ projwt,
                                                ushort* __restrict__ w1t) {
    int bid = blockIdx.x;
    const float* W; ushort* WT; int K, N;
    if (bid < 9216) {
        int s = bid / 3072, r = bid % 3072;
        K = 1024; N = 3072;
        W = qkvw + (size_t)s * K * N; WT = qkvwt + (size_t)s * N * K;
        bid = r;
    } else if (bid < 12288) {
        int b = bid - 9216; int s = b / 1024, r = b % 1024;
        K = 1024; N = 1024;
        W = projw + (size_t)s * K * N; WT = projwt + (size_t)s * N * K;
        bid = r;
    } else {
        int b = bid - 12288; int s = b / 4096, r = b % 4096;
        K = 1024; N = 4096;
        W = w1 + (size_t)s * K * N; WT = w1t + (size_t)s * N * K;
        bid = r;
    }
    int nt = bid % (N >> 5), kt = bid / (N >> 5);
    __shared__ float tb[32][33];
    int r = threadIdx.x >> 5, c = threadIdx.x & 31;
#pragma unroll
    for (int i = 0; i < 4; i++)
        tb[r + i*8][c] = W[(size_t)(kt*32 + r + i*8) * N + nt*32 + c];
    __syncthreads();
#pragma unroll
    for (int i = 0; i < 4; i++)
        WT[(size_t)(nt*32 + r + i*8) * K + kt*32 + c] = f2bf(tb[c][r + i*8]);
}

__global__ __launch_bounds__(256) void k_wt_slice(const float* __restrict__ W,
                                                  ushort* __restrict__ WT,
                                                  int K, int N) {
    int nt = blockIdx.x, kt = blockIdx.y;
    __shared__ float tb[32][33];
    int r = threadIdx.x >> 5, c = threadIdx.x & 31;
#pragma unroll
    for (int i = 0; i < 4; i++)
        tb[r + i*8][c] = W[(size_t)(kt*32 + r + i*8) * N + nt*32 + c];
    __syncthreads();
#pragma unroll
    for (int i = 0; i < 4; i++)
        WT[(size_t)(nt*32 + r + i*8) * K + kt*32 + c] = f2bf(tb[c][r + i*8]);
}

// ---------------- LN + (1+sc)*x + sh -> bf16, stream-select ----------------
__global__ __launch_bounds__(256) void k_ln_mod1(const float* __restrict__ img,
                                                 const float* __restrict__ tmp,
                                                 const float* __restrict__ txt,
                                                 const float* __restrict__ mod,
                                                 ushort* __restrict__ xm) {
    int l = blockIdx.x;
    const float* src; int strm;
    if (l < L_TXT)              { src = txt + (size_t)l * DMODEL;            strm = 2; }
    else if (l < L_TXT + L_IMG) { src = img + (size_t)(l - L_TXT) * DMODEL;  strm = 0; }
    else                        { src = tmp + (size_t)(l - L_TXT - L_IMG) * DMODEL; strm = 1; }

    int d = threadIdx.x * 4;
    float4 x = *reinterpret_cast<const float4*>(src + d);
    float s  = x.x + x.y + x.z + x.w;
    float s2 = x.x*x.x + x.y*x.y + x.z*x.z + x.w*x.w;
#pragma unroll
    for (int o = 32; o > 0; o >>= 1) { s += __shfl_xor(s, o); s2 += __shfl_xor(s2, o); }
    __shared__ float red[8];
    int wave = threadIdx.x >> 6, lane = threadIdx.x & 63;
    if (lane == 0) { red[wave*2] = s; red[wave*2+1] = s2; }
    __syncthreads();
    if (threadIdx.x == 0) {
        float a = 0.f, b = 0.f;
        for (int w = 0; w < 4; w++) { a += red[w*2]; b += red[w*2+1]; }
        red[0] = a; red[1] = b;
    }
    __syncthreads();
    float mean = red[0] * (1.0f/DMODEL);
    float var  = red[1] * (1.0f/DMODEL) - mean*mean;
    float inv  = rsqrtf(var + EPSV);

    const float* sh = mod + strm*6144;
    const float* sc = sh + 1024;
    float4 shv = *reinterpret_cast<const float4*>(sh + d);
    float4 scv = *reinterpret_cast<const float4*>(sc + d);
    ushort4v o;
    o.x = f2bf((1.f+scv.x)*((x.x-mean)*inv) + shv.x);
    o.y = f2bf((1.f+scv.y)*((x.y-mean)*inv) + shv.y);
    o.z = f2bf((1.f+scv.z)*((x.z-mean)*inv) + shv.z);
    o.w = f2bf((1.f+scv.w)*((x.w-mean)*inv) + shv.w);
    *reinterpret_cast<ushort4v*>(xm + (size_t)l*DMODEL + d) = o;
}

// ---------------- generic LN + modulate -> bf16 ----------------
__global__ __launch_bounds__(256) void k_ln_mod2(const float* __restrict__ src,
                                                 const float* __restrict__ sh,
                                                 const float* __restrict__ sc,
                                                 ushort* __restrict__ out) {
    int r = blockIdx.x;
    const float* srow = src + (size_t)r * DMODEL;
    int d = threadIdx.x * 4;
    float4 x = *reinterpret_cast<const float4*>(srow + d);
    float s  = x.x + x.y + x.z + x.w;
    float s2 = x.x*x.x + x.y*x.y + x.z*x.z + x.w*x.w;
#pragma unroll
    for (int o = 32; o > 0; o >>= 1) { s += __shfl_xor(s, o); s2 += __shfl_xor(s2, o); }
    __shared__ float red[8];
    int wave = threadIdx.x >> 6, lane = threadIdx.x & 63;
    if (lane == 0) { red[wave*2] = s; red[wave*2+1] = s2; }
    __syncthreads();
    if (threadIdx.x == 0) {
        float a = 0.f, b = 0.f;
        for (int w = 0; w < 4; w++) { a += red[w*2]; b += red[w*2+1]; }
        red[0] = a; red[1] = b;
    }
    __syncthreads();
    float mean = red[0] * (1.0f/DMODEL);
    float var  = red[1] * (1.0f/DMODEL) - mean*mean;
    float inv  = rsqrtf(var + EPSV);
    float4 shv = *reinterpret_cast<const float4*>(sh + d);
    float4 scv = *reinterpret_cast<const float4*>(sc + d);
    ushort4v o;
    o.x = f2bf((1.f+scv.x)*((x.x-mean)*inv) + shv.x);
    o.y = f2bf((1.f+scv.y)*((x.y-mean)*inv) + shv.y);
    o.z = f2bf((1.f+scv.z)*((x.z-mean)*inv) + shv.z);
    o.w = f2bf((1.f+scv.w)*((x.w-mean)*inv) + shv.w);
    *reinterpret_cast<ushort4v*>(out + (size_t)r*DMODEL + d) = o;
}

// ---------------- bf16 MFMA GEMM: A[M][K] @ BT[N][K]^T, 128x128 tile, BK=64 ----------------
__device__ __forceinline__ float gelu_fast(float x) {
    // 0.5*x*(1+tanh(u)) == x*sigmoid(2u), u = 0.79788456*(x + 0.044715 x^3)
    return x / (1.0f + __expf(-1.5957691216057308f * (x + 0.044715f * x * x * x)));
}

template<int MODE, typename OutT>
__global__ __launch_bounds__(256) void k_gemm_bf(const ushort* __restrict__ A,
                                                 const ushort* __restrict__ BT,
                                                 const float* __restrict__ bias,
                                                 const float* __restrict__ res,
                                                 const float* __restrict__ gate,
                                                 OutT* __restrict__ C,
                                                 int M, int N, int K) {
    __shared__ ushort Asl[128*64];
    __shared__ ushort Bsl[128*64];
    const int tid = threadIdx.x;
    const int lane = tid & 63, w = tid >> 6;
    const int wr = w >> 1, wc = w & 1;
    const int bm = blockIdx.y * 128, bn = blockIdx.x * 128;
    const int r15 = lane & 15, g4 = lane >> 4;

    f32x4 acc[4][4];
#pragma unroll
    for (int i = 0; i < 4; i++)
#pragma unroll
        for (int j = 0; j < 4; j++) acc[i][j] = (f32x4){0.f,0.f,0.f,0.f};

    for (int k0 = 0; k0 < K; k0 += 64) {
        // stage A,B tiles: linear LDS dest, inverse-swizzled global source
#pragma unroll
        for (int i = 0; i < 4; i++) {
            int seg = (i*4 + w) * 64 + lane;          // 0..1023
            int row = seg >> 3;
            int gs  = (seg & 7) ^ (row & 7);
            gload16(A  + (size_t)(bm + row) * K + k0 + gs*8, Asl + (size_t)(i*4 + w) * 512);
            gload16(BT + (size_t)(bn + row) * K + k0 + gs*8, Bsl + (size_t)(i*4 + w) * 512);
        }
        __syncthreads();   // drains vmcnt -> LDS data visible
#pragma unroll
        for (int kk = 0; kk < 2; kk++) {
            short8b a[4], b[4];
#pragma unroll
            for (int mi = 0; mi < 4; mi++) {
                int row = wr*64 + mi*16 + r15;
                int c   = kk*4 + g4;
                a[mi] = *reinterpret_cast<const short8b*>(&Asl[row*64 + ((c ^ (row & 7)))*8]);
            }
#pragma unroll
            for (int ni = 0; ni < 4; ni++) {
                int row = wc*64 + ni*16 + r15;
                int c   = kk*4 + g4;
                b[ni] = *reinterpret_cast<const short8b*>(&Bsl[row*64 + ((c ^ (row & 7)))*8]);
            }
#pragma unroll
            for (int mi = 0; mi < 4; mi++)
#pragma unroll
                for (int ni = 0; ni < 4; ni++)
                    acc[mi][ni] = __builtin_amdgcn_mfma_f32_16x16x32_bf16(a[mi], b[ni], acc[mi][ni], 0, 0, 0);
        }
        __syncthreads();   // all reads done before next stage overwrites
    }

#pragma unroll
    for (int mi = 0; mi < 4; mi++) {
#pragma unroll
        for (int ni = 0; ni < 4; ni++) {
            int col = bn + wc*64 + ni*16 + r15;
            float bv = bias ? bias[col] : 0.f;
#pragma unroll
            for (int r = 0; r < 4; r++) {
                int row = bm + wr*64 + mi*16 + g4*4 + r;
                float v = acc[mi][ni][r] + bv;
                if (MODE == 1) v = gelu_fast(v);
                if (MODE == 2) v = res[(size_t)row * N + col] + gate[col] * v;
                if (sizeof(OutT) == 2) C[(size_t)row * N + col] = (OutT)f2bf(v);
                else                   C[(size_t)row * N + col] = (OutT)v;
            }
        }
    }
}

// ---------------- qkv finalize: RMS + RoPE -> bf16 Q,K [H][L][64], V^T [H][64][L] ----------------
__global__ __launch_bounds__(256) void k_qkvfin(const ushort* __restrict__ qkv,
                                                const float* __restrict__ pe,
                                                const float* __restrict__ qs,
                                                const float* __restrict__ ks,
                                                ushort* __restrict__ Q,
                                                ushort* __restrict__ K,
                                                ushort* __restrict__ VT) {
    int wid  = (blockIdx.x * 256 + threadIdx.x) >> 6;
    int lane = threadIdx.x & 63;
    int l = wid >> 4;
    int h = wid & 15;
    int strm;
    if (l < L_TXT) strm = 2; else if (l < L_TXT + L_IMG) strm = 0; else strm = 1;

    const ushort* row = qkv + (size_t)l * 3 * DMODEL;
    float q = bf2f(row[h*HDIM + lane]);
    float k = bf2f(row[DMODEL + h*HDIM + lane]);
    float v = bf2f(row[2*DMODEL + h*HDIM + lane]);

    float sq = q*q, sk = k*k;
#pragma unroll
    for (int o = 32; o > 0; o >>= 1) { sq += __shfl_xor(sq, o); sk += __shfl_xor(sk, o); }
    float rq = q * rsqrtf(sq * (1.0f/HDIM) + EPSV) * qs[strm*HDIM + lane];
    float rk = k * rsqrtf(sk * (1.0f/HDIM) + EPSV) * ks[strm*HDIM + lane];

    // BUG replication: temporal stream's V is its RMS'd Q (pre-RoPE)
    float vout = (strm == 1) ? rq : v;

    float rq_p = __shfl_xor(rq, 1);
    float rk_p = __shfl_xor(rk, 1);
    float qe = (lane & 1) ? rq_p : rq;
    float qo = (lane & 1) ? rq : rq_p;
    float ke = (lane & 1) ? rk_p : rk;
    float ko = (lane & 1) ? rk : rk_p;
    const float* pel = pe + (size_t)l*128 + (lane >> 1)*4 + (lane & 1)*2;
    float qr = pel[0]*qe + pel[1]*qo;
    float kr = pel[0]*ke + pel[1]*ko;

    size_t idx = ((size_t)h * LTOT + l) * HDIM + lane;
    Q[idx] = f2bf(qr);
    K[idx] = f2bf(kr);
    VT[((size_t)h * HDIM + lane) * LTOT + l] = f2bf(vout);
}

// ---------------- MFMA flash attention (validated r2), bf16 output ----------------
__global__ __launch_bounds__(256) void k_attn_mfma(const ushort* __restrict__ Qb,
                                                   const ushort* __restrict__ Kb,
                                                   const ushort* __restrict__ VTb,
                                                   ushort* __restrict__ att) {
    const int w = threadIdx.x >> 6, lane = threadIdx.x & 63;
    const int strip = blockIdx.x * 4 + w;
    const int h  = strip / 144;
    const int qt = strip % 144;
    const int qbase = qt * 16;
    const int g = lane >> 4;
    const int q = lane & 15;

    __shared__ ushort plds[4][1024];
    ushort* P = plds[w];

    const ushort* qp = Qb + ((size_t)h * LTOT + qbase + q) * 64 + g*8;
    const short8b qf0 = *reinterpret_cast<const short8b*>(qp);
    const short8b qf1 = *reinterpret_cast<const short8b*>(qp + 32);

    f32x4 out[4];
#pragma unroll
    for (int d = 0; d < 4; d++) out[d] = (f32x4){0.f,0.f,0.f,0.f};
    float m = -1e30f, lsum = 0.f;

    for (int kv0 = 0; kv0 < LTOT; kv0 += 64) {
        f32x4 s[4];
        const ushort* kbase = Kb + ((size_t)h * LTOT + kv0 + q) * 64 + g*8;
#pragma unroll
        for (int ks = 0; ks < 4; ks++) {
            short8b kf0 = *reinterpret_cast<const short8b*>(kbase + ks*16*64);
            short8b kf1 = *reinterpret_cast<const short8b*>(kbase + ks*16*64 + 32);
            f32x4 acc = (f32x4){0.f,0.f,0.f,0.f};
            acc = __builtin_amdgcn_mfma_f32_16x16x32_bf16(kf0, qf0, acc, 0, 0, 0);
            acc = __builtin_amdgcn_mfma_f32_16x16x32_bf16(kf1, qf1, acc, 0, 0, 0);
            s[ks] = acc;
        }
        float tmax = -1e30f;
#pragma unroll
        for (int ks = 0; ks < 4; ks++)
#pragma unroll
            for (int r = 0; r < 4; r++) tmax = fmaxf(tmax, s[ks][r]);
        tmax = fmaxf(tmax, __shfl_xor(tmax, 16));
        tmax = fmaxf(tmax, __shfl_xor(tmax, 32));
        float newm = fmaxf(m, tmax * 0.125f);
        float c = __expf(m - newm);
        float p[16];
        float tsum = 0.f;
#pragma unroll
        for (int ks = 0; ks < 4; ks++)
#pragma unroll
            for (int r = 0; r < 4; r++) {
                float pv = __expf(s[ks][r] * 0.125f - newm);
                p[ks*4+r] = pv;
                tsum += pv;
            }
        tsum += __shfl_xor(tsum, 16);
        tsum += __shfl_xor(tsum, 32);
        lsum = lsum * c + tsum;
        m = newm;
#pragma unroll
        for (int d = 0; d < 4; d++) out[d] *= c;

#pragma unroll
        for (int ks = 0; ks < 4; ks++) {
            ushort4v pk;
            pk.x = f2bf(p[ks*4+0]); pk.y = f2bf(p[ks*4+1]);
            pk.z = f2bf(p[ks*4+2]); pk.w = f2bf(p[ks*4+3]);
            int widx = (q*64 + ks*16 + g*4) ^ ((q & 7) << 3);
            *reinterpret_cast<ushort4v*>(&P[widx]) = pk;
        }
#pragma unroll
        for (int c2 = 0; c2 < 2; c2++) {
            int ridx = (q*64 + c2*32 + g*8) ^ ((q & 7) << 3);
            short8b pf = *reinterpret_cast<const short8b*>(&P[ridx]);
#pragma unroll
            for (int ds = 0; ds < 4; ds++) {
                short8b vf = *reinterpret_cast<const short8b*>(
                    VTb + ((size_t)h * 64 + ds*16 + q) * LTOT + kv0 + c2*32 + g*8);
                out[ds] = __builtin_amdgcn_mfma_f32_16x16x32_bf16(vf, pf, out[ds], 0, 0, 0);
            }
        }
    }

    float inv = 1.0f / lsum;
    ushort* orow = att + (size_t)(qbase + q) * DMODEL + h * HDIM;
#pragma unroll
    for (int ds = 0; ds < 4; ds++) {
        ushort4v o4;
        o4.x = f2bf(out[ds][0]*inv); o4.y = f2bf(out[ds][1]*inv);
        o4.z = f2bf(out[ds][2]*inv); o4.w = f2bf(out[ds][3]*inv);
        *reinterpret_cast<ushort4v*>(orow + ds*16 + g*4) = o4;
    }
}

// ---------------- launch ----------------
extern "C" void kernel_launch(void* const* d_in, const int* in_sizes, int n_in,
                              void* d_out, int out_size, void* d_ws, size_t ws_size,
                              hipStream_t stream) {
    const float* img  = (const float*)d_in[0];
    const float* tmp  = (const float*)d_in[1];
    const float* txt  = (const float*)d_in[2];
    const float* vec  = (const float*)d_in[3];
    const float* pe   = (const float*)d_in[4];
    const float* modw = (const float*)d_in[5];
    const float* modb = (const float*)d_in[6];
    const float* qkvw = (const float*)d_in[7];
    const float* qsc  = (const float*)d_in[8];
    const float* ksc  = (const float*)d_in[9];
    const float* projw= (const float*)d_in[10];
    const float* projb= (const float*)d_in[11];
    const float* w1   = (const float*)d_in[12];
    const float* b1   = (const float*)d_in[13];
    const float* w2   = (const float*)d_in[14];
    const float* b2   = (const float*)d_in[15];

    char* wsb = (char*)d_ws;
    float*  mod    = (float*) (wsb + MOD_OFF);
    ushort* xm     = (ushort*)(wsb + XM_OFF);
    ushort* qkv    = (ushort*)(wsb + QKV_OFF);
    ushort* t1     = (ushort*)(wsb + QKV_OFF);      // overlay (qkv dead after qkvfin)
    ushort* Qb     = (ushort*)(wsb + QB_OFF);
    ushort* Kb     = (ushort*)(wsb + KB_OFF);
    ushort* VTb    = (ushort*)(wsb + VTB_OFF);
    ushort* w2t    = (ushort*)(wsb + QB_OFF);       // overlay (Qb/Kb dead after attn)
    ushort* att    = (ushort*)(wsb + ATT_OFF);
    float*  s1     = (float*) (wsb + S1_OFF);
    ushort* hbuf   = (ushort*)(wsb + HBUF_OFF);
    ushort* qkvwt  = (ushort*)(wsb + QKVWT_OFF);
    ushort* projwt = (ushort*)(wsb + PROJWT_OFF);
    ushort* w1t    = (ushort*)(wsb + W1T_OFF);

    float* out_img = (float*)d_out;
    float* out_tmp = out_img + (size_t)L_IMG * DMODEL;
    float* out_txt = out_tmp + (size_t)L_TMP * DMODEL;

    // weights (qkv/proj/w1) + mod vectors + LN/mod1
    k_wt_all<<<24576, 256, 0, stream>>>(qkvw, projw, w1, qkvwt, projwt, w1t);
    k_mod<<<72, 256, 0, stream>>>(vec, modw, modb, mod);
    k_ln_mod1<<<LTOT, 256, 0, stream>>>(img, tmp, txt, mod, xm);

    // QKV GEMMs (weight slice: img=0, tmp=1, txt=2)
    k_gemm_bf<0, ushort><<<dim3(24, 2),  256, 0, stream>>>(xm,                        qkvwt + (size_t)2*3072*1024, nullptr, nullptr, nullptr, qkv,                        L_TXT, 3072, DMODEL);
    k_gemm_bf<0, ushort><<<dim3(24, 8),  256, 0, stream>>>(xm + (size_t)256*DMODEL,   qkvwt,                       nullptr, nullptr, nullptr, qkv + (size_t)256*3072,     L_IMG, 3072, DMODEL);
    k_gemm_bf<0, ushort><<<dim3(24, 8),  256, 0, stream>>>(xm + (size_t)1280*DMODEL,  qkvwt + (size_t)1*3072*1024, nullptr, nullptr, nullptr, qkv + (size_t)1280*3072,    L_TMP, 3072, DMODEL);

    k_qkvfin<<<9216, 256, 0, stream>>>(qkv, pe, qsc, ksc, Qb, Kb, VTb);
    k_attn_mfma<<<576, 256, 0, stream>>>(Qb, Kb, VTb, att);

    // proj + residual + gate1 -> s1 (f32)
    k_gemm_bf<2, float><<<dim3(8, 8), 256, 0, stream>>>(att + (size_t)256*DMODEL,  projwt,                       projb,            img, mod + 0*6144 + 2*1024, s1 + (size_t)256*DMODEL,  L_IMG, DMODEL, DMODEL);
    k_gemm_bf<2, float><<<dim3(8, 8), 256, 0, stream>>>(att + (size_t)1280*DMODEL, projwt + (size_t)1*1024*1024, projb + DMODEL,   tmp, mod + 1*6144 + 2*1024, s1 + (size_t)1280*DMODEL, L_TMP, DMODEL, DMODEL);
    k_gemm_bf<2, float><<<dim3(8, 2), 256, 0, stream>>>(att,                       projwt + (size_t)2*1024*1024, projb + 2*DMODEL, txt, mod + 2*6144 + 2*1024, s1,                       L_TXT, DMODEL, DMODEL);

    // img MLP -> out_img   (w2 slice 0 converted into dead Qb/Kb region)
    k_wt_slice<<<dim3(32, 128), 256, 0, stream>>>(w2, w2t, DMLP, DMODEL);
    k_ln_mod2<<<L_IMG, 256, 0, stream>>>(s1 + (size_t)256*DMODEL, mod + 0*6144 + 3*1024, mod + 0*6144 + 4*1024, hbuf);
    k_gemm_bf<1, ushort><<<dim3(32, 8), 256, 0, stream>>>(hbuf, w1t, b1, nullptr, nullptr, t1, L_IMG, DMLP, DMODEL);
    k_gemm_bf<2, float ><<<dim3(8, 8),  256, 0, stream>>>(t1, w2t, b2, s1 + (size_t)256*DMODEL, mod + 0*6144 + 5*1024, out_img, L_IMG, DMODEL, DMLP);

    // temporal MLP (LN input is FINAL img — reference quirk) -> out_tmp
    k_wt_slice<<<dim3(32, 128), 256, 0, stream>>>(w2 + (size_t)DMLP*DMODEL, w2t, DMLP, DMODEL);
    k_ln_mod2<<<L_TMP, 256, 0, stream>>>(out_img, mod + 1*6144 + 3*1024, mod + 1*6144 + 4*1024, hbuf);
    k_gemm_bf<1, ushort><<<dim3(32, 8), 256, 0, stream>>>(hbuf, w1t + (size_t)1*DMLP*1024, b1 + DMLP, nullptr, nullptr, t1, L_TMP, DMLP, DMODEL);
    k_gemm_bf<2, float ><<<dim3(8, 8),  256, 0, stream>>>(t1, w2t, b2 + DMODEL, s1 + (size_t)1280*DMODEL, mod + 1*6144 + 5*1024, out_tmp, L_TMP, DMODEL, DMLP);

    // txt MLP -> out_txt
    k_wt_slice<<<dim3(32, 128), 256, 0, stream>>>(w2 + (size_t)2*DMLP*DMODEL, w2t, DMLP, DMODEL);
    k_ln_mod2<<<L_TXT, 256, 0, stream>>>(s1, mod + 2*6144 + 3*1024, mod + 2*6144 + 4*1024, hbuf);
    k_gemm_bf<1, ushort><<<dim3(32, 2), 256, 0, stream>>>(hbuf, w1t + (size_t)2*DMLP*1024, b1 + 2*DMLP, nullptr, nullptr, t1, L_TXT, DMLP, DMODEL);
    k_gemm_bf<2, float ><<<dim3(8, 2),  256, 0, stream>>>(t1, w2t, b2 + 2*DMODEL, s1, mod + 2*6144 + 5*1024, out_txt, L_TXT, DMODEL, DMLP);
}

// Round 4
// 533.365 us; speedup vs baseline: 6.2683x; 1.5853x over previous
//
#include <hip/hip_runtime.h>
#include <hip/hip_bf16.h>

#define L_TXT 256
#define L_IMG 1024
#define L_TMP 1024
#define LTOT  2304
#define DMODEL 1024
#define NH 16
#define HDIM 64
#define DMLP 4096
#define EPSV 1e-6f

typedef unsigned short ushort;
typedef __attribute__((ext_vector_type(8))) short short8b;   // 8 x bf16
typedef __attribute__((ext_vector_type(4))) float f32x4;
typedef __attribute__((ext_vector_type(4))) unsigned short ushort4v;

// ---- workspace layout (bytes) ----
#define MOD_OFF    ((size_t)0)                       // f32 3*6144
#define XM_OFF     ((size_t)73728)                   // bf16 2304*1024 (also LN buffer for MLPs)
#define QKV_OFF    ((size_t)4792320)                 // bf16 2304*3072 (t1 overlays, needs <=14.1MB)
#define QB_OFF     ((size_t)18948096)                // bf16 16*2304*64
#define KB_OFF     ((size_t)23666688)
#define VTB_OFF    ((size_t)28385280)
#define ATT_OFF    ((size_t)33103872)                // bf16 2304*1024
#define S1_OFF     ((size_t)37822464)                // f32 2304*1024
#define QKVWT_OFF  ((size_t)49356800)                // bf16 3*3072*1024
#define PROJWT_OFF ((size_t)68231168)                // bf16 3*1024*1024
#define W1T_OFF    ((size_t)74522624)                // bf16 3*4096*1024 (w2t slices overlay after mlp1)
// end ~ 99.7 MB

static __device__ __forceinline__ ushort f2bf(float x) {
    __hip_bfloat16 b = __float2bfloat16(x);
    return *reinterpret_cast<ushort*>(&b);
}
static __device__ __forceinline__ float bf2f(ushort u) {
    return __uint_as_float(((unsigned)u) << 16);
}

typedef __attribute__((address_space(1))) const unsigned char gas_t;
typedef __attribute__((address_space(3))) unsigned char las_t;
static __device__ __forceinline__ void gload16(const void* g, void* l) {
    __builtin_amdgcn_global_load_lds((gas_t*)g, (las_t*)l, 16, 0, 0);
}

// ---------------- mod GEMV (silu fused) ----------------
__global__ __launch_bounds__(256) void k_mod(const float* __restrict__ vec,
                                             const float* __restrict__ mw,
                                             const float* __restrict__ mb,
                                             float* __restrict__ mod) {
    __shared__ float svs[DMODEL];
    for (int i = threadIdx.x; i < DMODEL; i += 256) {
        float v = vec[i];
        svs[i] = v / (1.0f + __expf(-v));
    }
    __syncthreads();
    int g = blockIdx.x * 256 + threadIdx.x;
    int i = g / 6144;
    int j = g - i * 6144;
    const float* w = mw + (size_t)i * DMODEL * 6144 + j;
    float acc = 0.f;
#pragma unroll 4
    for (int k = 0; k < DMODEL; k++) acc += svs[k] * w[(size_t)k * 6144];
    mod[g] = acc + mb[g];
}

// ---------------- weight transpose-convert: f32 [K][N] -> bf16 [N][K] ----------------
__global__ __launch_bounds__(256) void k_wt_all(const float* __restrict__ qkvw,
                                                const float* __restrict__ projw,
                                                const float* __restrict__ w1,
                                                ushort* __restrict__ qkvwt,
                                                ushort* __restrict__ projwt,
                                                ushort* __restrict__ w1t) {
    int bid = blockIdx.x;
    const float* W; ushort* WT; int K, N;
    if (bid < 9216) {
        int s = bid / 3072, r = bid % 3072;
        K = 1024; N = 3072;
        W = qkvw + (size_t)s * K * N; WT = qkvwt + (size_t)s * N * K;
        bid = r;
    } else if (bid < 12288) {
        int b = bid - 9216; int s = b / 1024, r = b % 1024;
        K = 1024; N = 1024;
        W = projw + (size_t)s * K * N; WT = projwt + (size_t)s * N * K;
        bid = r;
    } else {
        int b = bid - 12288; int s = b / 4096, r = b % 4096;
        K = 1024; N = 4096;
        W = w1 + (size_t)s * K * N; WT = w1t + (size_t)s * N * K;
        bid = r;
    }
    int nt = bid % (N >> 5), kt = bid / (N >> 5);
    __shared__ float tb[32][33];
    int r = threadIdx.x >> 5, c = threadIdx.x & 31;
#pragma unroll
    for (int i = 0; i < 4; i++)
        tb[r + i*8][c] = W[(size_t)(kt*32 + r + i*8) * N + nt*32 + c];
    __syncthreads();
#pragma unroll
    for (int i = 0; i < 4; i++)
        WT[(size_t)(nt*32 + r + i*8) * K + kt*32 + c] = f2bf(tb[c][r + i*8]);
}

__global__ __launch_bounds__(256) void k_wt_slice(const float* __restrict__ W,
                                                  ushort* __restrict__ WT,
                                                  int K, int N) {
    int nt = blockIdx.x, kt = blockIdx.y;
    __shared__ float tb[32][33];
    int r = threadIdx.x >> 5, c = threadIdx.x & 31;
#pragma unroll
    for (int i = 0; i < 4; i++)
        tb[r + i*8][c] = W[(size_t)(kt*32 + r + i*8) * N + nt*32 + c];
    __syncthreads();
#pragma unroll
    for (int i = 0; i < 4; i++)
        WT[(size_t)(nt*32 + r + i*8) * K + kt*32 + c] = f2bf(tb[c][r + i*8]);
}

// ---------------- LN + (1+sc)*x + sh -> bf16, stream-select ----------------
__global__ __launch_bounds__(256) void k_ln_mod1(const float* __restrict__ img,
                                                 const float* __restrict__ tmp,
                                                 const float* __restrict__ txt,
                                                 const float* __restrict__ mod,
                                                 ushort* __restrict__ xm) {
    int l = blockIdx.x;
    const float* src; int strm;
    if (l < L_TXT)              { src = txt + (size_t)l * DMODEL;            strm = 2; }
    else if (l < L_TXT + L_IMG) { src = img + (size_t)(l - L_TXT) * DMODEL;  strm = 0; }
    else                        { src = tmp + (size_t)(l - L_TXT - L_IMG) * DMODEL; strm = 1; }

    int d = threadIdx.x * 4;
    float4 x = *reinterpret_cast<const float4*>(src + d);
    float s  = x.x + x.y + x.z + x.w;
    float s2 = x.x*x.x + x.y*x.y + x.z*x.z + x.w*x.w;
#pragma unroll
    for (int o = 32; o > 0; o >>= 1) { s += __shfl_xor(s, o); s2 += __shfl_xor(s2, o); }
    __shared__ float red[8];
    int wave = threadIdx.x >> 6, lane = threadIdx.x & 63;
    if (lane == 0) { red[wave*2] = s; red[wave*2+1] = s2; }
    __syncthreads();
    if (threadIdx.x == 0) {
        float a = 0.f, b = 0.f;
        for (int w = 0; w < 4; w++) { a += red[w*2]; b += red[w*2+1]; }
        red[0] = a; red[1] = b;
    }
    __syncthreads();
    float mean = red[0] * (1.0f/DMODEL);
    float var  = red[1] * (1.0f/DMODEL) - mean*mean;
    float inv  = rsqrtf(var + EPSV);

    const float* sh = mod + strm*6144;
    const float* sc = sh + 1024;
    float4 shv = *reinterpret_cast<const float4*>(sh + d);
    float4 scv = *reinterpret_cast<const float4*>(sc + d);
    ushort4v o;
    o.x = f2bf((1.f+scv.x)*((x.x-mean)*inv) + shv.x);
    o.y = f2bf((1.f+scv.y)*((x.y-mean)*inv) + shv.y);
    o.z = f2bf((1.f+scv.z)*((x.z-mean)*inv) + shv.z);
    o.w = f2bf((1.f+scv.w)*((x.w-mean)*inv) + shv.w);
    *reinterpret_cast<ushort4v*>(xm + (size_t)l*DMODEL + d) = o;
}

// ---------------- generic LN + modulate -> bf16 ----------------
__global__ __launch_bounds__(256) void k_ln_mod2(const float* __restrict__ src,
                                                 const float* __restrict__ sh,
                                                 const float* __restrict__ sc,
                                                 ushort* __restrict__ out) {
    int r = blockIdx.x;
    const float* srow = src + (size_t)r * DMODEL;
    int d = threadIdx.x * 4;
    float4 x = *reinterpret_cast<const float4*>(srow + d);
    float s  = x.x + x.y + x.z + x.w;
    float s2 = x.x*x.x + x.y*x.y + x.z*x.z + x.w*x.w;
#pragma unroll
    for (int o = 32; o > 0; o >>= 1) { s += __shfl_xor(s, o); s2 += __shfl_xor(s2, o); }
    __shared__ float red[8];
    int wave = threadIdx.x >> 6, lane = threadIdx.x & 63;
    if (lane == 0) { red[wave*2] = s; red[wave*2+1] = s2; }
    __syncthreads();
    if (threadIdx.x == 0) {
        float a = 0.f, b = 0.f;
        for (int w = 0; w < 4; w++) { a += red[w*2]; b += red[w*2+1]; }
        red[0] = a; red[1] = b;
    }
    __syncthreads();
    float mean = red[0] * (1.0f/DMODEL);
    float var  = red[1] * (1.0f/DMODEL) - mean*mean;
    float inv  = rsqrtf(var + EPSV);
    float4 shv = *reinterpret_cast<const float4*>(sh + d);
    float4 scv = *reinterpret_cast<const float4*>(sc + d);
    ushort4v o;
    o.x = f2bf((1.f+scv.x)*((x.x-mean)*inv) + shv.x);
    o.y = f2bf((1.f+scv.y)*((x.y-mean)*inv) + shv.y);
    o.z = f2bf((1.f+scv.z)*((x.z-mean)*inv) + shv.z);
    o.w = f2bf((1.f+scv.w)*((x.w-mean)*inv) + shv.w);
    *reinterpret_cast<ushort4v*>(out + (size_t)r*DMODEL + d) = o;
}

// ---------------- multi-stream bf16 MFMA GEMM: rows in global order (txt/img/tmp) ----------------
// per 128-row tile: stream s selected by row; weights BT + s*N*K; bias + s*N; gate mod+s*6144+gidx*1024.
// A/res/out given as per-stream local-base pointers (indexed by stream-local row).
__device__ __forceinline__ float gelu_fast(float x) {
    return x / (1.0f + __expf(-1.5957691216057308f * (x + 0.044715f * x * x * x)));
}

template<int MODE, typename OutT>
__global__ __launch_bounds__(256) void k_gemm_ms(const ushort* __restrict__ A_t,
                                                 const ushort* __restrict__ A_i,
                                                 const ushort* __restrict__ A_m,
                                                 const ushort* __restrict__ BT,
                                                 const float* __restrict__ bias,
                                                 const float* __restrict__ res_t,
                                                 const float* __restrict__ res_i,
                                                 const float* __restrict__ res_m,
                                                 const float* __restrict__ mod, int gidx,
                                                 OutT* __restrict__ out_t,
                                                 OutT* __restrict__ out_i,
                                                 OutT* __restrict__ out_m,
                                                 int N, int K, int ry0) {
    const int brow = (ry0 + blockIdx.y) * 128;
    int s, lrow;
    if (brow < 256)       { s = 2; lrow = brow; }
    else if (brow < 1280) { s = 0; lrow = brow - 256; }
    else                  { s = 1; lrow = brow - 1280; }

    const ushort* A = (s==2 ? A_t : s==0 ? A_i : A_m) + (size_t)lrow * K;
    const ushort* BTs = BT + (size_t)s * N * K;
    const float* bi = bias ? bias + (size_t)s * N : nullptr;
    const float* resl = (MODE==2) ? ((s==2 ? res_t : s==0 ? res_i : res_m) + (size_t)lrow * N) : nullptr;
    const float* gate = (MODE==2) ? (mod + s*6144 + gidx*1024) : nullptr;
    OutT* Cl = (s==2 ? out_t : s==0 ? out_i : out_m) + (size_t)lrow * N;

    __shared__ ushort Asl[128*64];
    __shared__ ushort Bsl[128*64];
    const int tid = threadIdx.x;
    const int lane = tid & 63, w = tid >> 6;
    const int wr = w >> 1, wc = w & 1;
    const int bn = blockIdx.x * 128;
    const int r15 = lane & 15, g4 = lane >> 4;

    f32x4 acc[4][4];
#pragma unroll
    for (int i = 0; i < 4; i++)
#pragma unroll
        for (int j = 0; j < 4; j++) acc[i][j] = (f32x4){0.f,0.f,0.f,0.f};

    for (int k0 = 0; k0 < K; k0 += 64) {
#pragma unroll
        for (int i = 0; i < 4; i++) {
            int seg = (i*4 + w) * 64 + lane;
            int row = seg >> 3;
            int gs  = (seg & 7) ^ (row & 7);
            gload16(A   + (size_t)row * K + k0 + gs*8, Asl + (size_t)(i*4 + w) * 512);
            gload16(BTs + (size_t)(bn + row) * K + k0 + gs*8, Bsl + (size_t)(i*4 + w) * 512);
        }
        __syncthreads();
#pragma unroll
        for (int kk = 0; kk < 2; kk++) {
            short8b a[4], b[4];
#pragma unroll
            for (int mi = 0; mi < 4; mi++) {
                int row = wr*64 + mi*16 + r15;
                int c   = kk*4 + g4;
                a[mi] = *reinterpret_cast<const short8b*>(&Asl[row*64 + ((c ^ (row & 7)))*8]);
            }
#pragma unroll
            for (int ni = 0; ni < 4; ni++) {
                int row = wc*64 + ni*16 + r15;
                int c   = kk*4 + g4;
                b[ni] = *reinterpret_cast<const short8b*>(&Bsl[row*64 + ((c ^ (row & 7)))*8]);
            }
#pragma unroll
            for (int mi = 0; mi < 4; mi++)
#pragma unroll
                for (int ni = 0; ni < 4; ni++)
                    acc[mi][ni] = __builtin_amdgcn_mfma_f32_16x16x32_bf16(a[mi], b[ni], acc[mi][ni], 0, 0, 0);
        }
        __syncthreads();
    }

#pragma unroll
    for (int mi = 0; mi < 4; mi++) {
#pragma unroll
        for (int ni = 0; ni < 4; ni++) {
            int col = bn + wc*64 + ni*16 + r15;
            float bv = bi ? bi[col] : 0.f;
#pragma unroll
            for (int r = 0; r < 4; r++) {
                int rr = wr*64 + mi*16 + g4*4 + r;
                float v = acc[mi][ni][r] + bv;
                if (MODE == 1) v = gelu_fast(v);
                if (MODE == 2) v = resl[(size_t)rr * N + col] + gate[col] * v;
                if (sizeof(OutT) == 2) Cl[(size_t)rr * N + col] = (OutT)f2bf(v);
                else                   Cl[(size_t)rr * N + col] = (OutT)v;
            }
        }
    }
}

// ---------------- qkv finalize: RMS + RoPE -> bf16 Q,K [H][L][64], V^T [H][64][L] ----------------
__global__ __launch_bounds__(256) void k_qkvfin(const ushort* __restrict__ qkv,
                                                const float* __restrict__ pe,
                                                const float* __restrict__ qs,
                                                const float* __restrict__ ks,
                                                ushort* __restrict__ Q,
                                                ushort* __restrict__ K,
                                                ushort* __restrict__ VT) {
    int wid  = (blockIdx.x * 256 + threadIdx.x) >> 6;
    int lane = threadIdx.x & 63;
    int l = wid >> 4;
    int h = wid & 15;
    int strm;
    if (l < L_TXT) strm = 2; else if (l < L_TXT + L_IMG) strm = 0; else strm = 1;

    const ushort* row = qkv + (size_t)l * 3 * DMODEL;
    float q = bf2f(row[h*HDIM + lane]);
    float k = bf2f(row[DMODEL + h*HDIM + lane]);
    float v = bf2f(row[2*DMODEL + h*HDIM + lane]);

    float sq = q*q, sk = k*k;
#pragma unroll
    for (int o = 32; o > 0; o >>= 1) { sq += __shfl_xor(sq, o); sk += __shfl_xor(sk, o); }
    float rq = q * rsqrtf(sq * (1.0f/HDIM) + EPSV) * qs[strm*HDIM + lane];
    float rk = k * rsqrtf(sk * (1.0f/HDIM) + EPSV) * ks[strm*HDIM + lane];

    // BUG replication: temporal stream's V is its RMS'd Q (pre-RoPE)
    float vout = (strm == 1) ? rq : v;

    float rq_p = __shfl_xor(rq, 1);
    float rk_p = __shfl_xor(rk, 1);
    float qe = (lane & 1) ? rq_p : rq;
    float qo = (lane & 1) ? rq : rq_p;
    float ke = (lane & 1) ? rk_p : rk;
    float ko = (lane & 1) ? rk : rk_p;
    const float* pel = pe + (size_t)l*128 + (lane >> 1)*4 + (lane & 1)*2;
    float qr = pel[0]*qe + pel[1]*qo;
    float kr = pel[0]*ke + pel[1]*ko;

    size_t idx = ((size_t)h * LTOT + l) * HDIM + lane;
    Q[idx] = f2bf(qr);
    K[idx] = f2bf(kr);
    VT[((size_t)h * HDIM + lane) * LTOT + l] = f2bf(vout);
}

// ---------------- MFMA flash attention with LDS-staged K/V ----------------
// block = 4 waves = one (head, 64-query tile); wave w owns queries [qt*64+w*16, +16).
// Per kv-iter: stage K 64x64 + V^T 64x64 via global_load_lds (pre-swizzled source),
// swizzled ds_read_b128 frags, online softmax per q-column, P via wave-private LDS.
__global__ __launch_bounds__(256) void k_attn_mfma(const ushort* __restrict__ Qb,
                                                   const ushort* __restrict__ Kb,
                                                   const ushort* __restrict__ VTb,
                                                   ushort* __restrict__ att) {
    const int tid = threadIdx.x;
    const int w = tid >> 6, lane = tid & 63;
    const int h  = blockIdx.x / 36;
    const int qt = blockIdx.x % 36;
    const int qbase = qt*64 + w*16;
    const int g = lane >> 4;
    const int q = lane & 15;

    __shared__ ushort Ksl[64*64];
    __shared__ ushort Vsl[64*64];
    __shared__ ushort plds[4][1024];
    ushort* P = plds[w];

    const ushort* Kg = Kb  + (size_t)h * LTOT * 64;
    const ushort* Vg = VTb + (size_t)h * 64 * LTOT;

    const ushort* qp = Qb + ((size_t)h * LTOT + qbase + q) * 64 + g*8;
    const short8b qf0 = *reinterpret_cast<const short8b*>(qp);
    const short8b qf1 = *reinterpret_cast<const short8b*>(qp + 32);

    f32x4 out[4];
#pragma unroll
    for (int d = 0; d < 4; d++) out[d] = (f32x4){0.f,0.f,0.f,0.f};
    float m = -1e30f, lsum = 0.f;

    for (int kv0 = 0; kv0 < LTOT; kv0 += 64) {
        // ---- stage K-tile [64 kv][64 d] and V^T-tile [64 d][64 kv], swizzled source ----
#pragma unroll
        for (int i = 0; i < 2; i++) {
            int seg = i*256 + tid;
            int row = seg >> 3;
            int gs  = (seg & 7) ^ (row & 7);
            gload16(Kg + (size_t)(kv0 + row)*64 + gs*8, Ksl + (size_t)(i*256 + w*64)*8);
            gload16(Vg + (size_t)row*LTOT + kv0 + gs*8, Vsl + (size_t)(i*256 + w*64)*8);
        }
        __syncthreads();

        // ---- S^T = mfma(K, Q): 4 sub-tiles of 16kv x 16q ----
        f32x4 s[4];
#pragma unroll
        for (int ks = 0; ks < 4; ks++) {
            int r = ks*16 + q;
            short8b kf0 = *reinterpret_cast<const short8b*>(&Ksl[r*64 + ((g     ^ (r & 7)))*8]);
            short8b kf1 = *reinterpret_cast<const short8b*>(&Ksl[r*64 + (((4+g) ^ (r & 7)))*8]);
            f32x4 acc = (f32x4){0.f,0.f,0.f,0.f};
            acc = __builtin_amdgcn_mfma_f32_16x16x32_bf16(kf0, qf0, acc, 0, 0, 0);
            acc = __builtin_amdgcn_mfma_f32_16x16x32_bf16(kf1, qf1, acc, 0, 0, 0);
            s[ks] = acc;
        }
        // ---- online softmax along kv for this lane's q column ----
        float tmax = -1e30f;
#pragma unroll
        for (int ks = 0; ks < 4; ks++)
#pragma unroll
            for (int r = 0; r < 4; r++) tmax = fmaxf(tmax, s[ks][r]);
        tmax = fmaxf(tmax, __shfl_xor(tmax, 16));
        tmax = fmaxf(tmax, __shfl_xor(tmax, 32));
        float newm = fmaxf(m, tmax * 0.125f);
        float c = __expf(m - newm);
        float p[16];
        float tsum = 0.f;
#pragma unroll
        for (int ks = 0; ks < 4; ks++)
#pragma unroll
            for (int r = 0; r < 4; r++) {
                float pv = __expf(s[ks][r] * 0.125f - newm);
                p[ks*4+r] = pv;
                tsum += pv;
            }
        tsum += __shfl_xor(tsum, 16);
        tsum += __shfl_xor(tsum, 32);
        lsum = lsum * c + tsum;
        m = newm;
#pragma unroll
        for (int d = 0; d < 4; d++) out[d] *= c;

        // ---- P -> bf16 -> wave-private LDS as [q][kv], XOR-swizzled ----
#pragma unroll
        for (int ks = 0; ks < 4; ks++) {
            ushort4v pk;
            pk.x = f2bf(p[ks*4+0]); pk.y = f2bf(p[ks*4+1]);
            pk.z = f2bf(p[ks*4+2]); pk.w = f2bf(p[ks*4+3]);
            int widx = (q*64 + ks*16 + g*4) ^ ((q & 7) << 3);
            *reinterpret_cast<ushort4v*>(&P[widx]) = pk;
        }
        // ---- PV^T from LDS V-tile ----
#pragma unroll
        for (int c2 = 0; c2 < 2; c2++) {
            int ridx = (q*64 + c2*32 + g*8) ^ ((q & 7) << 3);
            short8b pf = *reinterpret_cast<const short8b*>(&P[ridx]);
#pragma unroll
            for (int ds = 0; ds < 4; ds++) {
                int d = ds*16 + q;
                short8b vf = *reinterpret_cast<const short8b*>(&Vsl[d*64 + (((c2*4+g) ^ (d & 7)))*8]);
                out[ds] = __builtin_amdgcn_mfma_f32_16x16x32_bf16(vf, pf, out[ds], 0, 0, 0);
            }
        }
        __syncthreads();
    }

    float inv = 1.0f / lsum;
    ushort* orow = att + (size_t)(qbase + q) * DMODEL + h * HDIM;
#pragma unroll
    for (int ds = 0; ds < 4; ds++) {
        ushort4v o4;
        o4.x = f2bf(out[ds][0]*inv); o4.y = f2bf(out[ds][1]*inv);
        o4.z = f2bf(out[ds][2]*inv); o4.w = f2bf(out[ds][3]*inv);
        *reinterpret_cast<ushort4v*>(orow + ds*16 + g*4) = o4;
    }
}

// ---------------- launch ----------------
extern "C" void kernel_launch(void* const* d_in, const int* in_sizes, int n_in,
                              void* d_out, int out_size, void* d_ws, size_t ws_size,
                              hipStream_t stream) {
    const float* img  = (const float*)d_in[0];
    const float* tmp  = (const float*)d_in[1];
    const float* txt  = (const float*)d_in[2];
    const float* vec  = (const float*)d_in[3];
    const float* pe   = (const float*)d_in[4];
    const float* modw = (const float*)d_in[5];
    const float* modb = (const float*)d_in[6];
    const float* qkvw = (const float*)d_in[7];
    const float* qsc  = (const float*)d_in[8];
    const float* ksc  = (const float*)d_in[9];
    const float* projw= (const float*)d_in[10];
    const float* projb= (const float*)d_in[11];
    const float* w1   = (const float*)d_in[12];
    const float* b1   = (const float*)d_in[13];
    const float* w2   = (const float*)d_in[14];
    const float* b2   = (const float*)d_in[15];

    char* wsb = (char*)d_ws;
    float*  mod    = (float*) (wsb + MOD_OFF);
    ushort* xm     = (ushort*)(wsb + XM_OFF);
    ushort* qkv    = (ushort*)(wsb + QKV_OFF);
    ushort* t1     = (ushort*)(wsb + QKV_OFF);      // overlay (qkv dead after qkvfin); <=1280 rows live
    ushort* Qb     = (ushort*)(wsb + QB_OFF);
    ushort* Kb     = (ushort*)(wsb + KB_OFF);
    ushort* VTb    = (ushort*)(wsb + VTB_OFF);
    ushort* att    = (ushort*)(wsb + ATT_OFF);
    float*  s1     = (float*) (wsb + S1_OFF);
    ushort* qkvwt  = (ushort*)(wsb + QKVWT_OFF);
    ushort* projwt = (ushort*)(wsb + PROJWT_OFF);
    ushort* w1t    = (ushort*)(wsb + W1T_OFF);      // w2t[s] overlays w1t[s] after mlp1[s]

    float* out_img = (float*)d_out;
    float* out_tmp = out_img + (size_t)L_IMG * DMODEL;
    float* out_txt = out_tmp + (size_t)L_TMP * DMODEL;

    // weights + mod vectors + LN/mod1
    k_wt_all<<<24576, 256, 0, stream>>>(qkvw, projw, w1, qkvwt, projwt, w1t);
    k_mod<<<72, 256, 0, stream>>>(vec, modw, modb, mod);
    k_ln_mod1<<<LTOT, 256, 0, stream>>>(img, tmp, txt, mod, xm);

    // QKV: one merged dispatch over all 18 row-tiles
    k_gemm_ms<0, ushort><<<dim3(24, 18), 256, 0, stream>>>(
        xm, xm + (size_t)256*DMODEL, xm + (size_t)1280*DMODEL,
        qkvwt, nullptr, nullptr, nullptr, nullptr, nullptr, 0,
        qkv, qkv + (size_t)256*3072, qkv + (size_t)1280*3072, 3072, DMODEL, 0);

    k_qkvfin<<<9216, 256, 0, stream>>>(qkv, pe, qsc, ksc, Qb, Kb, VTb);
    k_attn_mfma<<<NH*36, 256, 0, stream>>>(Qb, Kb, VTb, att);

    // proj + residual + gate1 -> s1 (merged)
    k_gemm_ms<2, float><<<dim3(8, 18), 256, 0, stream>>>(
        att, att + (size_t)256*DMODEL, att + (size_t)1280*DMODEL,
        projwt, projb, txt, img, tmp, mod, 2,
        s1, s1 + (size_t)256*DMODEL, s1 + (size_t)1280*DMODEL, DMODEL, DMODEL, 0);

    // ---- phase A: txt + img MLP ----
    k_ln_mod2<<<L_TXT, 256, 0, stream>>>(s1,                        mod + 2*6144 + 3*1024, mod + 2*6144 + 4*1024, xm);
    k_ln_mod2<<<L_IMG, 256, 0, stream>>>(s1 + (size_t)256*DMODEL,   mod + 0*6144 + 3*1024, mod + 0*6144 + 4*1024, xm + (size_t)256*DMODEL);
    k_gemm_ms<1, ushort><<<dim3(32, 10), 256, 0, stream>>>(
        xm, xm + (size_t)256*DMODEL, xm + (size_t)1280*DMODEL,
        w1t, b1, nullptr, nullptr, nullptr, nullptr, 0,
        t1, t1 + (size_t)256*DMLP, t1, DMLP, DMODEL, 0);
    // w2t slices 0,2 overlay dead w1t slices 0,2
    k_wt_slice<<<dim3(32, 128), 256, 0, stream>>>(w2,                          w1t,                          DMLP, DMODEL);
    k_wt_slice<<<dim3(32, 128), 256, 0, stream>>>(w2 + (size_t)2*DMLP*DMODEL,  w1t + (size_t)2*DMLP*DMODEL,  DMLP, DMODEL);
    k_gemm_ms<2, float><<<dim3(8, 10), 256, 0, stream>>>(
        t1, t1 + (size_t)256*DMLP, t1,
        w1t /*= w2t*/, b2, s1, s1 + (size_t)256*DMODEL, s1 + (size_t)1280*DMODEL, mod, 5,
        out_txt, out_img, out_tmp, DMODEL, DMLP, 0);

    // ---- phase B: temporal MLP (LN input is FINAL img — reference quirk) ----
    k_ln_mod2<<<L_TMP, 256, 0, stream>>>(out_img, mod + 1*6144 + 3*1024, mod + 1*6144 + 4*1024, xm + (size_t)1280*DMODEL);
    k_gemm_ms<1, ushort><<<dim3(32, 8), 256, 0, stream>>>(
        xm, xm + (size_t)256*DMODEL, xm + (size_t)1280*DMODEL,
        w1t, b1, nullptr, nullptr, nullptr, nullptr, 0,
        t1, t1, t1, DMLP, DMODEL, 10);
    k_wt_slice<<<dim3(32, 128), 256, 0, stream>>>(w2 + (size_t)DMLP*DMODEL, w1t + (size_t)DMLP*DMODEL, DMLP, DMODEL);
    k_gemm_ms<2, float><<<dim3(8, 8), 256, 0, stream>>>(
        t1, t1, t1,
        w1t /*= w2t*/, b2, s1, s1, s1 + (size_t)1280*DMODEL, mod, 5,
        out_txt, out_img, out_tmp, DMODEL, DMLP, 10);
}

// Round 5
// 356.657 us; speedup vs baseline: 9.3740x; 1.4955x over previous
//
#include <hip/hip_runtime.h>
#include <hip/hip_bf16.h>

#define L_TXT 256
#define L_IMG 1024
#define L_TMP 1024
#define LTOT  2304
#define DMODEL 1024
#define NH 16
#define HDIM 64
#define DMLP 4096
#define EPSV 1e-6f

typedef unsigned short ushort;
typedef __attribute__((ext_vector_type(8))) short short8b;   // 8 x bf16
typedef __attribute__((ext_vector_type(8))) unsigned short ushort8v;
typedef __attribute__((ext_vector_type(4))) float f32x4;
typedef __attribute__((ext_vector_type(4))) unsigned short ushort4v;

// ---- workspace layout (bytes) ----
#define MOD_OFF    ((size_t)0)                       // f32 3*6144
#define XM_OFF     ((size_t)73728)                   // bf16 2304*1024 (also LN buffer for MLPs)
#define QKV_OFF    ((size_t)4792320)                 // bf16 2304*3072 (t1 overlays)
#define QB_OFF     ((size_t)18948096)                // bf16 16*2304*64
#define KB_OFF     ((size_t)23666688)
#define VTB_OFF    ((size_t)28385280)
#define ATT_OFF    ((size_t)33103872)                // bf16 2304*1024 (vtmp overlays pre-attn)
#define S1_OFF     ((size_t)37822464)                // f32 2304*1024
#define QKVWT_OFF  ((size_t)49356800)                // bf16 3*3072*1024
#define PROJWT_OFF ((size_t)68231168)                // bf16 3*1024*1024
#define W1T_OFF    ((size_t)74522624)                // bf16 3*4096*1024
#define W2T_OFF    ((size_t)99688448)                // bf16 3*1024*4096 (optional, if ws large)
#define W2T_END    ((size_t)124854272)

static __device__ __forceinline__ ushort f2bf(float x) {
    __hip_bfloat16 b = __float2bfloat16(x);
    return *reinterpret_cast<ushort*>(&b);
}
static __device__ __forceinline__ float bf2f(ushort u) {
    return __uint_as_float(((unsigned)u) << 16);
}

typedef __attribute__((address_space(1))) const unsigned char gas_t;
typedef __attribute__((address_space(3))) unsigned char las_t;
static __device__ __forceinline__ void gload16(const void* g, void* l) {
    __builtin_amdgcn_global_load_lds((gas_t*)g, (las_t*)l, 16, 0, 0);
}

// ---------------- fused: mod GEMV (144 blocks) + weight transpose-convert ----------------
// bid<144: mod GEMV, 128 outputs/block, 8-way K-split, float4 loads.
// else: 32x32 transpose tiles: qkv (9216), proj (3072), w1 (12288), [w2 (12288) if grid big].
__global__ __launch_bounds__(256) void k_wt_all(const float* __restrict__ vec,
                                                const float* __restrict__ modw,
                                                const float* __restrict__ modb,
                                                float* __restrict__ mod,
                                                const float* __restrict__ qkvw,
                                                const float* __restrict__ projw,
                                                const float* __restrict__ w1,
                                                const float* __restrict__ w2,
                                                ushort* __restrict__ qkvwt,
                                                ushort* __restrict__ projwt,
                                                ushort* __restrict__ w1t,
                                                ushort* __restrict__ w2t) {
    __shared__ float tb[32][33];
    __shared__ float svs[DMODEL];
    __shared__ float pl[8][128];
    int bid = blockIdx.x;
    int tid = threadIdx.x;
    if (bid < 144) {
        // ---- mod GEMV ----
        float4 vv = *reinterpret_cast<const float4*>(vec + tid*4);
        float4 sv4;
        sv4.x = vv.x / (1.0f + __expf(-vv.x));
        sv4.y = vv.y / (1.0f + __expf(-vv.y));
        sv4.z = vv.z / (1.0f + __expf(-vv.z));
        sv4.w = vv.w / (1.0f + __expf(-vv.w));
        *reinterpret_cast<float4*>(&svs[tid*4]) = sv4;
        __syncthreads();
        int g0 = bid * 128;
        int i  = g0 / 6144;
        int j0 = g0 - i * 6144;
        int jl = tid & 31, ko = tid >> 5;
        const float* wp = modw + (size_t)i * 1024 * 6144 + j0 + jl*4;
        float4 acc = {0.f,0.f,0.f,0.f};
        for (int kk = 0; kk < 128; kk++) {
            int k = kk*8 + ko;
            float4 wv = *reinterpret_cast<const float4*>(wp + (size_t)k * 6144);
            float s = svs[k];
            acc.x += s*wv.x; acc.y += s*wv.y; acc.z += s*wv.z; acc.w += s*wv.w;
        }
        pl[ko][jl*4+0] = acc.x; pl[ko][jl*4+1] = acc.y;
        pl[ko][jl*4+2] = acc.z; pl[ko][jl*4+3] = acc.w;
        __syncthreads();
        if (tid < 128) {
            float s = 0.f;
#pragma unroll
            for (int k = 0; k < 8; k++) s += pl[k][tid];
            mod[g0 + tid] = s + modb[g0 + tid];
        }
        return;
    }
    bid -= 144;
    const float* W; ushort* WT; int K, N;
    if (bid < 9216) {
        int s = bid / 3072, r = bid % 3072;
        K = 1024; N = 3072;
        W = qkvw + (size_t)s * K * N; WT = qkvwt + (size_t)s * N * K;
        bid = r;
    } else if (bid < 12288) {
        int b = bid - 9216; int s = b / 1024, r = b % 1024;
        K = 1024; N = 1024;
        W = projw + (size_t)s * K * N; WT = projwt + (size_t)s * N * K;
        bid = r;
    } else if (bid < 24576) {
        int b = bid - 12288; int s = b / 4096, r = b % 4096;
        K = 1024; N = 4096;
        W = w1 + (size_t)s * K * N; WT = w1t + (size_t)s * N * K;
        bid = r;
    } else {
        int b = bid - 24576; int s = b / 4096, r = b % 4096;
        K = 4096; N = 1024;     // w2: f32 [4096][1024] -> bf16 [1024][4096]
        W = w2 + (size_t)s * K * N; WT = w2t + (size_t)s * N * K;
        bid = r;
    }
    int nt = bid % (N >> 5), kt = bid / (N >> 5);
    int r = tid >> 5, c = tid & 31;
#pragma unroll
    for (int i = 0; i < 4; i++)
        tb[r + i*8][c] = W[(size_t)(kt*32 + r + i*8) * N + nt*32 + c];
    __syncthreads();
#pragma unroll
    for (int i = 0; i < 4; i++)
        WT[(size_t)(nt*32 + r + i*8) * K + kt*32 + c] = f2bf(tb[c][r + i*8]);
}

__global__ __launch_bounds__(256) void k_wt_slice(const float* __restrict__ W,
                                                  ushort* __restrict__ WT,
                                                  int K, int N) {
    int nt = blockIdx.x, kt = blockIdx.y;
    __shared__ float tb[32][33];
    int r = threadIdx.x >> 5, c = threadIdx.x & 31;
#pragma unroll
    for (int i = 0; i < 4; i++)
        tb[r + i*8][c] = W[(size_t)(kt*32 + r + i*8) * N + nt*32 + c];
    __syncthreads();
#pragma unroll
    for (int i = 0; i < 4; i++)
        WT[(size_t)(nt*32 + r + i*8) * K + kt*32 + c] = f2bf(tb[c][r + i*8]);
}

// ---------------- LN + (1+sc)*x + sh -> bf16, stream-select ----------------
__global__ __launch_bounds__(256) void k_ln_mod1(const float* __restrict__ img,
                                                 const float* __restrict__ tmp,
                                                 const float* __restrict__ txt,
                                                 const float* __restrict__ mod,
                                                 ushort* __restrict__ xm) {
    int l = blockIdx.x;
    const float* src; int strm;
    if (l < L_TXT)              { src = txt + (size_t)l * DMODEL;            strm = 2; }
    else if (l < L_TXT + L_IMG) { src = img + (size_t)(l - L_TXT) * DMODEL;  strm = 0; }
    else                        { src = tmp + (size_t)(l - L_TXT - L_IMG) * DMODEL; strm = 1; }

    int d = threadIdx.x * 4;
    float4 x = *reinterpret_cast<const float4*>(src + d);
    float s  = x.x + x.y + x.z + x.w;
    float s2 = x.x*x.x + x.y*x.y + x.z*x.z + x.w*x.w;
#pragma unroll
    for (int o = 32; o > 0; o >>= 1) { s += __shfl_xor(s, o); s2 += __shfl_xor(s2, o); }
    __shared__ float red[8];
    int wave = threadIdx.x >> 6, lane = threadIdx.x & 63;
    if (lane == 0) { red[wave*2] = s; red[wave*2+1] = s2; }
    __syncthreads();
    if (threadIdx.x == 0) {
        float a = 0.f, b = 0.f;
        for (int w = 0; w < 4; w++) { a += red[w*2]; b += red[w*2+1]; }
        red[0] = a; red[1] = b;
    }
    __syncthreads();
    float mean = red[0] * (1.0f/DMODEL);
    float var  = red[1] * (1.0f/DMODEL) - mean*mean;
    float inv  = rsqrtf(var + EPSV);

    const float* sh = mod + strm*6144;
    const float* sc = sh + 1024;
    float4 shv = *reinterpret_cast<const float4*>(sh + d);
    float4 scv = *reinterpret_cast<const float4*>(sc + d);
    ushort4v o;
    o.x = f2bf((1.f+scv.x)*((x.x-mean)*inv) + shv.x);
    o.y = f2bf((1.f+scv.y)*((x.y-mean)*inv) + shv.y);
    o.z = f2bf((1.f+scv.z)*((x.z-mean)*inv) + shv.z);
    o.w = f2bf((1.f+scv.w)*((x.w-mean)*inv) + shv.w);
    *reinterpret_cast<ushort4v*>(xm + (size_t)l*DMODEL + d) = o;
}

// ---------------- generic LN + modulate -> bf16 ----------------
__global__ __launch_bounds__(256) void k_ln_mod2(const float* __restrict__ src,
                                                 const float* __restrict__ sh,
                                                 const float* __restrict__ sc,
                                                 ushort* __restrict__ out) {
    int r = blockIdx.x;
    const float* srow = src + (size_t)r * DMODEL;
    int d = threadIdx.x * 4;
    float4 x = *reinterpret_cast<const float4*>(srow + d);
    float s  = x.x + x.y + x.z + x.w;
    float s2 = x.x*x.x + x.y*x.y + x.z*x.z + x.w*x.w;
#pragma unroll
    for (int o = 32; o > 0; o >>= 1) { s += __shfl_xor(s, o); s2 += __shfl_xor(s2, o); }
    __shared__ float red[8];
    int wave = threadIdx.x >> 6, lane = threadIdx.x & 63;
    if (lane == 0) { red[wave*2] = s; red[wave*2+1] = s2; }
    __syncthreads();
    if (threadIdx.x == 0) {
        float a = 0.f, b = 0.f;
        for (int w = 0; w < 4; w++) { a += red[w*2]; b += red[w*2+1]; }
        red[0] = a; red[1] = b;
    }
    __syncthreads();
    float mean = red[0] * (1.0f/DMODEL);
    float var  = red[1] * (1.0f/DMODEL) - mean*mean;
    float inv  = rsqrtf(var + EPSV);
    float4 shv = *reinterpret_cast<const float4*>(sh + d);
    float4 scv = *reinterpret_cast<const float4*>(sc + d);
    ushort4v o;
    o.x = f2bf((1.f+scv.x)*((x.x-mean)*inv) + shv.x);
    o.y = f2bf((1.f+scv.y)*((x.y-mean)*inv) + shv.y);
    o.z = f2bf((1.f+scv.z)*((x.z-mean)*inv) + shv.z);
    o.w = f2bf((1.f+scv.w)*((x.w-mean)*inv) + shv.w);
    *reinterpret_cast<ushort4v*>(out + (size_t)r*DMODEL + d) = o;
}

// ---------------- multi-stream bf16 MFMA GEMM, templated BM (128 or 64), BN=128, BK=64 ----------------
__device__ __forceinline__ float gelu_fast(float x) {
    return x / (1.0f + __expf(-1.5957691216057308f * (x + 0.044715f * x * x * x)));
}

template<int MODE, int BM, typename OutT>
__global__ __launch_bounds__(256) void k_gemm_ms(const ushort* __restrict__ A_t,
                                                 const ushort* __restrict__ A_i,
                                                 const ushort* __restrict__ A_m,
                                                 const ushort* __restrict__ BT,
                                                 const float* __restrict__ bias,
                                                 const float* __restrict__ res_t,
                                                 const float* __restrict__ res_i,
                                                 const float* __restrict__ res_m,
                                                 const float* __restrict__ mod, int gidx,
                                                 OutT* __restrict__ out_t,
                                                 OutT* __restrict__ out_i,
                                                 OutT* __restrict__ out_m,
                                                 int N, int K, int ry0) {
    constexpr int MI = BM / 32;          // M-fragments per wave
    const int brow = (ry0 + blockIdx.y) * BM;
    int s, lrow;
    if (brow < 256)       { s = 2; lrow = brow; }
    else if (brow < 1280) { s = 0; lrow = brow - 256; }
    else                  { s = 1; lrow = brow - 1280; }

    const ushort* A = (s==2 ? A_t : s==0 ? A_i : A_m) + (size_t)lrow * K;
    const ushort* BTs = BT + (size_t)s * N * K;
    const float* bi = bias ? bias + (size_t)s * N : nullptr;
    const float* resl = (MODE==2) ? ((s==2 ? res_t : s==0 ? res_i : res_m) + (size_t)lrow * N) : nullptr;
    const float* gate = (MODE==2) ? (mod + s*6144 + gidx*1024) : nullptr;
    OutT* Cl = (s==2 ? out_t : s==0 ? out_i : out_m) + (size_t)lrow * N;

    __shared__ ushort Asl[BM*64];
    __shared__ ushort Bsl[128*64];
    const int tid = threadIdx.x;
    const int lane = tid & 63, w = tid >> 6;
    const int wr = w >> 1, wc = w & 1;
    const int bn = blockIdx.x * 128;
    const int r15 = lane & 15, g4 = lane >> 4;

    f32x4 acc[MI][4];
#pragma unroll
    for (int i = 0; i < MI; i++)
#pragma unroll
        for (int j = 0; j < 4; j++) acc[i][j] = (f32x4){0.f,0.f,0.f,0.f};

    for (int k0 = 0; k0 < K; k0 += 64) {
#pragma unroll
        for (int i = 0; i < BM/32; i++) {
            int chunk = i*4 + w;
            int seg = chunk*64 + lane;
            int row = seg >> 3;
            int gs  = (seg & 7) ^ (row & 7);
            gload16(A + (size_t)row * K + k0 + gs*8, Asl + (size_t)chunk * 512);
        }
#pragma unroll
        for (int i = 0; i < 4; i++) {
            int chunk = i*4 + w;
            int seg = chunk*64 + lane;
            int row = seg >> 3;
            int gs  = (seg & 7) ^ (row & 7);
            gload16(BTs + (size_t)(bn + row) * K + k0 + gs*8, Bsl + (size_t)chunk * 512);
        }
        __syncthreads();
#pragma unroll
        for (int kk = 0; kk < 2; kk++) {
            short8b a[MI], b[4];
#pragma unroll
            for (int mi = 0; mi < MI; mi++) {
                int row = wr*(MI*16) + mi*16 + r15;
                int c   = kk*4 + g4;
                a[mi] = *reinterpret_cast<const short8b*>(&Asl[row*64 + ((c ^ (row & 7)))*8]);
            }
#pragma unroll
            for (int ni = 0; ni < 4; ni++) {
                int row = wc*64 + ni*16 + r15;
                int c   = kk*4 + g4;
                b[ni] = *reinterpret_cast<const short8b*>(&Bsl[row*64 + ((c ^ (row & 7)))*8]);
            }
#pragma unroll
            for (int mi = 0; mi < MI; mi++)
#pragma unroll
                for (int ni = 0; ni < 4; ni++)
                    acc[mi][ni] = __builtin_amdgcn_mfma_f32_16x16x32_bf16(a[mi], b[ni], acc[mi][ni], 0, 0, 0);
        }
        __syncthreads();
    }

#pragma unroll
    for (int mi = 0; mi < MI; mi++) {
#pragma unroll
        for (int ni = 0; ni < 4; ni++) {
            int col = bn + wc*64 + ni*16 + r15;
            float bv = bi ? bi[col] : 0.f;
#pragma unroll
            for (int r = 0; r < 4; r++) {
                int rr = wr*(MI*16) + mi*16 + g4*4 + r;
                float v = acc[mi][ni][r] + bv;
                if (MODE == 1) v = gelu_fast(v);
                if (MODE == 2) v = resl[(size_t)rr * N + col] + gate[col] * v;
                if (sizeof(OutT) == 2) Cl[(size_t)rr * N + col] = (OutT)f2bf(v);
                else                   Cl[(size_t)rr * N + col] = (OutT)v;
            }
        }
    }
}

// ---------------- qkv finalize: RMS + RoPE -> bf16 Q,K [H][L][64], Vtmp [H][L][64] ----------------
__global__ __launch_bounds__(256) void k_qkvfin(const ushort* __restrict__ qkv,
                                                const float* __restrict__ pe,
                                                const float* __restrict__ qs,
                                                const float* __restrict__ ks,
                                                ushort* __restrict__ Q,
                                                ushort* __restrict__ K,
                                                ushort* __restrict__ Vt) {
    int wid  = (blockIdx.x * 256 + threadIdx.x) >> 6;
    int lane = threadIdx.x & 63;
    int l = wid >> 4;
    int h = wid & 15;
    int strm;
    if (l < L_TXT) strm = 2; else if (l < L_TXT + L_IMG) strm = 0; else strm = 1;

    const ushort* row = qkv + (size_t)l * 3 * DMODEL;
    float q = bf2f(row[h*HDIM + lane]);
    float k = bf2f(row[DMODEL + h*HDIM + lane]);
    float v = bf2f(row[2*DMODEL + h*HDIM + lane]);

    float sq = q*q, sk = k*k;
#pragma unroll
    for (int o = 32; o > 0; o >>= 1) { sq += __shfl_xor(sq, o); sk += __shfl_xor(sk, o); }
    float rq = q * rsqrtf(sq * (1.0f/HDIM) + EPSV) * qs[strm*HDIM + lane];
    float rk = k * rsqrtf(sk * (1.0f/HDIM) + EPSV) * ks[strm*HDIM + lane];

    // BUG replication: temporal stream's V is its RMS'd Q (pre-RoPE)
    float vout = (strm == 1) ? rq : v;

    float rq_p = __shfl_xor(rq, 1);
    float rk_p = __shfl_xor(rk, 1);
    float qe = (lane & 1) ? rq_p : rq;
    float qo = (lane & 1) ? rq : rq_p;
    float ke = (lane & 1) ? rk_p : rk;
    float ko = (lane & 1) ? rk : rk_p;
    const float* pel = pe + (size_t)l*128 + (lane >> 1)*4 + (lane & 1)*2;
    float qr = pel[0]*qe + pel[1]*qo;
    float kr = pel[0]*ke + pel[1]*ko;

    size_t idx = ((size_t)h * LTOT + l) * HDIM + lane;
    Q[idx] = f2bf(qr);
    K[idx] = f2bf(kr);
    Vt[idx] = f2bf(vout);
}

// ---------------- V transpose: [H][L][64] -> [H][64][L], 64x64 LDS tiles ----------------
__global__ __launch_bounds__(256) void k_vt(const ushort* __restrict__ Vt,
                                            ushort* __restrict__ VT) {
    int h  = blockIdx.x >> 5;          // 0..15  (36 tiles -> use /36 grid)
    int lt = blockIdx.x & 31;
    if (lt >= 36) return;              // padded grid
    h = blockIdx.x / 36; lt = blockIdx.x % 36;
    int l0 = lt * 64;
    __shared__ ushort tbuf[64][72];
    int tid = threadIdx.x;
    {
        int l = tid >> 2, dc = (tid & 3) * 16;
        const ushort* src = Vt + ((size_t)NH*0 + (size_t)h * LTOT + l0 + l) * 64 + dc;
        ushort8v a = *reinterpret_cast<const ushort8v*>(src);
        ushort8v b = *reinterpret_cast<const ushort8v*>(src + 8);
#pragma unroll
        for (int i = 0; i < 8; i++) { tbuf[l][dc+i] = a[i]; tbuf[l][dc+8+i] = b[i]; }
    }
    __syncthreads();
    {
        int d = tid >> 2, lc = (tid & 3) * 16;
        ushort8v a, b;
#pragma unroll
        for (int i = 0; i < 8; i++) { a[i] = tbuf[lc+i][d]; b[i] = tbuf[lc+8+i][d]; }
        ushort* dst = VT + ((size_t)h * 64 + d) * LTOT + l0 + lc;
        *reinterpret_cast<ushort8v*>(dst) = a;
        *reinterpret_cast<ushort8v*>(dst + 8) = b;
    }
}

// ---------------- MFMA flash attention with LDS-staged K/V ----------------
__global__ __launch_bounds__(256) void k_attn_mfma(const ushort* __restrict__ Qb,
                                                   const ushort* __restrict__ Kb,
                                                   const ushort* __restrict__ VTb,
                                                   ushort* __restrict__ att) {
    const int tid = threadIdx.x;
    const int w = tid >> 6, lane = tid & 63;
    const int h  = blockIdx.x / 36;
    const int qt = blockIdx.x % 36;
    const int qbase = qt*64 + w*16;
    const int g = lane >> 4;
    const int q = lane & 15;

    __shared__ ushort Ksl[64*64];
    __shared__ ushort Vsl[64*64];
    __shared__ ushort plds[4][1024];
    ushort* P = plds[w];

    const ushort* Kg = Kb  + (size_t)h * LTOT * 64;
    const ushort* Vg = VTb + (size_t)h * 64 * LTOT;

    const ushort* qp = Qb + ((size_t)h * LTOT + qbase + q) * 64 + g*8;
    const short8b qf0 = *reinterpret_cast<const short8b*>(qp);
    const short8b qf1 = *reinterpret_cast<const short8b*>(qp + 32);

    f32x4 out[4];
#pragma unroll
    for (int d = 0; d < 4; d++) out[d] = (f32x4){0.f,0.f,0.f,0.f};
    float m = -1e30f, lsum = 0.f;

    for (int kv0 = 0; kv0 < LTOT; kv0 += 64) {
#pragma unroll
        for (int i = 0; i < 2; i++) {
            int seg = i*256 + tid;
            int row = seg >> 3;
            int gs  = (seg & 7) ^ (row & 7);
            gload16(Kg + (size_t)(kv0 + row)*64 + gs*8, Ksl + (size_t)(i*256 + w*64)*8);
            gload16(Vg + (size_t)row*LTOT + kv0 + gs*8, Vsl + (size_t)(i*256 + w*64)*8);
        }
        __syncthreads();

        f32x4 s[4];
#pragma unroll
        for (int ks = 0; ks < 4; ks++) {
            int r = ks*16 + q;
            short8b kf0 = *reinterpret_cast<const short8b*>(&Ksl[r*64 + ((g     ^ (r & 7)))*8]);
            short8b kf1 = *reinterpret_cast<const short8b*>(&Ksl[r*64 + (((4+g) ^ (r & 7)))*8]);
            f32x4 acc = (f32x4){0.f,0.f,0.f,0.f};
            acc = __builtin_amdgcn_mfma_f32_16x16x32_bf16(kf0, qf0, acc, 0, 0, 0);
            acc = __builtin_amdgcn_mfma_f32_16x16x32_bf16(kf1, qf1, acc, 0, 0, 0);
            s[ks] = acc;
        }
        float tmax = -1e30f;
#pragma unroll
        for (int ks = 0; ks < 4; ks++)
#pragma unroll
            for (int r = 0; r < 4; r++) tmax = fmaxf(tmax, s[ks][r]);
        tmax = fmaxf(tmax, __shfl_xor(tmax, 16));
        tmax = fmaxf(tmax, __shfl_xor(tmax, 32));
        float newm = fmaxf(m, tmax * 0.125f);
        float c = __expf(m - newm);
        float p[16];
        float tsum = 0.f;
#pragma unroll
        for (int ks = 0; ks < 4; ks++)
#pragma unroll
            for (int r = 0; r < 4; r++) {
                float pv = __expf(s[ks][r] * 0.125f - newm);
                p[ks*4+r] = pv;
                tsum += pv;
            }
        tsum += __shfl_xor(tsum, 16);
        tsum += __shfl_xor(tsum, 32);
        lsum = lsum * c + tsum;
        m = newm;
#pragma unroll
        for (int d = 0; d < 4; d++) out[d] *= c;

#pragma unroll
        for (int ks = 0; ks < 4; ks++) {
            ushort4v pk;
            pk.x = f2bf(p[ks*4+0]); pk.y = f2bf(p[ks*4+1]);
            pk.z = f2bf(p[ks*4+2]); pk.w = f2bf(p[ks*4+3]);
            int widx = (q*64 + ks*16 + g*4) ^ ((q & 7) << 3);
            *reinterpret_cast<ushort4v*>(&P[widx]) = pk;
        }
#pragma unroll
        for (int c2 = 0; c2 < 2; c2++) {
            int ridx = (q*64 + c2*32 + g*8) ^ ((q & 7) << 3);
            short8b pf = *reinterpret_cast<const short8b*>(&P[ridx]);
#pragma unroll
            for (int ds = 0; ds < 4; ds++) {
                int d = ds*16 + q;
                short8b vf = *reinterpret_cast<const short8b*>(&Vsl[d*64 + (((c2*4+g) ^ (d & 7)))*8]);
                out[ds] = __builtin_amdgcn_mfma_f32_16x16x32_bf16(vf, pf, out[ds], 0, 0, 0);
            }
        }
        __syncthreads();
    }

    float inv = 1.0f / lsum;
    ushort* orow = att + (size_t)(qbase + q) * DMODEL + h * HDIM;
#pragma unroll
    for (int ds = 0; ds < 4; ds++) {
        ushort4v o4;
        o4.x = f2bf(out[ds][0]*inv); o4.y = f2bf(out[ds][1]*inv);
        o4.z = f2bf(out[ds][2]*inv); o4.w = f2bf(out[ds][3]*inv);
        *reinterpret_cast<ushort4v*>(orow + ds*16 + g*4) = o4;
    }
}

// ---------------- launch ----------------
extern "C" void kernel_launch(void* const* d_in, const int* in_sizes, int n_in,
                              void* d_out, int out_size, void* d_ws, size_t ws_size,
                              hipStream_t stream) {
    const float* img  = (const float*)d_in[0];
    const float* tmp  = (const float*)d_in[1];
    const float* txt  = (const float*)d_in[2];
    const float* vec  = (const float*)d_in[3];
    const float* pe   = (const float*)d_in[4];
    const float* modw = (const float*)d_in[5];
    const float* modb = (const float*)d_in[6];
    const float* qkvw = (const float*)d_in[7];
    const float* qsc  = (const float*)d_in[8];
    const float* ksc  = (const float*)d_in[9];
    const float* projw= (const float*)d_in[10];
    const float* projb= (const float*)d_in[11];
    const float* w1   = (const float*)d_in[12];
    const float* b1   = (const float*)d_in[13];
    const float* w2   = (const float*)d_in[14];
    const float* b2   = (const float*)d_in[15];

    char* wsb = (char*)d_ws;
    float*  mod    = (float*) (wsb + MOD_OFF);
    ushort* xm     = (ushort*)(wsb + XM_OFF);
    ushort* qkv    = (ushort*)(wsb + QKV_OFF);
    ushort* t1     = (ushort*)(wsb + QKV_OFF);
    ushort* Qb     = (ushort*)(wsb + QB_OFF);
    ushort* Kb     = (ushort*)(wsb + KB_OFF);
    ushort* VTb    = (ushort*)(wsb + VTB_OFF);
    ushort* vtmp   = (ushort*)(wsb + ATT_OFF);      // overlay: dead before attn writes att
    ushort* att    = (ushort*)(wsb + ATT_OFF);
    float*  s1     = (float*) (wsb + S1_OFF);
    ushort* qkvwt  = (ushort*)(wsb + QKVWT_OFF);
    ushort* projwt = (ushort*)(wsb + PROJWT_OFF);
    ushort* w1t    = (ushort*)(wsb + W1T_OFF);

    const bool bigws = ws_size >= W2T_END;
    ushort* w2t = bigws ? (ushort*)(wsb + W2T_OFF) : w1t;   // fallback: overlay w1t

    float* out_img = (float*)d_out;
    float* out_tmp = out_img + (size_t)L_IMG * DMODEL;
    float* out_txt = out_tmp + (size_t)L_TMP * DMODEL;

    // fused conversions + mod GEMV
    int wt_blocks = bigws ? (144 + 24576 + 12288) : (144 + 24576);
    k_wt_all<<<wt_blocks, 256, 0, stream>>>(vec, modw, modb, mod,
                                            qkvw, projw, w1, w2,
                                            qkvwt, projwt, w1t, w2t);
    k_ln_mod1<<<LTOT, 256, 0, stream>>>(img, tmp, txt, mod, xm);

    // QKV: merged dispatch, BM=128
    k_gemm_ms<0, 128, ushort><<<dim3(24, 18), 256, 0, stream>>>(
        xm, xm + (size_t)256*DMODEL, xm + (size_t)1280*DMODEL,
        qkvwt, nullptr, nullptr, nullptr, nullptr, nullptr, 0,
        qkv, qkv + (size_t)256*3072, qkv + (size_t)1280*3072, 3072, DMODEL, 0);

    k_qkvfin<<<9216, 256, 0, stream>>>(qkv, pe, qsc, ksc, Qb, Kb, vtmp);
    k_vt<<<NH*36, 256, 0, stream>>>(vtmp, VTb);
    k_attn_mfma<<<NH*36, 256, 0, stream>>>(Qb, Kb, VTb, att);

    // proj + residual + gate1 -> s1 (BM=64: 288 blocks)
    k_gemm_ms<2, 64, float><<<dim3(8, 36), 256, 0, stream>>>(
        att, att + (size_t)256*DMODEL, att + (size_t)1280*DMODEL,
        projwt, projb, txt, img, tmp, mod, 2,
        s1, s1 + (size_t)256*DMODEL, s1 + (size_t)1280*DMODEL, DMODEL, DMODEL, 0);

    // ---- phase A: txt + img MLP ----
    k_ln_mod2<<<L_TXT, 256, 0, stream>>>(s1,                        mod + 2*6144 + 3*1024, mod + 2*6144 + 4*1024, xm);
    k_ln_mod2<<<L_IMG, 256, 0, stream>>>(s1 + (size_t)256*DMODEL,   mod + 0*6144 + 3*1024, mod + 0*6144 + 4*1024, xm + (size_t)256*DMODEL);
    k_gemm_ms<1, 128, ushort><<<dim3(32, 10), 256, 0, stream>>>(
        xm, xm + (size_t)256*DMODEL, xm + (size_t)1280*DMODEL,
        w1t, b1, nullptr, nullptr, nullptr, nullptr, 0,
        t1, t1 + (size_t)256*DMLP, t1, DMLP, DMODEL, 0);
    if (!bigws) {
        k_wt_slice<<<dim3(32, 128), 256, 0, stream>>>(w2,                          w1t,                          DMLP, DMODEL);
        k_wt_slice<<<dim3(32, 128), 256, 0, stream>>>(w2 + (size_t)2*DMLP*DMODEL,  w1t + (size_t)2*DMLP*DMODEL,  DMLP, DMODEL);
    }
    // mlp2 phase A (BM=64: rows 0..1279 -> 20 tiles)
    k_gemm_ms<2, 64, float><<<dim3(8, 20), 256, 0, stream>>>(
        t1, t1 + (size_t)256*DMLP, t1,
        w2t, b2, s1, s1 + (size_t)256*DMODEL, s1 + (size_t)1280*DMODEL, mod, 5,
        out_txt, out_img, out_tmp, DMODEL, DMLP, 0);

    // ---- phase B: temporal MLP (LN input is FINAL img — reference quirk) ----
    k_ln_mod2<<<L_TMP, 256, 0, stream>>>(out_img, mod + 1*6144 + 3*1024, mod + 1*6144 + 4*1024, xm + (size_t)1280*DMODEL);
    k_gemm_ms<1, 128, ushort><<<dim3(32, 8), 256, 0, stream>>>(
        xm, xm + (size_t)256*DMODEL, xm + (size_t)1280*DMODEL,
        w1t, b1, nullptr, nullptr, nullptr, nullptr, 0,
        t1, t1, t1, DMLP, DMODEL, 10);
    if (!bigws) {
        k_wt_slice<<<dim3(32, 128), 256, 0, stream>>>(w2 + (size_t)DMLP*DMODEL, w1t + (size_t)DMLP*DMODEL, DMLP, DMODEL);
    }
    // mlp2 phase B (BM=64: rows 1280..2303 -> 16 tiles, ry0=20)
    k_gemm_ms<2, 64, float><<<dim3(8, 16), 256, 0, stream>>>(
        t1, t1, t1,
        w2t, b2, s1, s1, s1 + (size_t)1280*DMODEL, mod, 5,
        out_txt, out_img, out_tmp, DMODEL, DMLP, 20);
}

// Round 6
// 354.799 us; speedup vs baseline: 9.4231x; 1.0052x over previous
//
#include <hip/hip_runtime.h>
#include <hip/hip_bf16.h>

#define L_TXT 256
#define L_IMG 1024
#define L_TMP 1024
#define LTOT  2304
#define DMODEL 1024
#define NH 16
#define HDIM 64
#define DMLP 4096
#define EPSV 1e-6f

typedef unsigned short ushort;
typedef __attribute__((ext_vector_type(8))) short short8b;   // 8 x bf16
typedef __attribute__((ext_vector_type(8))) unsigned short ushort8v;
typedef __attribute__((ext_vector_type(4))) float f32x4;
typedef __attribute__((ext_vector_type(4))) unsigned short ushort4v;

// ---- workspace layout (bytes) ----
#define MOD_OFF    ((size_t)0)                       // f32 3*6144
#define XM_OFF     ((size_t)73728)                   // bf16 2304*1024
#define QKV_OFF    ((size_t)4792320)                 // bf16 2304*3072 (t1 overlays)
#define QB_OFF     ((size_t)18948096)                // bf16 16*2304*64
#define KB_OFF     ((size_t)23666688)
#define VTB_OFF    ((size_t)28385280)
#define ATT_OFF    ((size_t)33103872)                // bf16 2304*1024
#define S1_OFF     ((size_t)37822464)                // f32 2304*1024
#define QKVWT_OFF  ((size_t)49356800)                // bf16 3*3072*1024
#define PROJWT_OFF ((size_t)68231168)                // bf16 3*1024*1024
#define W1T_OFF    ((size_t)74522624)                // bf16 3*4096*1024
#define W2T_OFF    ((size_t)99688448)                // bf16 3*1024*4096 (if ws large)
#define W2T_END    ((size_t)124854272)

static __device__ __forceinline__ ushort f2bf(float x) {
    __hip_bfloat16 b = __float2bfloat16(x);
    return *reinterpret_cast<ushort*>(&b);
}
static __device__ __forceinline__ float bf2f(ushort u) {
    return __uint_as_float(((unsigned)u) << 16);
}

typedef __attribute__((address_space(1))) const unsigned char gas_t;
typedef __attribute__((address_space(3))) unsigned char las_t;
static __device__ __forceinline__ void gload16(const void* g, void* l) {
    __builtin_amdgcn_global_load_lds((gas_t*)g, (las_t*)l, 16, 0, 0);
}

// ---------------- fused: mod GEMV (144 blocks) + 64x64 weight transpose-convert ----------------
__global__ __launch_bounds__(256) void k_conv(const float* __restrict__ vec,
                                              const float* __restrict__ modw,
                                              const float* __restrict__ modb,
                                              float* __restrict__ mod,
                                              const float* __restrict__ qkvw,
                                              const float* __restrict__ projw,
                                              const float* __restrict__ w1,
                                              const float* __restrict__ w2,
                                              ushort* __restrict__ qkvwt,
                                              ushort* __restrict__ projwt,
                                              ushort* __restrict__ w1t,
                                              ushort* __restrict__ w2t) {
    __shared__ float tb[64][65];
    int bid = blockIdx.x;
    int tid = threadIdx.x;
    if (bid < 144) {
        // ---- mod GEMV: 128 outputs/block, 8-way K-split ----
        __shared__ float svs[DMODEL];
        __shared__ float pl[8][128];
        float4 vv = *reinterpret_cast<const float4*>(vec + tid*4);
        float4 sv4;
        sv4.x = vv.x / (1.0f + __expf(-vv.x));
        sv4.y = vv.y / (1.0f + __expf(-vv.y));
        sv4.z = vv.z / (1.0f + __expf(-vv.z));
        sv4.w = vv.w / (1.0f + __expf(-vv.w));
        *reinterpret_cast<float4*>(&svs[tid*4]) = sv4;
        __syncthreads();
        int g0 = bid * 128;
        int i  = g0 / 6144;
        int j0 = g0 - i * 6144;
        int jl = tid & 31, ko = tid >> 5;
        const float* wp = modw + (size_t)i * 1024 * 6144 + j0 + jl*4;
        float4 acc = {0.f,0.f,0.f,0.f};
        for (int kk = 0; kk < 128; kk++) {
            int k = kk*8 + ko;
            float4 wv = *reinterpret_cast<const float4*>(wp + (size_t)k * 6144);
            float s = svs[k];
            acc.x += s*wv.x; acc.y += s*wv.y; acc.z += s*wv.z; acc.w += s*wv.w;
        }
        pl[ko][jl*4+0] = acc.x; pl[ko][jl*4+1] = acc.y;
        pl[ko][jl*4+2] = acc.z; pl[ko][jl*4+3] = acc.w;
        __syncthreads();
        if (tid < 128) {
            float s = 0.f;
#pragma unroll
            for (int k = 0; k < 8; k++) s += pl[k][tid];
            mod[g0 + tid] = s + modb[g0 + tid];
        }
        return;
    }
    int b = bid - 144;
    const float* W; ushort* WT; int K, N, nt, kt;
    if (b < 2304) {                 // qkv: K=1024, N=3072 -> 16x48 tiles per s
        int s = b / 768, r = b % 768;
        K = 1024; N = 3072; nt = r % 48; kt = r / 48;
        W = qkvw + (size_t)s * K * N; WT = qkvwt + (size_t)s * N * K;
    } else if (b < 3072) {          // proj: 16x16
        b -= 2304; int s = b / 256, r = b % 256;
        K = 1024; N = 1024; nt = r % 16; kt = r / 16;
        W = projw + (size_t)s * K * N; WT = projwt + (size_t)s * N * K;
    } else if (b < 6144) {          // w1: 16x64
        b -= 3072; int s = b / 1024, r = b % 1024;
        K = 1024; N = 4096; nt = r % 64; kt = r / 64;
        W = w1 + (size_t)s * K * N; WT = w1t + (size_t)s * N * K;
    } else {                        // w2: K=4096, N=1024 -> 64x16
        b -= 6144; int s = b / 1024, r = b % 1024;
        K = 4096; N = 1024; nt = r % 16; kt = r / 16;
        W = w2 + (size_t)s * K * N; WT = w2t + (size_t)s * N * K;
    }
    // load 64x64 f32 tile (float4), store to LDS
    {
        int r = tid >> 4, c4 = (tid & 15) * 4;
#pragma unroll
        for (int i = 0; i < 4; i++) {
            float4 v = *reinterpret_cast<const float4*>(W + (size_t)(kt*64 + r + i*16) * N + nt*64 + c4);
            tb[r + i*16][c4+0] = v.x; tb[r + i*16][c4+1] = v.y;
            tb[r + i*16][c4+2] = v.z; tb[r + i*16][c4+3] = v.w;
        }
    }
    __syncthreads();
    // transposed bf16 store: out row n, 64 k's
    {
        int n = tid >> 2, ks = (tid & 3) * 16;
        ushort8v u0, u1;
#pragma unroll
        for (int i = 0; i < 8; i++) u0[i] = f2bf(tb[ks+i][n]);
#pragma unroll
        for (int i = 0; i < 8; i++) u1[i] = f2bf(tb[ks+8+i][n]);
        ushort* dst = WT + (size_t)(nt*64 + n) * K + kt*64 + ks;
        *reinterpret_cast<ushort8v*>(dst)     = u0;
        *reinterpret_cast<ushort8v*>(dst + 8) = u1;
    }
}

// standalone slice variant (w2 fallback when ws too small): grid (N/64, K/64)
__global__ __launch_bounds__(256) void k_conv_slice(const float* __restrict__ W,
                                                    ushort* __restrict__ WT,
                                                    int K, int N) {
    __shared__ float tb[64][65];
    int nt = blockIdx.x, kt = blockIdx.y, tid = threadIdx.x;
    {
        int r = tid >> 4, c4 = (tid & 15) * 4;
#pragma unroll
        for (int i = 0; i < 4; i++) {
            float4 v = *reinterpret_cast<const float4*>(W + (size_t)(kt*64 + r + i*16) * N + nt*64 + c4);
            tb[r + i*16][c4+0] = v.x; tb[r + i*16][c4+1] = v.y;
            tb[r + i*16][c4+2] = v.z; tb[r + i*16][c4+3] = v.w;
        }
    }
    __syncthreads();
    {
        int n = tid >> 2, ks = (tid & 3) * 16;
        ushort8v u0, u1;
#pragma unroll
        for (int i = 0; i < 8; i++) u0[i] = f2bf(tb[ks+i][n]);
#pragma unroll
        for (int i = 0; i < 8; i++) u1[i] = f2bf(tb[ks+8+i][n]);
        ushort* dst = WT + (size_t)(nt*64 + n) * K + kt*64 + ks;
        *reinterpret_cast<ushort8v*>(dst)     = u0;
        *reinterpret_cast<ushort8v*>(dst + 8) = u1;
    }
}

// ---------------- LN + (1+sc)*x + sh -> bf16, stream-select (inputs) ----------------
__global__ __launch_bounds__(256) void k_ln_mod1(const float* __restrict__ img,
                                                 const float* __restrict__ tmp,
                                                 const float* __restrict__ txt,
                                                 const float* __restrict__ mod,
                                                 ushort* __restrict__ xm) {
    int l = blockIdx.x;
    const float* src; int strm;
    if (l < L_TXT)              { src = txt + (size_t)l * DMODEL;            strm = 2; }
    else if (l < L_TXT + L_IMG) { src = img + (size_t)(l - L_TXT) * DMODEL;  strm = 0; }
    else                        { src = tmp + (size_t)(l - L_TXT - L_IMG) * DMODEL; strm = 1; }

    int d = threadIdx.x * 4;
    float4 x = *reinterpret_cast<const float4*>(src + d);
    float s  = x.x + x.y + x.z + x.w;
    float s2 = x.x*x.x + x.y*x.y + x.z*x.z + x.w*x.w;
#pragma unroll
    for (int o = 32; o > 0; o >>= 1) { s += __shfl_xor(s, o); s2 += __shfl_xor(s2, o); }
    __shared__ float red[8];
    int wave = threadIdx.x >> 6, lane = threadIdx.x & 63;
    if (lane == 0) { red[wave*2] = s; red[wave*2+1] = s2; }
    __syncthreads();
    if (threadIdx.x == 0) {
        float a = 0.f, b = 0.f;
        for (int w = 0; w < 4; w++) { a += red[w*2]; b += red[w*2+1]; }
        red[0] = a; red[1] = b;
    }
    __syncthreads();
    float mean = red[0] * (1.0f/DMODEL);
    float var  = red[1] * (1.0f/DMODEL) - mean*mean;
    float inv  = rsqrtf(var + EPSV);

    const float* sh = mod + strm*6144;
    const float* sc = sh + 1024;
    float4 shv = *reinterpret_cast<const float4*>(sh + d);
    float4 scv = *reinterpret_cast<const float4*>(sc + d);
    ushort4v o;
    o.x = f2bf((1.f+scv.x)*((x.x-mean)*inv) + shv.x);
    o.y = f2bf((1.f+scv.y)*((x.y-mean)*inv) + shv.y);
    o.z = f2bf((1.f+scv.z)*((x.z-mean)*inv) + shv.z);
    o.w = f2bf((1.f+scv.w)*((x.w-mean)*inv) + shv.w);
    *reinterpret_cast<ushort4v*>(xm + (size_t)l*DMODEL + d) = o;
}

// ---------------- generic LN + modulate -> bf16 (explicit pointers) ----------------
__global__ __launch_bounds__(256) void k_ln_mod2(const float* __restrict__ src,
                                                 const float* __restrict__ sh,
                                                 const float* __restrict__ sc,
                                                 ushort* __restrict__ out) {
    int r = blockIdx.x;
    const float* srow = src + (size_t)r * DMODEL;
    int d = threadIdx.x * 4;
    float4 x = *reinterpret_cast<const float4*>(srow + d);
    float s  = x.x + x.y + x.z + x.w;
    float s2 = x.x*x.x + x.y*x.y + x.z*x.z + x.w*x.w;
#pragma unroll
    for (int o = 32; o > 0; o >>= 1) { s += __shfl_xor(s, o); s2 += __shfl_xor(s2, o); }
    __shared__ float red[8];
    int wave = threadIdx.x >> 6, lane = threadIdx.x & 63;
    if (lane == 0) { red[wave*2] = s; red[wave*2+1] = s2; }
    __syncthreads();
    if (threadIdx.x == 0) {
        float a = 0.f, b = 0.f;
        for (int w = 0; w < 4; w++) { a += red[w*2]; b += red[w*2+1]; }
        red[0] = a; red[1] = b;
    }
    __syncthreads();
    float mean = red[0] * (1.0f/DMODEL);
    float var  = red[1] * (1.0f/DMODEL) - mean*mean;
    float inv  = rsqrtf(var + EPSV);
    float4 shv = *reinterpret_cast<const float4*>(sh + d);
    float4 scv = *reinterpret_cast<const float4*>(sc + d);
    ushort4v o;
    o.x = f2bf((1.f+scv.x)*((x.x-mean)*inv) + shv.x);
    o.y = f2bf((1.f+scv.y)*((x.y-mean)*inv) + shv.y);
    o.z = f2bf((1.f+scv.z)*((x.z-mean)*inv) + shv.z);
    o.w = f2bf((1.f+scv.w)*((x.w-mean)*inv) + shv.w);
    *reinterpret_cast<ushort4v*>(out + (size_t)r*DMODEL + d) = o;
}

// ---------------- phase-A LN: global rows 0..1279 of s1 (txt then img), out xm ----------------
__global__ __launch_bounds__(256) void k_ln_modg(const float* __restrict__ s1,
                                                 const float* __restrict__ mod,
                                                 ushort* __restrict__ xm) {
    int row = blockIdx.x;
    int strm = row < 256 ? 2 : 0;
    const float* srow = s1 + (size_t)row * DMODEL;
    int d = threadIdx.x * 4;
    float4 x = *reinterpret_cast<const float4*>(srow + d);
    float s  = x.x + x.y + x.z + x.w;
    float s2 = x.x*x.x + x.y*x.y + x.z*x.z + x.w*x.w;
#pragma unroll
    for (int o = 32; o > 0; o >>= 1) { s += __shfl_xor(s, o); s2 += __shfl_xor(s2, o); }
    __shared__ float red[8];
    int wave = threadIdx.x >> 6, lane = threadIdx.x & 63;
    if (lane == 0) { red[wave*2] = s; red[wave*2+1] = s2; }
    __syncthreads();
    if (threadIdx.x == 0) {
        float a = 0.f, b = 0.f;
        for (int w = 0; w < 4; w++) { a += red[w*2]; b += red[w*2+1]; }
        red[0] = a; red[1] = b;
    }
    __syncthreads();
    float mean = red[0] * (1.0f/DMODEL);
    float var  = red[1] * (1.0f/DMODEL) - mean*mean;
    float inv  = rsqrtf(var + EPSV);
    const float* sh = mod + strm*6144 + 3*1024;
    const float* sc = mod + strm*6144 + 4*1024;
    float4 shv = *reinterpret_cast<const float4*>(sh + d);
    float4 scv = *reinterpret_cast<const float4*>(sc + d);
    ushort4v o;
    o.x = f2bf((1.f+scv.x)*((x.x-mean)*inv) + shv.x);
    o.y = f2bf((1.f+scv.y)*((x.y-mean)*inv) + shv.y);
    o.z = f2bf((1.f+scv.z)*((x.z-mean)*inv) + shv.z);
    o.w = f2bf((1.f+scv.w)*((x.w-mean)*inv) + shv.w);
    *reinterpret_cast<ushort4v*>(xm + (size_t)row*DMODEL + d) = o;
}

// ---------------- multi-stream bf16 MFMA GEMM, templated BM, BN=128, BK=64 ----------------
__device__ __forceinline__ float gelu_fast(float x) {
    return x / (1.0f + __expf(-1.5957691216057308f * (x + 0.044715f * x * x * x)));
}

template<int MODE, int BM, typename OutT>
__global__ __launch_bounds__(256) void k_gemm_ms(const ushort* __restrict__ A_t,
                                                 const ushort* __restrict__ A_i,
                                                 const ushort* __restrict__ A_m,
                                                 const ushort* __restrict__ BT,
                                                 const float* __restrict__ bias,
                                                 const float* __restrict__ res_t,
                                                 const float* __restrict__ res_i,
                                                 const float* __restrict__ res_m,
                                                 const float* __restrict__ mod, int gidx,
                                                 OutT* __restrict__ out_t,
                                                 OutT* __restrict__ out_i,
                                                 OutT* __restrict__ out_m,
                                                 int N, int K, int ry0) {
    constexpr int MI = BM / 32;
    const int brow = (ry0 + blockIdx.y) * BM;
    int s, lrow;
    if (brow < 256)       { s = 2; lrow = brow; }
    else if (brow < 1280) { s = 0; lrow = brow - 256; }
    else                  { s = 1; lrow = brow - 1280; }

    const ushort* A = (s==2 ? A_t : s==0 ? A_i : A_m) + (size_t)lrow * K;
    const ushort* BTs = BT + (size_t)s * N * K;
    const float* bi = bias ? bias + (size_t)s * N : nullptr;
    const float* resl = (MODE==2) ? ((s==2 ? res_t : s==0 ? res_i : res_m) + (size_t)lrow * N) : nullptr;
    const float* gate = (MODE==2) ? (mod + s*6144 + gidx*1024) : nullptr;
    OutT* Cl = (s==2 ? out_t : s==0 ? out_i : out_m) + (size_t)lrow * N;

    __shared__ ushort Asl[BM*64];
    __shared__ ushort Bsl[128*64];
    const int tid = threadIdx.x;
    const int lane = tid & 63, w = tid >> 6;
    const int wr = w >> 1, wc = w & 1;
    const int bn = blockIdx.x * 128;
    const int r15 = lane & 15, g4 = lane >> 4;

    f32x4 acc[MI][4];
#pragma unroll
    for (int i = 0; i < MI; i++)
#pragma unroll
        for (int j = 0; j < 4; j++) acc[i][j] = (f32x4){0.f,0.f,0.f,0.f};

    for (int k0 = 0; k0 < K; k0 += 64) {
#pragma unroll
        for (int i = 0; i < BM/32; i++) {
            int chunk = i*4 + w;
            int seg = chunk*64 + lane;
            int row = seg >> 3;
            int gs  = (seg & 7) ^ (row & 7);
            gload16(A + (size_t)row * K + k0 + gs*8, Asl + (size_t)chunk * 512);
        }
#pragma unroll
        for (int i = 0; i < 4; i++) {
            int chunk = i*4 + w;
            int seg = chunk*64 + lane;
            int row = seg >> 3;
            int gs  = (seg & 7) ^ (row & 7);
            gload16(BTs + (size_t)(bn + row) * K + k0 + gs*8, Bsl + (size_t)chunk * 512);
        }
        __syncthreads();
#pragma unroll
        for (int kk = 0; kk < 2; kk++) {
            short8b a[MI], b[4];
#pragma unroll
            for (int mi = 0; mi < MI; mi++) {
                int row = wr*(MI*16) + mi*16 + r15;
                int c   = kk*4 + g4;
                a[mi] = *reinterpret_cast<const short8b*>(&Asl[row*64 + ((c ^ (row & 7)))*8]);
            }
#pragma unroll
            for (int ni = 0; ni < 4; ni++) {
                int row = wc*64 + ni*16 + r15;
                int c   = kk*4 + g4;
                b[ni] = *reinterpret_cast<const short8b*>(&Bsl[row*64 + ((c ^ (row & 7)))*8]);
            }
#pragma unroll
            for (int mi = 0; mi < MI; mi++)
#pragma unroll
                for (int ni = 0; ni < 4; ni++)
                    acc[mi][ni] = __builtin_amdgcn_mfma_f32_16x16x32_bf16(a[mi], b[ni], acc[mi][ni], 0, 0, 0);
        }
        __syncthreads();
    }

#pragma unroll
    for (int mi = 0; mi < MI; mi++) {
#pragma unroll
        for (int ni = 0; ni < 4; ni++) {
            int col = bn + wc*64 + ni*16 + r15;
            float bv = bi ? bi[col] : 0.f;
#pragma unroll
            for (int r = 0; r < 4; r++) {
                int rr = wr*(MI*16) + mi*16 + g4*4 + r;
                float v = acc[mi][ni][r] + bv;
                if (MODE == 1) v = gelu_fast(v);
                if (MODE == 2) v = resl[(size_t)rr * N + col] + gate[col] * v;
                if (sizeof(OutT) == 2) Cl[(size_t)rr * N + col] = (OutT)f2bf(v);
                else                   Cl[(size_t)rr * N + col] = (OutT)v;
            }
        }
    }
}

// ---------------- qkv finalize + V transpose: block = (h, 64-l tile) ----------------
__global__ __launch_bounds__(256) void k_qkvfin(const ushort* __restrict__ qkv,
                                                const float* __restrict__ pe,
                                                const float* __restrict__ qs,
                                                const float* __restrict__ ks,
                                                ushort* __restrict__ Q,
                                                ushort* __restrict__ K,
                                                ushort* __restrict__ VT) {
    const int tid = threadIdx.x;
    const int w = tid >> 6, lane = tid & 63;
    const int h  = blockIdx.x / 36;
    const int l0 = (blockIdx.x % 36) * 64;
    __shared__ ushort vbuf[64][65];

    for (int it = 0; it < 16; it++) {
        int ll = it*4 + w;
        int l = l0 + ll;
        int strm;
        if (l < L_TXT) strm = 2; else if (l < L_TXT + L_IMG) strm = 0; else strm = 1;
        const ushort* row = qkv + (size_t)l * 3 * DMODEL + h*HDIM + lane;
        float q = bf2f(row[0]);
        float k = bf2f(row[DMODEL]);
        float v = bf2f(row[2*DMODEL]);

        float sq = q*q, sk = k*k;
#pragma unroll
        for (int o = 32; o > 0; o >>= 1) { sq += __shfl_xor(sq, o); sk += __shfl_xor(sk, o); }
        float rq = q * rsqrtf(sq * (1.0f/HDIM) + EPSV) * qs[strm*HDIM + lane];
        float rk = k * rsqrtf(sk * (1.0f/HDIM) + EPSV) * ks[strm*HDIM + lane];

        // BUG replication: temporal stream's V is its RMS'd Q (pre-RoPE)
        float vout = (strm == 1) ? rq : v;

        float rq_p = __shfl_xor(rq, 1);
        float rk_p = __shfl_xor(rk, 1);
        float qe = (lane & 1) ? rq_p : rq;
        float qo = (lane & 1) ? rq : rq_p;
        float ke = (lane & 1) ? rk_p : rk;
        float ko = (lane & 1) ? rk : rk_p;
        const float* pel = pe + (size_t)l*128 + (lane >> 1)*4 + (lane & 1)*2;
        float qr = pel[0]*qe + pel[1]*qo;
        float kr = pel[0]*ke + pel[1]*ko;

        size_t idx = ((size_t)h * LTOT + l) * HDIM + lane;
        Q[idx] = f2bf(qr);
        K[idx] = f2bf(kr);
        vbuf[ll][lane] = f2bf(vout);
    }
    __syncthreads();
    // VT store: out row d (head-dim), 64 l's
    {
        int d = tid >> 2, ls = (tid & 3) * 16;
        ushort8v u0, u1;
#pragma unroll
        for (int i = 0; i < 8; i++) u0[i] = vbuf[ls+i][d];
#pragma unroll
        for (int i = 0; i < 8; i++) u1[i] = vbuf[ls+8+i][d];
        ushort* dst = VT + ((size_t)h * 64 + d) * LTOT + l0 + ls;
        *reinterpret_cast<ushort8v*>(dst)     = u0;
        *reinterpret_cast<ushort8v*>(dst + 8) = u1;
    }
}

// ---------------- MFMA flash attention: LDS K/V double-buffer + prefetch + setprio ----------------
__global__ __launch_bounds__(256) void k_attn_mfma(const ushort* __restrict__ Qb,
                                                   const ushort* __restrict__ Kb,
                                                   const ushort* __restrict__ VTb,
                                                   ushort* __restrict__ att) {
    const int tid = threadIdx.x;
    const int w = tid >> 6, lane = tid & 63;
    const int h  = blockIdx.x / 36;
    const int qt = blockIdx.x % 36;
    const int qbase = qt*64 + w*16;
    const int g = lane >> 4;
    const int q = lane & 15;

    __shared__ ushort Ksl[2][64*64];
    __shared__ ushort Vsl[2][64*64];
    __shared__ ushort plds[4][1024];
    ushort* P = plds[w];

    const ushort* Kg = Kb  + (size_t)h * LTOT * 64;
    const ushort* Vg = VTb + (size_t)h * 64 * LTOT;

    const ushort* qp = Qb + ((size_t)h * LTOT + qbase + q) * 64 + g*8;
    const short8b qf0 = *reinterpret_cast<const short8b*>(qp);
    const short8b qf1 = *reinterpret_cast<const short8b*>(qp + 32);

    f32x4 out[4];
#pragma unroll
    for (int d = 0; d < 4; d++) out[d] = (f32x4){0.f,0.f,0.f,0.f};
    float m = -1e30f, lsum = 0.f;

    // prologue: stage tile 0 into buffer 0
#pragma unroll
    for (int i = 0; i < 2; i++) {
        int seg = i*256 + tid;
        int row = seg >> 3;
        int gs  = (seg & 7) ^ (row & 7);
        gload16(Kg + (size_t)row*64 + gs*8, &Ksl[0][(size_t)(i*256 + w*64)*8]);
        gload16(Vg + (size_t)row*LTOT + gs*8, &Vsl[0][(size_t)(i*256 + w*64)*8]);
    }

    for (int t = 0; t < 36; t++) {
        const int cb = t & 1;
        __syncthreads();   // waits current buffer's loads + all waves done with prev buffer
        if (t < 35) {      // prefetch next tile into other buffer (overlaps compute below)
            int kvn = (t+1) * 64;
#pragma unroll
            for (int i = 0; i < 2; i++) {
                int seg = i*256 + tid;
                int row = seg >> 3;
                int gs  = (seg & 7) ^ (row & 7);
                gload16(Kg + (size_t)(kvn + row)*64 + gs*8, &Ksl[cb^1][(size_t)(i*256 + w*64)*8]);
                gload16(Vg + (size_t)row*LTOT + kvn + gs*8, &Vsl[cb^1][(size_t)(i*256 + w*64)*8]);
            }
        }

        f32x4 s[4];
        __builtin_amdgcn_s_setprio(1);
#pragma unroll
        for (int ks = 0; ks < 4; ks++) {
            int r = ks*16 + q;
            short8b kf0 = *reinterpret_cast<const short8b*>(&Ksl[cb][r*64 + ((g     ^ (r & 7)))*8]);
            short8b kf1 = *reinterpret_cast<const short8b*>(&Ksl[cb][r*64 + (((4+g) ^ (r & 7)))*8]);
            f32x4 acc = (f32x4){0.f,0.f,0.f,0.f};
            acc = __builtin_amdgcn_mfma_f32_16x16x32_bf16(kf0, qf0, acc, 0, 0, 0);
            acc = __builtin_amdgcn_mfma_f32_16x16x32_bf16(kf1, qf1, acc, 0, 0, 0);
            s[ks] = acc;
        }
        __builtin_amdgcn_s_setprio(0);
        float tmax = -1e30f;
#pragma unroll
        for (int ks = 0; ks < 4; ks++)
#pragma unroll
            for (int r = 0; r < 4; r++) tmax = fmaxf(tmax, s[ks][r]);
        tmax = fmaxf(tmax, __shfl_xor(tmax, 16));
        tmax = fmaxf(tmax, __shfl_xor(tmax, 32));
        float newm = fmaxf(m, tmax * 0.125f);
        float c = __expf(m - newm);
        float p[16];
        float tsum = 0.f;
#pragma unroll
        for (int ks = 0; ks < 4; ks++)
#pragma unroll
            for (int r = 0; r < 4; r++) {
                float pv = __expf(s[ks][r] * 0.125f - newm);
                p[ks*4+r] = pv;
                tsum += pv;
            }
        tsum += __shfl_xor(tsum, 16);
        tsum += __shfl_xor(tsum, 32);
        lsum = lsum * c + tsum;
        m = newm;
#pragma unroll
        for (int d = 0; d < 4; d++) out[d] *= c;

#pragma unroll
        for (int ks = 0; ks < 4; ks++) {
            ushort4v pk;
            pk.x = f2bf(p[ks*4+0]); pk.y = f2bf(p[ks*4+1]);
            pk.z = f2bf(p[ks*4+2]); pk.w = f2bf(p[ks*4+3]);
            int widx = (q*64 + ks*16 + g*4) ^ ((q & 7) << 3);
            *reinterpret_cast<ushort4v*>(&P[widx]) = pk;
        }
        __builtin_amdgcn_s_setprio(1);
#pragma unroll
        for (int c2 = 0; c2 < 2; c2++) {
            int ridx = (q*64 + c2*32 + g*8) ^ ((q & 7) << 3);
            short8b pf = *reinterpret_cast<const short8b*>(&P[ridx]);
#pragma unroll
            for (int ds = 0; ds < 4; ds++) {
                int d = ds*16 + q;
                short8b vf = *reinterpret_cast<const short8b*>(&Vsl[cb][d*64 + (((c2*4+g) ^ (d & 7)))*8]);
                out[ds] = __builtin_amdgcn_mfma_f32_16x16x32_bf16(vf, pf, out[ds], 0, 0, 0);
            }
        }
        __builtin_amdgcn_s_setprio(0);
    }

    float inv = 1.0f / lsum;
    ushort* orow = att + (size_t)(qbase + q) * DMODEL + h * HDIM;
#pragma unroll
    for (int ds = 0; ds < 4; ds++) {
        ushort4v o4;
        o4.x = f2bf(out[ds][0]*inv); o4.y = f2bf(out[ds][1]*inv);
        o4.z = f2bf(out[ds][2]*inv); o4.w = f2bf(out[ds][3]*inv);
        *reinterpret_cast<ushort4v*>(orow + ds*16 + g*4) = o4;
    }
}

// ---------------- launch ----------------
extern "C" void kernel_launch(void* const* d_in, const int* in_sizes, int n_in,
                              void* d_out, int out_size, void* d_ws, size_t ws_size,
                              hipStream_t stream) {
    const float* img  = (const float*)d_in[0];
    const float* tmp  = (const float*)d_in[1];
    const float* txt  = (const float*)d_in[2];
    const float* vec  = (const float*)d_in[3];
    const float* pe   = (const float*)d_in[4];
    const float* modw = (const float*)d_in[5];
    const float* modb = (const float*)d_in[6];
    const float* qkvw = (const float*)d_in[7];
    const float* qsc  = (const float*)d_in[8];
    const float* ksc  = (const float*)d_in[9];
    const float* projw= (const float*)d_in[10];
    const float* projb= (const float*)d_in[11];
    const float* w1   = (const float*)d_in[12];
    const float* b1   = (const float*)d_in[13];
    const float* w2   = (const float*)d_in[14];
    const float* b2   = (const float*)d_in[15];

    char* wsb = (char*)d_ws;
    float*  mod    = (float*) (wsb + MOD_OFF);
    ushort* xm     = (ushort*)(wsb + XM_OFF);
    ushort* qkv    = (ushort*)(wsb + QKV_OFF);
    ushort* t1     = (ushort*)(wsb + QKV_OFF);
    ushort* Qb     = (ushort*)(wsb + QB_OFF);
    ushort* Kb     = (ushort*)(wsb + KB_OFF);
    ushort* VTb    = (ushort*)(wsb + VTB_OFF);
    ushort* att    = (ushort*)(wsb + ATT_OFF);
    float*  s1     = (float*) (wsb + S1_OFF);
    ushort* qkvwt  = (ushort*)(wsb + QKVWT_OFF);
    ushort* projwt = (ushort*)(wsb + PROJWT_OFF);
    ushort* w1t    = (ushort*)(wsb + W1T_OFF);

    const bool bigws = ws_size >= W2T_END;
    ushort* w2t = bigws ? (ushort*)(wsb + W2T_OFF) : w1t;   // fallback: overlay w1t

    float* out_img = (float*)d_out;
    float* out_tmp = out_img + (size_t)L_IMG * DMODEL;
    float* out_txt = out_tmp + (size_t)L_TMP * DMODEL;

    // fused conversions + mod GEMV (w2 tiles only if separate region available)
    int conv_blocks = bigws ? (144 + 9216) : (144 + 6144);
    k_conv<<<conv_blocks, 256, 0, stream>>>(vec, modw, modb, mod,
                                            qkvw, projw, w1, w2,
                                            qkvwt, projwt, w1t, w2t);
    k_ln_mod1<<<LTOT, 256, 0, stream>>>(img, tmp, txt, mod, xm);

    // QKV: merged dispatch, BM=128
    k_gemm_ms<0, 128, ushort><<<dim3(24, 18), 256, 0, stream>>>(
        xm, xm + (size_t)256*DMODEL, xm + (size_t)1280*DMODEL,
        qkvwt, nullptr, nullptr, nullptr, nullptr, nullptr, 0,
        qkv, qkv + (size_t)256*3072, qkv + (size_t)1280*3072, 3072, DMODEL, 0);

    k_qkvfin<<<NH*36, 256, 0, stream>>>(qkv, pe, qsc, ksc, Qb, Kb, VTb);
    k_attn_mfma<<<NH*36, 256, 0, stream>>>(Qb, Kb, VTb, att);

    // proj + residual + gate1 -> s1 (BM=64: 288 blocks)
    k_gemm_ms<2, 64, float><<<dim3(8, 36), 256, 0, stream>>>(
        att, att + (size_t)256*DMODEL, att + (size_t)1280*DMODEL,
        projwt, projb, txt, img, tmp, mod, 2,
        s1, s1 + (size_t)256*DMODEL, s1 + (size_t)1280*DMODEL, DMODEL, DMODEL, 0);

    // ---- phase A: txt + img MLP ----
    k_ln_modg<<<1280, 256, 0, stream>>>(s1, mod, xm);
    k_gemm_ms<1, 128, ushort><<<dim3(32, 10), 256, 0, stream>>>(
        xm, xm + (size_t)256*DMODEL, xm + (size_t)1280*DMODEL,
        w1t, b1, nullptr, nullptr, nullptr, nullptr, 0,
        t1, t1 + (size_t)256*DMLP, t1, DMLP, DMODEL, 0);
    if (!bigws) {
        k_conv_slice<<<dim3(16, 64), 256, 0, stream>>>(w2,                          w1t,                          DMLP, DMODEL);
        k_conv_slice<<<dim3(16, 64), 256, 0, stream>>>(w2 + (size_t)2*DMLP*DMODEL,  w1t + (size_t)2*DMLP*DMODEL,  DMLP, DMODEL);
    }
    k_gemm_ms<2, 64, float><<<dim3(8, 20), 256, 0, stream>>>(
        t1, t1 + (size_t)256*DMLP, t1,
        w2t, b2, s1, s1 + (size_t)256*DMODEL, s1 + (size_t)1280*DMODEL, mod, 5,
        out_txt, out_img, out_tmp, DMODEL, DMLP, 0);

    // ---- phase B: temporal MLP (LN input is FINAL img — reference quirk) ----
    k_ln_mod2<<<L_TMP, 256, 0, stream>>>(out_img, mod + 1*6144 + 3*1024, mod + 1*6144 + 4*1024, xm + (size_t)1280*DMODEL);
    k_gemm_ms<1, 128, ushort><<<dim3(32, 8), 256, 0, stream>>>(
        xm, xm + (size_t)256*DMODEL, xm + (size_t)1280*DMODEL,
        w1t, b1, nullptr, nullptr, nullptr, nullptr, 0,
        t1, t1, t1, DMLP, DMODEL, 10);
    if (!bigws) {
        k_conv_slice<<<dim3(16, 64), 256, 0, stream>>>(w2 + (size_t)DMLP*DMODEL, w1t + (size_t)DMLP*DMODEL, DMLP, DMODEL);
    }
    k_gemm_ms<2, 64, float><<<dim3(8, 16), 256, 0, stream>>>(
        t1, t1, t1,
        w2t, b2, s1, s1, s1 + (size_t)1280*DMODEL, mod, 5,
        out_txt, out_img, out_tmp, DMODEL, DMLP, 20);
}

// Round 7
// 327.814 us; speedup vs baseline: 10.1988x; 1.0823x over previous
//
#include <hip/hip_runtime.h>
#include <hip/hip_bf16.h>

#define L_TXT 256
#define L_IMG 1024
#define L_TMP 1024
#define LTOT  2304
#define DMODEL 1024
#define NH 16
#define HDIM 64
#define DMLP 4096
#define EPSV 1e-6f

typedef unsigned short ushort;
typedef __attribute__((ext_vector_type(8))) short short8b;   // 8 x bf16
typedef __attribute__((ext_vector_type(8))) unsigned short ushort8v;
typedef __attribute__((ext_vector_type(4))) float f32x4;
typedef __attribute__((ext_vector_type(4))) unsigned short ushort4v;

// ---- workspace layout (bytes) ----
#define MOD_OFF    ((size_t)0)                       // f32 3*6144
#define XM_OFF     ((size_t)73728)                   // bf16 2304*1024
#define QKV_OFF    ((size_t)4792320)                 // bf16 2304*3072 (t1 overlays)
#define QB_OFF     ((size_t)18948096)                // bf16 16*2304*64
#define KB_OFF     ((size_t)23666688)
#define VTB_OFF    ((size_t)28385280)
#define ATT_OFF    ((size_t)33103872)                // bf16 2304*1024 (mod partials overlay pre-attn)
#define S1_OFF     ((size_t)37822464)                // f32 2304*1024
#define QKVWT_OFF  ((size_t)49356800)                // bf16 3*3072*1024
#define PROJWT_OFF ((size_t)68231168)                // bf16 3*1024*1024
#define W1T_OFF    ((size_t)74522624)                // bf16 3*4096*1024
#define W2T_OFF    ((size_t)99688448)                // bf16 3*1024*4096 (if ws large)
#define W2T_END    ((size_t)124854272)

static __device__ __forceinline__ ushort f2bf(float x) {
    __hip_bfloat16 b = __float2bfloat16(x);
    return *reinterpret_cast<ushort*>(&b);
}
static __device__ __forceinline__ float bf2f(ushort u) {
    return __uint_as_float(((unsigned)u) << 16);
}

typedef __attribute__((address_space(1))) const unsigned char gas_t;
typedef __attribute__((address_space(3))) unsigned char las_t;
static __device__ __forceinline__ void gload16(const void* g, void* l) {
    __builtin_amdgcn_global_load_lds((gas_t*)g, (las_t*)l, 16, 0, 0);
}

// ---------------- fused: mod GEMV partials (576 blocks) + 64x64 weight transpose-convert ----------------
// bid<576: mod partial (g=bid>>2, ksplit=bid&3): 128 outputs over K=256 -> modp[ks][18432].
// else: 64x64 transpose tiles: qkv (2304), proj (768), w1 (3072), [w2 (3072) if bigws].
__global__ __launch_bounds__(256) void k_conv(const float* __restrict__ vec,
                                              const float* __restrict__ modw,
                                              float* __restrict__ modp,
                                              const float* __restrict__ qkvw,
                                              const float* __restrict__ projw,
                                              const float* __restrict__ w1,
                                              const float* __restrict__ w2,
                                              ushort* __restrict__ qkvwt,
                                              ushort* __restrict__ projwt,
                                              ushort* __restrict__ w1t,
                                              ushort* __restrict__ w2t) {
    __shared__ float tb[64][65];
    int bid = blockIdx.x;
    int tid = threadIdx.x;
    if (bid < 576) {
        // ---- mod GEMV partial: K-slice of 256 ----
        float* svs = &tb[0][0];             // 256 floats
        float* pl  = &tb[0][0] + 1024;      // 8 x 128
        int g0 = (bid >> 2) * 128;
        int ks = bid & 3;
        int i  = g0 / 6144;
        int j0 = g0 - i * 6144;
        {
            float v = vec[ks*256 + tid];
            svs[tid] = v / (1.0f + __expf(-v));
        }
        __syncthreads();
        int jl = tid & 31, ko = tid >> 5;
        const float* wp = modw + (size_t)i * 1024 * 6144 + (size_t)(ks*256) * 6144 + j0 + jl*4;
        float4 acc = {0.f,0.f,0.f,0.f};
#pragma unroll 8
        for (int kk = 0; kk < 32; kk++) {
            int k = kk*8 + ko;
            float4 wv = *reinterpret_cast<const float4*>(wp + (size_t)k * 6144);
            float s = svs[k];
            acc.x += s*wv.x; acc.y += s*wv.y; acc.z += s*wv.z; acc.w += s*wv.w;
        }
        pl[ko*128 + jl*4+0] = acc.x; pl[ko*128 + jl*4+1] = acc.y;
        pl[ko*128 + jl*4+2] = acc.z; pl[ko*128 + jl*4+3] = acc.w;
        __syncthreads();
        if (tid < 128) {
            float s = 0.f;
#pragma unroll
            for (int k = 0; k < 8; k++) s += pl[k*128 + tid];
            modp[(size_t)ks*18432 + g0 + tid] = s;
        }
        return;
    }
    int b = bid - 576;
    const float* W; ushort* WT; int K, N, nt, kt;
    if (b < 2304) {                 // qkv: K=1024, N=3072 -> 16x48
        int s = b / 768, r = b % 768;
        K = 1024; N = 3072; nt = r % 48; kt = r / 48;
        W = qkvw + (size_t)s * K * N; WT = qkvwt + (size_t)s * N * K;
    } else if (b < 3072) {          // proj: 16x16
        b -= 2304; int s = b / 256, r = b % 256;
        K = 1024; N = 1024; nt = r % 16; kt = r / 16;
        W = projw + (size_t)s * K * N; WT = projwt + (size_t)s * N * K;
    } else if (b < 6144) {          // w1: 16x64
        b -= 3072; int s = b / 1024, r = b % 1024;
        K = 1024; N = 4096; nt = r % 64; kt = r / 64;
        W = w1 + (size_t)s * K * N; WT = w1t + (size_t)s * N * K;
    } else {                        // w2: K=4096, N=1024 -> 64x16
        b -= 6144; int s = b / 1024, r = b % 1024;
        K = 4096; N = 1024; nt = r % 16; kt = r / 16;
        W = w2 + (size_t)s * K * N; WT = w2t + (size_t)s * N * K;
    }
    {
        int r = tid >> 4, c4 = (tid & 15) * 4;
#pragma unroll
        for (int i = 0; i < 4; i++) {
            float4 v = *reinterpret_cast<const float4*>(W + (size_t)(kt*64 + r + i*16) * N + nt*64 + c4);
            tb[r + i*16][c4+0] = v.x; tb[r + i*16][c4+1] = v.y;
            tb[r + i*16][c4+2] = v.z; tb[r + i*16][c4+3] = v.w;
        }
    }
    __syncthreads();
    // transposed bf16 store: 128B segments (8 lanes x 16B per out-row)
    {
        int n  = tid >> 3;           // 0..31
        int k8 = (tid & 7) * 8;      // 0..56
#pragma unroll
        for (int half = 0; half < 2; half++) {
            int nn = n + half*32;
            ushort8v u;
#pragma unroll
            for (int i = 0; i < 8; i++) u[i] = f2bf(tb[k8+i][nn]);
            *reinterpret_cast<ushort8v*>(WT + (size_t)(nt*64 + nn) * K + kt*64 + k8) = u;
        }
    }
}

// mod partial reduce: mod[g] = sum_ks p[ks][g] + bias[g]
__global__ __launch_bounds__(256) void k_modr(const float* __restrict__ p,
                                              const float* __restrict__ modb,
                                              float* __restrict__ mod) {
    int g = blockIdx.x * 256 + threadIdx.x;
    float s = p[g] + p[18432 + g] + p[2*18432 + g] + p[3*18432 + g];
    mod[g] = s + modb[g];
}

// standalone slice transpose (w2 fallback when ws too small): grid (N/64, K/64)
__global__ __launch_bounds__(256) void k_conv_slice(const float* __restrict__ W,
                                                    ushort* __restrict__ WT,
                                                    int K, int N) {
    __shared__ float tb[64][65];
    int nt = blockIdx.x, kt = blockIdx.y, tid = threadIdx.x;
    {
        int r = tid >> 4, c4 = (tid & 15) * 4;
#pragma unroll
        for (int i = 0; i < 4; i++) {
            float4 v = *reinterpret_cast<const float4*>(W + (size_t)(kt*64 + r + i*16) * N + nt*64 + c4);
            tb[r + i*16][c4+0] = v.x; tb[r + i*16][c4+1] = v.y;
            tb[r + i*16][c4+2] = v.z; tb[r + i*16][c4+3] = v.w;
        }
    }
    __syncthreads();
    {
        int n  = tid >> 3;
        int k8 = (tid & 7) * 8;
#pragma unroll
        for (int half = 0; half < 2; half++) {
            int nn = n + half*32;
            ushort8v u;
#pragma unroll
            for (int i = 0; i < 8; i++) u[i] = f2bf(tb[k8+i][nn]);
            *reinterpret_cast<ushort8v*>(WT + (size_t)(nt*64 + nn) * K + kt*64 + k8) = u;
        }
    }
}

// ---------------- LN + (1+sc)*x + sh -> bf16, stream-select (inputs) ----------------
__global__ __launch_bounds__(256) void k_ln_mod1(const float* __restrict__ img,
                                                 const float* __restrict__ tmp,
                                                 const float* __restrict__ txt,
                                                 const float* __restrict__ mod,
                                                 ushort* __restrict__ xm) {
    int l = blockIdx.x;
    const float* src; int strm;
    if (l < L_TXT)              { src = txt + (size_t)l * DMODEL;            strm = 2; }
    else if (l < L_TXT + L_IMG) { src = img + (size_t)(l - L_TXT) * DMODEL;  strm = 0; }
    else                        { src = tmp + (size_t)(l - L_TXT - L_IMG) * DMODEL; strm = 1; }

    int d = threadIdx.x * 4;
    float4 x = *reinterpret_cast<const float4*>(src + d);
    float s  = x.x + x.y + x.z + x.w;
    float s2 = x.x*x.x + x.y*x.y + x.z*x.z + x.w*x.w;
#pragma unroll
    for (int o = 32; o > 0; o >>= 1) { s += __shfl_xor(s, o); s2 += __shfl_xor(s2, o); }
    __shared__ float red[8];
    int wave = threadIdx.x >> 6, lane = threadIdx.x & 63;
    if (lane == 0) { red[wave*2] = s; red[wave*2+1] = s2; }
    __syncthreads();
    if (threadIdx.x == 0) {
        float a = 0.f, b = 0.f;
        for (int w = 0; w < 4; w++) { a += red[w*2]; b += red[w*2+1]; }
        red[0] = a; red[1] = b;
    }
    __syncthreads();
    float mean = red[0] * (1.0f/DMODEL);
    float var  = red[1] * (1.0f/DMODEL) - mean*mean;
    float inv  = rsqrtf(var + EPSV);

    const float* sh = mod + strm*6144;
    const float* sc = sh + 1024;
    float4 shv = *reinterpret_cast<const float4*>(sh + d);
    float4 scv = *reinterpret_cast<const float4*>(sc + d);
    ushort4v o;
    o.x = f2bf((1.f+scv.x)*((x.x-mean)*inv) + shv.x);
    o.y = f2bf((1.f+scv.y)*((x.y-mean)*inv) + shv.y);
    o.z = f2bf((1.f+scv.z)*((x.z-mean)*inv) + shv.z);
    o.w = f2bf((1.f+scv.w)*((x.w-mean)*inv) + shv.w);
    *reinterpret_cast<ushort4v*>(xm + (size_t)l*DMODEL + d) = o;
}

// ---------------- generic LN + modulate -> bf16 (explicit pointers) ----------------
__global__ __launch_bounds__(256) void k_ln_mod2(const float* __restrict__ src,
                                                 const float* __restrict__ sh,
                                                 const float* __restrict__ sc,
                                                 ushort* __restrict__ out) {
    int r = blockIdx.x;
    const float* srow = src + (size_t)r * DMODEL;
    int d = threadIdx.x * 4;
    float4 x = *reinterpret_cast<const float4*>(srow + d);
    float s  = x.x + x.y + x.z + x.w;
    float s2 = x.x*x.x + x.y*x.y + x.z*x.z + x.w*x.w;
#pragma unroll
    for (int o = 32; o > 0; o >>= 1) { s += __shfl_xor(s, o); s2 += __shfl_xor(s2, o); }
    __shared__ float red[8];
    int wave = threadIdx.x >> 6, lane = threadIdx.x & 63;
    if (lane == 0) { red[wave*2] = s; red[wave*2+1] = s2; }
    __syncthreads();
    if (threadIdx.x == 0) {
        float a = 0.f, b = 0.f;
        for (int w = 0; w < 4; w++) { a += red[w*2]; b += red[w*2+1]; }
        red[0] = a; red[1] = b;
    }
    __syncthreads();
    float mean = red[0] * (1.0f/DMODEL);
    float var  = red[1] * (1.0f/DMODEL) - mean*mean;
    float inv  = rsqrtf(var + EPSV);
    float4 shv = *reinterpret_cast<const float4*>(sh + d);
    float4 scv = *reinterpret_cast<const float4*>(sc + d);
    ushort4v o;
    o.x = f2bf((1.f+scv.x)*((x.x-mean)*inv) + shv.x);
    o.y = f2bf((1.f+scv.y)*((x.y-mean)*inv) + shv.y);
    o.z = f2bf((1.f+scv.z)*((x.z-mean)*inv) + shv.z);
    o.w = f2bf((1.f+scv.w)*((x.w-mean)*inv) + shv.w);
    *reinterpret_cast<ushort4v*>(out + (size_t)r*DMODEL + d) = o;
}

// ---------------- phase-A LN: global rows 0..1279 of s1 (txt then img) ----------------
__global__ __launch_bounds__(256) void k_ln_modg(const float* __restrict__ s1,
                                                 const float* __restrict__ mod,
                                                 ushort* __restrict__ xm) {
    int row = blockIdx.x;
    int strm = row < 256 ? 2 : 0;
    const float* srow = s1 + (size_t)row * DMODEL;
    int d = threadIdx.x * 4;
    float4 x = *reinterpret_cast<const float4*>(srow + d);
    float s  = x.x + x.y + x.z + x.w;
    float s2 = x.x*x.x + x.y*x.y + x.z*x.z + x.w*x.w;
#pragma unroll
    for (int o = 32; o > 0; o >>= 1) { s += __shfl_xor(s, o); s2 += __shfl_xor(s2, o); }
    __shared__ float red[8];
    int wave = threadIdx.x >> 6, lane = threadIdx.x & 63;
    if (lane == 0) { red[wave*2] = s; red[wave*2+1] = s2; }
    __syncthreads();
    if (threadIdx.x == 0) {
        float a = 0.f, b = 0.f;
        for (int w = 0; w < 4; w++) { a += red[w*2]; b += red[w*2+1]; }
        red[0] = a; red[1] = b;
    }
    __syncthreads();
    float mean = red[0] * (1.0f/DMODEL);
    float var  = red[1] * (1.0f/DMODEL) - mean*mean;
    float inv  = rsqrtf(var + EPSV);
    const float* sh = mod + strm*6144 + 3*1024;
    const float* sc = mod + strm*6144 + 4*1024;
    float4 shv = *reinterpret_cast<const float4*>(sh + d);
    float4 scv = *reinterpret_cast<const float4*>(sc + d);
    ushort4v o;
    o.x = f2bf((1.f+scv.x)*((x.x-mean)*inv) + shv.x);
    o.y = f2bf((1.f+scv.y)*((x.y-mean)*inv) + shv.y);
    o.z = f2bf((1.f+scv.z)*((x.z-mean)*inv) + shv.z);
    o.w = f2bf((1.f+scv.w)*((x.w-mean)*inv) + shv.w);
    *reinterpret_cast<ushort4v*>(xm + (size_t)row*DMODEL + d) = o;
}

// ---------------- multi-stream bf16 MFMA GEMM, templated BM/BN, BK=64 ----------------
__device__ __forceinline__ float gelu_fast(float x) {
    return x / (1.0f + __expf(-1.5957691216057308f * (x + 0.044715f * x * x * x)));
}

template<int MODE, int BM, int BN, typename OutT>
__global__ __launch_bounds__(256) void k_gemm_ms(const ushort* __restrict__ A_t,
                                                 const ushort* __restrict__ A_i,
                                                 const ushort* __restrict__ A_m,
                                                 const ushort* __restrict__ BT,
                                                 const float* __restrict__ bias,
                                                 const float* __restrict__ res_t,
                                                 const float* __restrict__ res_i,
                                                 const float* __restrict__ res_m,
                                                 const float* __restrict__ mod, int gidx,
                                                 OutT* __restrict__ out_t,
                                                 OutT* __restrict__ out_i,
                                                 OutT* __restrict__ out_m,
                                                 int N, int K, int ry0) {
    constexpr int MI = BM / 32;
    constexpr int NI = BN / 32;
    const int brow = (ry0 + blockIdx.y) * BM;
    int s, lrow;
    if (brow < 256)       { s = 2; lrow = brow; }
    else if (brow < 1280) { s = 0; lrow = brow - 256; }
    else                  { s = 1; lrow = brow - 1280; }

    const ushort* A = (s==2 ? A_t : s==0 ? A_i : A_m) + (size_t)lrow * K;
    const ushort* BTs = BT + (size_t)s * N * K;
    const float* bi = bias ? bias + (size_t)s * N : nullptr;
    const float* resl = (MODE==2) ? ((s==2 ? res_t : s==0 ? res_i : res_m) + (size_t)lrow * N) : nullptr;
    const float* gate = (MODE==2) ? (mod + s*6144 + gidx*1024) : nullptr;
    OutT* Cl = (s==2 ? out_t : s==0 ? out_i : out_m) + (size_t)lrow * N;

    __shared__ ushort Asl[BM*64];
    __shared__ ushort Bsl[BN*64];
    const int tid = threadIdx.x;
    const int lane = tid & 63, w = tid >> 6;
    const int wr = w >> 1, wc = w & 1;
    const int bn = blockIdx.x * BN;
    const int r15 = lane & 15, g4 = lane >> 4;

    f32x4 acc[MI][NI];
#pragma unroll
    for (int i = 0; i < MI; i++)
#pragma unroll
        for (int j = 0; j < NI; j++) acc[i][j] = (f32x4){0.f,0.f,0.f,0.f};

    for (int k0 = 0; k0 < K; k0 += 64) {
#pragma unroll
        for (int i = 0; i < BM/32; i++) {
            int chunk = i*4 + w;
            int seg = chunk*64 + lane;
            int row = seg >> 3;
            int gs  = (seg & 7) ^ (row & 7);
            gload16(A + (size_t)row * K + k0 + gs*8, Asl + (size_t)chunk * 512);
        }
#pragma unroll
        for (int i = 0; i < BN/32; i++) {
            int chunk = i*4 + w;
            int seg = chunk*64 + lane;
            int row = seg >> 3;
            int gs  = (seg & 7) ^ (row & 7);
            gload16(BTs + (size_t)(bn + row) * K + k0 + gs*8, Bsl + (size_t)chunk * 512);
        }
        __syncthreads();
#pragma unroll
        for (int kk = 0; kk < 2; kk++) {
            short8b a[MI], b[NI];
#pragma unroll
            for (int mi = 0; mi < MI; mi++) {
                int row = wr*(MI*16) + mi*16 + r15;
                int c   = kk*4 + g4;
                a[mi] = *reinterpret_cast<const short8b*>(&Asl[row*64 + ((c ^ (row & 7)))*8]);
            }
#pragma unroll
            for (int ni = 0; ni < NI; ni++) {
                int row = wc*(NI*16) + ni*16 + r15;
                int c   = kk*4 + g4;
                b[ni] = *reinterpret_cast<const short8b*>(&Bsl[row*64 + ((c ^ (row & 7)))*8]);
            }
#pragma unroll
            for (int mi = 0; mi < MI; mi++)
#pragma unroll
                for (int ni = 0; ni < NI; ni++)
                    acc[mi][ni] = __builtin_amdgcn_mfma_f32_16x16x32_bf16(a[mi], b[ni], acc[mi][ni], 0, 0, 0);
        }
        __syncthreads();
    }

#pragma unroll
    for (int mi = 0; mi < MI; mi++) {
#pragma unroll
        for (int ni = 0; ni < NI; ni++) {
            int col = bn + wc*(NI*16) + ni*16 + r15;
            float bv = bi ? bi[col] : 0.f;
#pragma unroll
            for (int r = 0; r < 4; r++) {
                int rr = wr*(MI*16) + mi*16 + g4*4 + r;
                float v = acc[mi][ni][r] + bv;
                if (MODE == 1) v = gelu_fast(v);
                if (MODE == 2) v = resl[(size_t)rr * N + col] + gate[col] * v;
                if (sizeof(OutT) == 2) Cl[(size_t)rr * N + col] = (OutT)f2bf(v);
                else                   Cl[(size_t)rr * N + col] = (OutT)v;
            }
        }
    }
}

// ---------------- qkv finalize + V transpose: block = (h, 64-l tile) ----------------
__global__ __launch_bounds__(256) void k_qkvfin(const ushort* __restrict__ qkv,
                                                const float* __restrict__ pe,
                                                const float* __restrict__ qs,
                                                const float* __restrict__ ks,
                                                ushort* __restrict__ Q,
                                                ushort* __restrict__ K,
                                                ushort* __restrict__ VT) {
    const int tid = threadIdx.x;
    const int w = tid >> 6, lane = tid & 63;
    const int h  = blockIdx.x / 36;
    const int l0 = (blockIdx.x % 36) * 64;
    __shared__ ushort vbuf[64][65];

    for (int it = 0; it < 16; it++) {
        int ll = it*4 + w;
        int l = l0 + ll;
        int strm;
        if (l < L_TXT) strm = 2; else if (l < L_TXT + L_IMG) strm = 0; else strm = 1;
        const ushort* row = qkv + (size_t)l * 3 * DMODEL + h*HDIM + lane;
        float q = bf2f(row[0]);
        float k = bf2f(row[DMODEL]);
        float v = bf2f(row[2*DMODEL]);

        float sq = q*q, sk = k*k;
#pragma unroll
        for (int o = 32; o > 0; o >>= 1) { sq += __shfl_xor(sq, o); sk += __shfl_xor(sk, o); }
        float rq = q * rsqrtf(sq * (1.0f/HDIM) + EPSV) * qs[strm*HDIM + lane];
        float rk = k * rsqrtf(sk * (1.0f/HDIM) + EPSV) * ks[strm*HDIM + lane];

        // BUG replication: temporal stream's V is its RMS'd Q (pre-RoPE)
        float vout = (strm == 1) ? rq : v;

        float rq_p = __shfl_xor(rq, 1);
        float rk_p = __shfl_xor(rk, 1);
        float qe = (lane & 1) ? rq_p : rq;
        float qo = (lane & 1) ? rq : rq_p;
        float ke = (lane & 1) ? rk_p : rk;
        float ko = (lane & 1) ? rk : rk_p;
        const float* pel = pe + (size_t)l*128 + (lane >> 1)*4 + (lane & 1)*2;
        float qr = pel[0]*qe + pel[1]*qo;
        float kr = pel[0]*ke + pel[1]*ko;

        size_t idx = ((size_t)h * LTOT + l) * HDIM + lane;
        Q[idx] = f2bf(qr);
        K[idx] = f2bf(kr);
        vbuf[ll][lane] = f2bf(vout);
    }
    __syncthreads();
    {
        int d = tid >> 2, ls = (tid & 3) * 16;
        ushort8v u0, u1;
#pragma unroll
        for (int i = 0; i < 8; i++) u0[i] = vbuf[ls+i][d];
#pragma unroll
        for (int i = 0; i < 8; i++) u1[i] = vbuf[ls+8+i][d];
        ushort* dst = VT + ((size_t)h * 64 + d) * LTOT + l0 + ls;
        *reinterpret_cast<ushort8v*>(dst)     = u0;
        *reinterpret_cast<ushort8v*>(dst + 8) = u1;
    }
}

// ---------------- MFMA flash attention: LDS K/V double-buffer + prefetch + setprio ----------------
__global__ __launch_bounds__(256) void k_attn_mfma(const ushort* __restrict__ Qb,
                                                   const ushort* __restrict__ Kb,
                                                   const ushort* __restrict__ VTb,
                                                   ushort* __restrict__ att) {
    const int tid = threadIdx.x;
    const int w = tid >> 6, lane = tid & 63;
    const int h  = blockIdx.x / 36;
    const int qt = blockIdx.x % 36;
    const int qbase = qt*64 + w*16;
    const int g = lane >> 4;
    const int q = lane & 15;

    __shared__ ushort Ksl[2][64*64];
    __shared__ ushort Vsl[2][64*64];
    __shared__ ushort plds[4][1024];
    ushort* P = plds[w];

    const ushort* Kg = Kb  + (size_t)h * LTOT * 64;
    const ushort* Vg = VTb + (size_t)h * 64 * LTOT;

    const ushort* qp = Qb + ((size_t)h * LTOT + qbase + q) * 64 + g*8;
    const short8b qf0 = *reinterpret_cast<const short8b*>(qp);
    const short8b qf1 = *reinterpret_cast<const short8b*>(qp + 32);

    f32x4 out[4];
#pragma unroll
    for (int d = 0; d < 4; d++) out[d] = (f32x4){0.f,0.f,0.f,0.f};
    float m = -1e30f, lsum = 0.f;

#pragma unroll
    for (int i = 0; i < 2; i++) {
        int seg = i*256 + tid;
        int row = seg >> 3;
        int gs  = (seg & 7) ^ (row & 7);
        gload16(Kg + (size_t)row*64 + gs*8, &Ksl[0][(size_t)(i*256 + w*64)*8]);
        gload16(Vg + (size_t)row*LTOT + gs*8, &Vsl[0][(size_t)(i*256 + w*64)*8]);
    }

    for (int t = 0; t < 36; t++) {
        const int cb = t & 1;
        __syncthreads();
        if (t < 35) {
            int kvn = (t+1) * 64;
#pragma unroll
            for (int i = 0; i < 2; i++) {
                int seg = i*256 + tid;
                int row = seg >> 3;
                int gs  = (seg & 7) ^ (row & 7);
                gload16(Kg + (size_t)(kvn + row)*64 + gs*8, &Ksl[cb^1][(size_t)(i*256 + w*64)*8]);
                gload16(Vg + (size_t)row*LTOT + kvn + gs*8, &Vsl[cb^1][(size_t)(i*256 + w*64)*8]);
            }
        }

        f32x4 s[4];
        __builtin_amdgcn_s_setprio(1);
#pragma unroll
        for (int ks = 0; ks < 4; ks++) {
            int r = ks*16 + q;
            short8b kf0 = *reinterpret_cast<const short8b*>(&Ksl[cb][r*64 + ((g     ^ (r & 7)))*8]);
            short8b kf1 = *reinterpret_cast<const short8b*>(&Ksl[cb][r*64 + (((4+g) ^ (r & 7)))*8]);
            f32x4 acc = (f32x4){0.f,0.f,0.f,0.f};
            acc = __builtin_amdgcn_mfma_f32_16x16x32_bf16(kf0, qf0, acc, 0, 0, 0);
            acc = __builtin_amdgcn_mfma_f32_16x16x32_bf16(kf1, qf1, acc, 0, 0, 0);
            s[ks] = acc;
        }
        __builtin_amdgcn_s_setprio(0);
        float tmax = -1e30f;
#pragma unroll
        for (int ks = 0; ks < 4; ks++)
#pragma unroll
            for (int r = 0; r < 4; r++) tmax = fmaxf(tmax, s[ks][r]);
        tmax = fmaxf(tmax, __shfl_xor(tmax, 16));
        tmax = fmaxf(tmax, __shfl_xor(tmax, 32));
        float newm = fmaxf(m, tmax * 0.125f);
        float c = __expf(m - newm);
        float p[16];
        float tsum = 0.f;
#pragma unroll
        for (int ks = 0; ks < 4; ks++)
#pragma unroll
            for (int r = 0; r < 4; r++) {
                float pv = __expf(s[ks][r] * 0.125f - newm);
                p[ks*4+r] = pv;
                tsum += pv;
            }
        tsum += __shfl_xor(tsum, 16);
        tsum += __shfl_xor(tsum, 32);
        lsum = lsum * c + tsum;
        m = newm;
#pragma unroll
        for (int d = 0; d < 4; d++) out[d] *= c;

#pragma unroll
        for (int ks = 0; ks < 4; ks++) {
            ushort4v pk;
            pk.x = f2bf(p[ks*4+0]); pk.y = f2bf(p[ks*4+1]);
            pk.z = f2bf(p[ks*4+2]); pk.w = f2bf(p[ks*4+3]);
            int widx = (q*64 + ks*16 + g*4) ^ ((q & 7) << 3);
            *reinterpret_cast<ushort4v*>(&P[widx]) = pk;
        }
        __builtin_amdgcn_s_setprio(1);
#pragma unroll
        for (int c2 = 0; c2 < 2; c2++) {
            int ridx = (q*64 + c2*32 + g*8) ^ ((q & 7) << 3);
            short8b pf = *reinterpret_cast<const short8b*>(&P[ridx]);
#pragma unroll
            for (int ds = 0; ds < 4; ds++) {
                int d = ds*16 + q;
                short8b vf = *reinterpret_cast<const short8b*>(&Vsl[cb][d*64 + (((c2*4+g) ^ (d & 7)))*8]);
                out[ds] = __builtin_amdgcn_mfma_f32_16x16x32_bf16(vf, pf, out[ds], 0, 0, 0);
            }
        }
        __builtin_amdgcn_s_setprio(0);
    }

    float inv = 1.0f / lsum;
    ushort* orow = att + (size_t)(qbase + q) * DMODEL + h * HDIM;
#pragma unroll
    for (int ds = 0; ds < 4; ds++) {
        ushort4v o4;
        o4.x = f2bf(out[ds][0]*inv); o4.y = f2bf(out[ds][1]*inv);
        o4.z = f2bf(out[ds][2]*inv); o4.w = f2bf(out[ds][3]*inv);
        *reinterpret_cast<ushort4v*>(orow + ds*16 + g*4) = o4;
    }
}

// ---------------- launch ----------------
extern "C" void kernel_launch(void* const* d_in, const int* in_sizes, int n_in,
                              void* d_out, int out_size, void* d_ws, size_t ws_size,
                              hipStream_t stream) {
    const float* img  = (const float*)d_in[0];
    const float* tmp  = (const float*)d_in[1];
    const float* txt  = (const float*)d_in[2];
    const float* vec  = (const float*)d_in[3];
    const float* pe   = (const float*)d_in[4];
    const float* modw = (const float*)d_in[5];
    const float* modb = (const float*)d_in[6];
    const float* qkvw = (const float*)d_in[7];
    const float* qsc  = (const float*)d_in[8];
    const float* ksc  = (const float*)d_in[9];
    const float* projw= (const float*)d_in[10];
    const float* projb= (const float*)d_in[11];
    const float* w1   = (const float*)d_in[12];
    const float* b1   = (const float*)d_in[13];
    const float* w2   = (const float*)d_in[14];
    const float* b2   = (const float*)d_in[15];

    char* wsb = (char*)d_ws;
    float*  mod    = (float*) (wsb + MOD_OFF);
    ushort* xm     = (ushort*)(wsb + XM_OFF);
    ushort* qkv    = (ushort*)(wsb + QKV_OFF);
    ushort* t1     = (ushort*)(wsb + QKV_OFF);
    ushort* Qb     = (ushort*)(wsb + QB_OFF);
    ushort* Kb     = (ushort*)(wsb + KB_OFF);
    ushort* VTb    = (ushort*)(wsb + VTB_OFF);
    float*  modp   = (float*) (wsb + ATT_OFF);      // overlay: dead before attn writes att
    ushort* att    = (ushort*)(wsb + ATT_OFF);
    float*  s1     = (float*) (wsb + S1_OFF);
    ushort* qkvwt  = (ushort*)(wsb + QKVWT_OFF);
    ushort* projwt = (ushort*)(wsb + PROJWT_OFF);
    ushort* w1t    = (ushort*)(wsb + W1T_OFF);

    const bool bigws = ws_size >= W2T_END;
    ushort* w2t = bigws ? (ushort*)(wsb + W2T_OFF) : w1t;   // fallback: overlay w1t

    float* out_img = (float*)d_out;
    float* out_tmp = out_img + (size_t)L_IMG * DMODEL;
    float* out_txt = out_tmp + (size_t)L_TMP * DMODEL;

    // fused conversions + mod GEMV partials
    int conv_blocks = 576 + (bigws ? 9216 : 6144);
    k_conv<<<conv_blocks, 256, 0, stream>>>(vec, modw, modp,
                                            qkvw, projw, w1, w2,
                                            qkvwt, projwt, w1t, w2t);
    k_modr<<<72, 256, 0, stream>>>(modp, modb, mod);
    k_ln_mod1<<<LTOT, 256, 0, stream>>>(img, tmp, txt, mod, xm);

    // QKV: merged dispatch, BM=128
    k_gemm_ms<0, 128, 128, ushort><<<dim3(24, 18), 256, 0, stream>>>(
        xm, xm + (size_t)256*DMODEL, xm + (size_t)1280*DMODEL,
        qkvwt, nullptr, nullptr, nullptr, nullptr, nullptr, 0,
        qkv, qkv + (size_t)256*3072, qkv + (size_t)1280*3072, 3072, DMODEL, 0);

    k_qkvfin<<<NH*36, 256, 0, stream>>>(qkv, pe, qsc, ksc, Qb, Kb, VTb);
    k_attn_mfma<<<NH*36, 256, 0, stream>>>(Qb, Kb, VTb, att);

    // proj + residual + gate1 -> s1 (BM=64: 288 blocks)
    k_gemm_ms<2, 64, 128, float><<<dim3(8, 36), 256, 0, stream>>>(
        att, att + (size_t)256*DMODEL, att + (size_t)1280*DMODEL,
        projwt, projb, txt, img, tmp, mod, 2,
        s1, s1 + (size_t)256*DMODEL, s1 + (size_t)1280*DMODEL, DMODEL, DMODEL, 0);

    // ---- phase A: txt + img MLP ----
    k_ln_modg<<<1280, 256, 0, stream>>>(s1, mod, xm);
    k_gemm_ms<1, 128, 128, ushort><<<dim3(32, 10), 256, 0, stream>>>(
        xm, xm + (size_t)256*DMODEL, xm + (size_t)1280*DMODEL,
        w1t, b1, nullptr, nullptr, nullptr, nullptr, 0,
        t1, t1 + (size_t)256*DMLP, t1, DMLP, DMODEL, 0);
    if (!bigws) {
        k_conv_slice<<<dim3(16, 64), 256, 0, stream>>>(w2,                          w1t,                          DMLP, DMODEL);
        k_conv_slice<<<dim3(16, 64), 256, 0, stream>>>(w2 + (size_t)2*DMLP*DMODEL,  w1t + (size_t)2*DMLP*DMODEL,  DMLP, DMODEL);
    }
    // mlp2 phase A (BM=64, BN=64: grid 16x20 = 320 blocks)
    k_gemm_ms<2, 64, 64, float><<<dim3(16, 20), 256, 0, stream>>>(
        t1, t1 + (size_t)256*DMLP, t1,
        w2t, b2, s1, s1 + (size_t)256*DMODEL, s1 + (size_t)1280*DMODEL, mod, 5,
        out_txt, out_img, out_tmp, DMODEL, DMLP, 0);

    // ---- phase B: temporal MLP (LN input is FINAL img — reference quirk) ----
    k_ln_mod2<<<L_TMP, 256, 0, stream>>>(out_img, mod + 1*6144 + 3*1024, mod + 1*6144 + 4*1024, xm + (size_t)1280*DMODEL);
    k_gemm_ms<1, 128, 128, ushort><<<dim3(32, 8), 256, 0, stream>>>(
        xm, xm + (size_t)256*DMODEL, xm + (size_t)1280*DMODEL,
        w1t, b1, nullptr, nullptr, nullptr, nullptr, 0,
        t1, t1, t1, DMLP, DMODEL, 10);
    if (!bigws) {
        k_conv_slice<<<dim3(16, 64), 256, 0, stream>>>(w2 + (size_t)DMLP*DMODEL, w1t + (size_t)DMLP*DMODEL, DMLP, DMODEL);
    }
    // mlp2 phase B (BM=64, BN=64: grid 16x16 = 256 blocks, ry0=20)
    k_gemm_ms<2, 64, 64, float><<<dim3(16, 16), 256, 0, stream>>>(
        t1, t1, t1,
        w2t, b2, s1, s1, s1 + (size_t)1280*DMODEL, mod, 5,
        out_txt, out_img, out_tmp, DMODEL, DMLP, 20);
}